// Round 8
// baseline (1852.498 us; speedup 1.0000x reference)
//
#include <hip/hip_runtime.h>
#include <hip/hip_bf16.h>
#include <math.h>

#define BB 64
#define SS 64
#define VV 8
#define WW 256
#define DD 8
#define BS (BB*SS)        // 4096
#define BSV (BB*SS*VV)    // 32768

typedef __attribute__((ext_vector_type(8))) short s8v;
typedef __attribute__((ext_vector_type(4))) float f4v;

__device__ __forceinline__ short f2b(float f) {
    __hip_bfloat16 h = __float2bfloat16(f);
    return *reinterpret_cast<short*>(&h);
}
__device__ __forceinline__ float b2f(short s) {
    __hip_bfloat16 h = *reinterpret_cast<__hip_bfloat16*>(&s);
    return __bfloat162float(h);
}

// ---------------------------------------------------------------------------
// bf16 MFMA GEMM (BK=32, LDS stride 40): C = act(A@B + bias) (+res)
// ---------------------------------------------------------------------------
template<int TM, int TN, int WM, int WN, bool OUTBF>
__global__ __launch_bounds__(256) void gemm_mfma(
    const short* __restrict__ A, const short* __restrict__ Bt,
    const float* __restrict__ bias, const float* __restrict__ res,
    float* __restrict__ Cf, short* __restrict__ Cb, short* __restrict__ Cb2,
    int M, int N, int K, int ldc, int ldc2, int relu)
{
    constexpr int MT  = WM / 16;
    constexpr int NT  = WN / 16;
    constexpr int RWN = TN / WN;
    __shared__ __align__(16) short As[TM * 40];
    __shared__ __align__(16) short Bs[TN * 40];
    int tid = threadIdx.x;
    int m0 = blockIdx.y * TM, n0 = blockIdx.x * TN;
    int lane = tid & 63, w = tid >> 6;
    int lm = lane & 15, lq = lane >> 4;
    int wm = (w / RWN) * WM, wn = (w % RWN) * WN;
    f4v acc[MT][NT];
#pragma unroll
    for (int i = 0; i < MT; i++)
#pragma unroll
        for (int j = 0; j < NT; j++) acc[i][j] = (f4v){0.f, 0.f, 0.f, 0.f};

    for (int k0 = 0; k0 < K; k0 += 32) {
        for (int c = tid; c < TM * 4; c += 256) {
            int r = c >> 2, kc = (c & 3) << 3;
            *(s8v*)&As[r * 40 + kc] = *(const s8v*)&A[(size_t)(m0 + r) * K + k0 + kc];
        }
        for (int c = tid; c < TN * 4; c += 256) {
            int r = c >> 2, kc = (c & 3) << 3;
            *(s8v*)&Bs[r * 40 + kc] = *(const s8v*)&Bt[(size_t)(n0 + r) * K + k0 + kc];
        }
        __syncthreads();
        s8v af[MT], bfv[NT];
#pragma unroll
        for (int i = 0; i < MT; i++)
            af[i] = *(const s8v*)&As[(wm + i * 16 + lm) * 40 + lq * 8];
#pragma unroll
        for (int j = 0; j < NT; j++)
            bfv[j] = *(const s8v*)&Bs[(wn + j * 16 + lm) * 40 + lq * 8];
#pragma unroll
        for (int i = 0; i < MT; i++)
#pragma unroll
            for (int j = 0; j < NT; j++)
                acc[i][j] = __builtin_amdgcn_mfma_f32_16x16x32_bf16(af[i], bfv[j], acc[i][j], 0, 0, 0);
        __syncthreads();
    }
#pragma unroll
    for (int i = 0; i < MT; i++) {
        int row = m0 + wm + i * 16 + lq * 4;
#pragma unroll
        for (int j = 0; j < NT; j++) {
            int col = n0 + wn + j * 16 + lm;
            float bv = bias ? bias[col] : 0.f;
#pragma unroll
            for (int r = 0; r < 4; r++) {
                float v = acc[i][j][r] + bv;
                if (relu) v = fmaxf(v, 0.f);
                size_t idx = (size_t)(row + r) * ldc + col;
                if (OUTBF) {
                    Cb[idx] = f2b(v);
                } else {
                    if (res) v += res[idx];
                    Cf[idx] = v;
                    if (Cb2) Cb2[(size_t)(row + r) * ldc2 + col] = f2b(v);
                }
            }
        }
    }
}

// ---------------------------------------------------------------------------
// LN-input fused GEMM: C = act(LN(A_fp32) @ B + bias). K=256 fixed, TM=64.
// A fp32 [M,256] (the residual stream). Per-block: LN of 64 rows (4 lanes/row,
// shfl reduce), normalized bf16 A-tile RESIDENT in LDS (staged once), then
// BK=32 B-staging K-loop. Grid (N/TN, M/64) — full parallelism retained.
// ---------------------------------------------------------------------------
template<int TN, int WM, int WN, bool OUTBF>
__global__ __launch_bounds__(256) void gemm_lnin(
    const float* __restrict__ A, const short* __restrict__ Bt,
    const float* __restrict__ g, const float* __restrict__ b, float eps,
    const float* __restrict__ bias,
    float* __restrict__ Cf, short* __restrict__ Cb, int ldc, int relu)
{
    constexpr int MT  = WM / 16;
    constexpr int NT  = WN / 16;
    constexpr int RWN = TN / WN;
    __shared__ __align__(16) short As[64 * 264];
    __shared__ __align__(16) short Bs[TN * 40];
    int tid = threadIdx.x;
    int m0 = blockIdx.y * 64, n0 = blockIdx.x * TN;
    int lane = tid & 63, w = tid >> 6;
    int lm = lane & 15, lq = lane >> 4;
    int wm = (w / RWN) * WM, wn = (w % RWN) * WN;

    // ---- LN stage: row r = tid>>2, 64 cols per thread ----
    {
        int r = tid >> 2, seg = tid & 3;
        const float* arow = &A[(size_t)(m0 + r) * 256 + seg * 64];
        float vals[64];
        float sum = 0.f;
#pragma unroll
        for (int k = 0; k < 16; k++) {
            float4 v = *(const float4*)&arow[k * 4];
            vals[k*4] = v.x; vals[k*4+1] = v.y; vals[k*4+2] = v.z; vals[k*4+3] = v.w;
            sum += v.x + v.y + v.z + v.w;
        }
        sum += __shfl_xor(sum, 1); sum += __shfl_xor(sum, 2);
        float mean = sum * (1.f / 256.f);
        float var = 0.f;
#pragma unroll
        for (int k = 0; k < 64; k++) { float d = vals[k] - mean; var += d * d; }
        var += __shfl_xor(var, 1); var += __shfl_xor(var, 2);
        float inv = rsqrtf(var * (1.f / 256.f) + eps);
#pragma unroll
        for (int k8 = 0; k8 < 8; k8++) {
            int col = seg * 64 + k8 * 8;
            float4 g0 = *(const float4*)&g[col], g1 = *(const float4*)&g[col + 4];
            float4 b0 = *(const float4*)&b[col], b1 = *(const float4*)&b[col + 4];
            s8v o;
            o[0] = f2b((vals[k8*8+0] - mean) * inv * g0.x + b0.x);
            o[1] = f2b((vals[k8*8+1] - mean) * inv * g0.y + b0.y);
            o[2] = f2b((vals[k8*8+2] - mean) * inv * g0.z + b0.z);
            o[3] = f2b((vals[k8*8+3] - mean) * inv * g0.w + b0.w);
            o[4] = f2b((vals[k8*8+4] - mean) * inv * g1.x + b1.x);
            o[5] = f2b((vals[k8*8+5] - mean) * inv * g1.y + b1.y);
            o[6] = f2b((vals[k8*8+6] - mean) * inv * g1.z + b1.z);
            o[7] = f2b((vals[k8*8+7] - mean) * inv * g1.w + b1.w);
            *(s8v*)&As[r * 264 + col] = o;
        }
    }
    f4v acc[MT][NT];
#pragma unroll
    for (int i = 0; i < MT; i++)
#pragma unroll
        for (int j = 0; j < NT; j++) acc[i][j] = (f4v){0.f, 0.f, 0.f, 0.f};

    for (int k0 = 0; k0 < 256; k0 += 32) {
        for (int c = tid; c < TN * 4; c += 256) {
            int r = c >> 2, kc = (c & 3) << 3;
            *(s8v*)&Bs[r * 40 + kc] = *(const s8v*)&Bt[(size_t)(n0 + r) * 256 + k0 + kc];
        }
        __syncthreads();   // also covers the LN-stage LDS writes on iter 0
        s8v af[MT], bfv[NT];
#pragma unroll
        for (int i = 0; i < MT; i++)
            af[i] = *(const s8v*)&As[(wm + i * 16 + lm) * 264 + k0 + lq * 8];
#pragma unroll
        for (int j = 0; j < NT; j++)
            bfv[j] = *(const s8v*)&Bs[(wn + j * 16 + lm) * 40 + lq * 8];
#pragma unroll
        for (int i = 0; i < MT; i++)
#pragma unroll
            for (int j = 0; j < NT; j++)
                acc[i][j] = __builtin_amdgcn_mfma_f32_16x16x32_bf16(af[i], bfv[j], acc[i][j], 0, 0, 0);
        __syncthreads();
    }
#pragma unroll
    for (int i = 0; i < MT; i++) {
        int row = m0 + wm + i * 16 + lq * 4;
#pragma unroll
        for (int j = 0; j < NT; j++) {
            int col = n0 + wn + j * 16 + lm;
            float bv = bias ? bias[col] : 0.f;
#pragma unroll
            for (int r = 0; r < 4; r++) {
                float v = acc[i][j][r] + bv;
                if (relu) v = fmaxf(v, 0.f);
                size_t idx = (size_t)(row + r) * ldc + col;
                if (OUTBF) Cb[idx] = f2b(v);
                else       Cf[idx] = v;
            }
        }
    }
}

// ---------------------------------------------------------------------------
// Batched kv GEMM for 4 layers (grid n=4, z=4, m=256 for rgbf L2 locality)
// ---------------------------------------------------------------------------
__global__ __launch_bounds__(256) void kvbatch(
    const short* __restrict__ rgbf, const short* __restrict__ hall,
    const short* __restrict__ kvpT, short* __restrict__ kvall, int base)
{
    __shared__ __align__(16) short As[128 * 72];
    __shared__ __align__(16) short Bs[128 * 72];
    int z = blockIdx.y, layer = base + z;
    const short* H  = hall + (size_t)layer * BSV * 32;
    const short* Bt = kvpT + (size_t)layer * 512 * 288;
    short* C = kvall + (size_t)z * BSV * 512;
    int tid = threadIdx.x;
    int m0 = blockIdx.z * 128, n0 = blockIdx.x * 128;
    int lane = tid & 63, w = tid >> 6;
    int lm = lane & 15, lq = lane >> 4;
    int wm = (w >> 1) * 64, wn = (w & 1) * 64;
    f4v acc[4][4];
#pragma unroll
    for (int i = 0; i < 4; i++)
#pragma unroll
        for (int j = 0; j < 4; j++) acc[i][j] = (f4v){0.f, 0.f, 0.f, 0.f};

    for (int k0 = 0; k0 < 256; k0 += 64) {
#pragma unroll
        for (int c = 0; c < 4; c++) {
            int e = tid + c * 256;
            int r = e >> 3, kc = (e & 7) << 3;
            *(s8v*)&As[r * 72 + kc] = *(const s8v*)&rgbf[(size_t)(m0 + r) * 256 + k0 + kc];
            *(s8v*)&Bs[r * 72 + kc] = *(const s8v*)&Bt[(size_t)(n0 + r) * 288 + k0 + kc];
        }
        __syncthreads();
#pragma unroll
        for (int cc = 0; cc < 2; cc++) {
            s8v af[4], bfv[4];
#pragma unroll
            for (int i = 0; i < 4; i++)
                af[i] = *(const s8v*)&As[(wm + i * 16 + lm) * 72 + cc * 32 + lq * 8];
#pragma unroll
            for (int j = 0; j < 4; j++)
                bfv[j] = *(const s8v*)&Bs[(wn + j * 16 + lm) * 72 + cc * 32 + lq * 8];
#pragma unroll
            for (int i = 0; i < 4; i++)
#pragma unroll
                for (int j = 0; j < 4; j++)
                    acc[i][j] = __builtin_amdgcn_mfma_f32_16x16x32_bf16(af[i], bfv[j], acc[i][j], 0, 0, 0);
        }
        __syncthreads();
    }
#pragma unroll
    for (int c = 0; c < 2; c++) {
        int e = tid + c * 256;
        int r = e >> 2, kc = (e & 3) << 3;
        *(s8v*)&As[r * 72 + kc] = *(const s8v*)&H[(size_t)(m0 + r) * 32 + kc];
        *(s8v*)&Bs[r * 72 + kc] = *(const s8v*)&Bt[(size_t)(n0 + r) * 288 + 256 + kc];
    }
    __syncthreads();
    {
        s8v af[4], bfv[4];
#pragma unroll
        for (int i = 0; i < 4; i++)
            af[i] = *(const s8v*)&As[(wm + i * 16 + lm) * 72 + lq * 8];
#pragma unroll
        for (int j = 0; j < 4; j++)
            bfv[j] = *(const s8v*)&Bs[(wn + j * 16 + lm) * 72 + lq * 8];
#pragma unroll
        for (int i = 0; i < 4; i++)
#pragma unroll
            for (int j = 0; j < 4; j++)
                acc[i][j] = __builtin_amdgcn_mfma_f32_16x16x32_bf16(af[i], bfv[j], acc[i][j], 0, 0, 0);
    }
#pragma unroll
    for (int i = 0; i < 4; i++) {
        int row = m0 + wm + i * 16 + lq * 4;
#pragma unroll
        for (int j = 0; j < 4; j++) {
            int col = n0 + wn + j * 16 + lm;
#pragma unroll
            for (int r = 0; r < 4; r++)
                C[(size_t)(row + r) * 512 + col] = f2b(acc[i][j][r]);
        }
    }
}

// hall[l][row][t] = relu(ray_diff[row] @ pw1[l] + pb1[l])  (all 8 layers)
__global__ void hallk(const float* __restrict__ rdiff, const float* __restrict__ pw1,
                      const float* __restrict__ pb1, short* __restrict__ hall)
{
    int idx = blockIdx.x * 256 + threadIdx.x;
    int t = idx & 31, row = (idx >> 5) & (BSV - 1), l = idx >> 20;
    float a = pb1[l * 32 + t];
    for (int c = 0; c < 4; c++) a += rdiff[row * 4 + c] * pw1[l * 128 + c * 32 + t];
    hall[idx] = f2b(fmaxf(a, 0.f));
}

// ---------------------------------------------------------------------------
// Fused cross-attention: per block = 8 samples (64 kv rows).
// ---------------------------------------------------------------------------
__global__ __launch_bounds__(256) void crossattn(
    const short* __restrict__ kv, const float* __restrict__ qf,
    const int* __restrict__ mask,
    const short* __restrict__ aw1T, const float* __restrict__ ab1,
    const short* __restrict__ aw2T, const float* __restrict__ ab2,
    short* __restrict__ obb)
{
    __shared__ __align__(16) short a_s[64 * 264];
    __shared__ __align__(16) short w_s[256 * 40];
    __shared__ __align__(16) short ph_s[64 * 40];
    __shared__ int msk[64];
    int blk = blockIdx.x, tid = threadIdx.x;
    int row0 = blk * 64, bs0 = blk * 8;
    int lane = tid & 63, w = tid >> 6, lm = lane & 15, lq = lane >> 4;
    if (tid < 64) msk[tid] = mask[bs0 * 8 + tid];
#pragma unroll
    for (int i = 0; i < 8; i++) {
        int e = tid + i * 256;
        int r = e >> 5, col = (e & 31) << 3;
        s8v kk = *(const s8v*)&kv[(size_t)(row0 + r) * 512 + col];
        const float* qp = &qf[(size_t)(bs0 + (r >> 3)) * 256 + col];
        s8v o;
#pragma unroll
        for (int j = 0; j < 8; j++) o[j] = f2b(b2f(kk[j]) - qp[j]);
        *(s8v*)&a_s[r * 264 + col] = o;
    }
#pragma unroll
    for (int i = 0; i < 4; i++) {
        int e = tid + i * 256;
        int r = e >> 5, col = (e & 31) << 3;
        *(s8v*)&w_s[r * 264 + col] = *(const s8v*)&aw1T[r * 256 + col];
    }
    __syncthreads();
    f4v a2[2];
    a2[0] = (f4v){0.f, 0.f, 0.f, 0.f}; a2[1] = (f4v){0.f, 0.f, 0.f, 0.f};
#pragma unroll
    for (int c = 0; c < 8; c++) {
        s8v af = *(const s8v*)&a_s[(w * 16 + lm) * 264 + c * 32 + lq * 8];
#pragma unroll
        for (int j = 0; j < 2; j++) {
            s8v bf = *(const s8v*)&w_s[(j * 16 + lm) * 264 + c * 32 + lq * 8];
            a2[j] = __builtin_amdgcn_mfma_f32_16x16x32_bf16(af, bf, a2[j], 0, 0, 0);
        }
    }
#pragma unroll
    for (int j = 0; j < 2; j++) {
        int col = j * 16 + lm;
        float bv = ab1[col];
#pragma unroll
        for (int r = 0; r < 4; r++)
            ph_s[(w * 16 + lq * 4 + r) * 40 + col] = f2b(fmaxf(a2[j][r] + bv, 0.f));
    }
    __syncthreads();
#pragma unroll
    for (int i = 0; i < 4; i++) {
        int e = tid + i * 256;
        int r = e >> 2, col = (e & 3) << 3;
        *(s8v*)&w_s[r * 40 + col] = *(const s8v*)&aw2T[r * 32 + col];
    }
#pragma unroll
    for (int i = 0; i < 8; i++) {
        int e = tid + i * 256;
        int r = e >> 5, col = (e & 31) << 3;
        *(s8v*)&a_s[r * 264 + col] = *(const s8v*)&kv[(size_t)(row0 + r) * 512 + 256 + col];
    }
    __syncthreads();
    s8v pf = *(const s8v*)&ph_s[(w * 16 + lm) * 40 + lq * 8];
    f4v a3[16];
#pragma unroll
    for (int j = 0; j < 16; j++) {
        s8v bf = *(const s8v*)&w_s[(j * 16 + lm) * 40 + lq * 8];
        a3[j] = __builtin_amdgcn_mfma_f32_16x16x32_bf16(pf, bf, (f4v){0.f, 0.f, 0.f, 0.f}, 0, 0, 0);
    }
    int sample = 2 * w + (lq >> 1);
    int mk[4];
#pragma unroll
    for (int r = 0; r < 4; r++) mk[r] = msk[sample * 8 + (lq & 1) * 4 + r];
#pragma unroll
    for (int j = 0; j < 16; j++) {
        int col = j * 16 + lm;
        float bv = ab2[col];
        float vals[4];
#pragma unroll
        for (int r = 0; r < 4; r++) vals[r] = mk[r] ? (a3[j][r] + bv) : -1e9f;
        float mx = fmaxf(fmaxf(vals[0], vals[1]), fmaxf(vals[2], vals[3]));
        mx = fmaxf(mx, __shfl_xor(mx, 16));
        float ev[4], s = 0.f;
#pragma unroll
        for (int r = 0; r < 4; r++) { ev[r] = expf(vals[r] - mx); s += ev[r]; }
        s += __shfl_xor(s, 16);
        float o = 0.f;
#pragma unroll
        for (int r = 0; r < 4; r++)
            o += ev[r] * b2f(a_s[(w * 16 + lq * 4 + r) * 264 + col]);
        o += __shfl_xor(o, 16);
        o /= s;
        if (!(lq & 1)) obb[(size_t)(bs0 + sample) * 256 + col] = f2b(o);
    }
}

// LayerNorm over 256, fp32 in -> bf16 out (final norm only)
__global__ __launch_bounds__(256) void lnormB(
    const float* __restrict__ in, const float* __restrict__ g,
    const float* __restrict__ b, short* __restrict__ out, float eps)
{
    int row = blockIdx.x, t = threadIdx.x;
    float x = in[(size_t)row * WW + t];
    __shared__ float red[256];
    red[t] = x;
    __syncthreads();
    for (int s = 128; s > 0; s >>= 1) { if (t < s) red[t] += red[t + s]; __syncthreads(); }
    float m = red[0] * (1.f / 256.f);
    __syncthreads();
    float d = x - m;
    red[t] = d * d;
    __syncthreads();
    for (int s = 128; s > 0; s >>= 1) { if (t < s) red[t] += red[t + s]; __syncthreads(); }
    float var = red[0] * (1.f / 256.f);
    out[(size_t)row * WW + t] = f2b(d / sqrtf(var + eps) * g[t] + b[t]);
}

// Weight convert+transpose: W fp32 [K,N] -> Wt bf16 [N,Kpad]
__global__ void wconv(const float* __restrict__ W, short* __restrict__ Wt,
                      int K, int N, int Kpad, int zi, size_t zo)
{
    __shared__ float t[32][33];
    int z = blockIdx.z;
    W  += (size_t)z * zi;
    Wt += (size_t)z * zo;
    int n0 = blockIdx.x * 32, k0 = blockIdx.y * 32;
    int tx = threadIdx.x, ty = threadIdx.y;
#pragma unroll
    for (int i = 0; i < 4; i++) {
        int k = k0 + ty + i * 8;
        t[ty + i * 8][tx] = (k < K) ? W[(size_t)k * N + n0 + tx] : 0.f;
    }
    __syncthreads();
#pragma unroll
    for (int i = 0; i < 4; i++) {
        int n = n0 + ty + i * 8;
        Wt[(size_t)n * Kpad + k0 + tx] = f2b(t[tx][ty + i * 8]);
    }
}

// rgb_feat fp32 [32768,35] -> bf16 [32768,64] zero-padded
__global__ void rgbconv(const float* __restrict__ x, short* __restrict__ o)
{
    int idx = blockIdx.x * 256 + threadIdx.x;
    int row = idx >> 6, col = idx & 63;
    o[idx] = f2b(col < 35 ? x[row * 35 + col] : 0.f);
}

__global__ void penc_pts(const float* __restrict__ pts, float* __restrict__ out)
{
    int bs = blockIdx.x * blockDim.x + threadIdx.x;
    if (bs >= BS) return;
    float xs[3] = {pts[bs * 3], pts[bs * 3 + 1], pts[bs * 3 + 2]};
    float* o = out + (size_t)bs * 63;
    o[0] = xs[0]; o[1] = xs[1]; o[2] = xs[2];
    for (int d = 0; d < 3; d++) {
        float f = 1.f;
        for (int k = 0; k < 10; k++) {
            float ang = xs[d] * f;
            o[3 + d * 10 + k]  = sinf(ang);
            o[33 + d * 10 + k] = cosf(ang);
            f *= 2.f;
        }
    }
}

__global__ void penc_views(const float* __restrict__ ray_d, float* __restrict__ out)
{
    int b = threadIdx.x;
    if (b >= BB) return;
    float x = ray_d[b * 3], y = ray_d[b * 3 + 1], z = ray_d[b * 3 + 2];
    float inv = 1.f / sqrtf(x * x + y * y + z * z);
    float v[3] = {x * inv, y * inv, z * inv};
    float* o = out + (size_t)b * 27;
    o[0] = v[0]; o[1] = v[1]; o[2] = v[2];
    for (int d = 0; d < 3; d++) {
        float f = 1.f;
        for (int k = 0; k < 4; k++) {
            float ang = v[d] * f;
            o[3 + d * 4 + k]  = sinf(ang);
            o[15 + d * 4 + k] = cosf(ang);
            f *= 2.f;
        }
    }
}

// static tail of cat buffer: catb[bs][256..383] = [ipts(63) | ivw(27) | 0(38)]
__global__ void catfill(const float* __restrict__ ipts, const float* __restrict__ ivw,
                        short* __restrict__ catb)
{
    int idx = blockIdx.x * 256 + threadIdx.x;
    int bs = idx >> 7, c = idx & 127;
    float v;
    if (c < 63)      v = ipts[bs * 63 + c];
    else if (c < 90) v = ivw[(bs >> 6) * 27 + (c - 63)];
    else             v = 0.f;
    catb[(size_t)bs * 384 + 256 + c] = f2b(v);
}

// view-max only (LN now fused into layer-0 qw via gemm_lnin)
__global__ __launch_bounds__(256) void vmax(
    const short* __restrict__ rgbf, float* __restrict__ fq)
{
    int idx = blockIdx.x * 256 + threadIdx.x;
    int bs = idx >> 8, t = idx & 255;
    float m = -1e30f;
    for (int v = 0; v < VV; v++) m = fmaxf(m, b2f(rgbf[((size_t)(bs * VV + v)) * 256 + t]));
    fq[idx] = m;
}

// ---------------------------------------------------------------------------
// MFMA self-attention: one wave per (b,h). QKV packed bf16 [4096,768].
// ---------------------------------------------------------------------------
__global__ __launch_bounds__(64) void attn_mfma(
    const short* __restrict__ QKV, short* __restrict__ O)
{
    __shared__ __align__(16) short P[64 * 72];
    __shared__ __align__(16) short Vt[64 * 72];
    int blk = blockIdx.x;
    int b = blk >> 2, h = blk & 3, lane = threadIdx.x;
    int lm = lane & 15, lq = lane >> 4;
    const short* base = QKV + (size_t)b * 64 * 768 + h * 64;
    {
        const short* vrow = base + 512 + (size_t)lane * 768;
#pragma unroll
        for (int c = 0; c < 8; c++) {
            s8v v = *(const s8v*)&vrow[c * 8];
#pragma unroll
            for (int j = 0; j < 8; j++)
                Vt[(c * 8 + j) * 72 + lane] = v[j];
        }
    }
    s8v qfr[4][2], kf[4][2];
#pragma unroll
    for (int i = 0; i < 4; i++)
#pragma unroll
        for (int c = 0; c < 2; c++) {
            qfr[i][c] = *(const s8v*)&base[(size_t)(i * 16 + lm) * 768 + c * 32 + lq * 8];
            kf[i][c]  = *(const s8v*)&base[(size_t)(i * 16 + lm) * 768 + 256 + c * 32 + lq * 8];
        }
    f4v acc[4][4];
#pragma unroll
    for (int i = 0; i < 4; i++)
#pragma unroll
        for (int j = 0; j < 4; j++) acc[i][j] = (f4v){0.f, 0.f, 0.f, 0.f};
#pragma unroll
    for (int c = 0; c < 2; c++)
#pragma unroll
        for (int i = 0; i < 4; i++)
#pragma unroll
            for (int j = 0; j < 4; j++)
                acc[i][j] = __builtin_amdgcn_mfma_f32_16x16x32_bf16(qfr[i][c], kf[j][c], acc[i][j], 0, 0, 0);
#pragma unroll
    for (int i = 0; i < 4; i++) {
#pragma unroll
        for (int r = 0; r < 4; r++) {
            float lv[4];
#pragma unroll
            for (int j = 0; j < 4; j++) lv[j] = acc[i][j][r] * 0.125f;
            float mx = fmaxf(fmaxf(lv[0], lv[1]), fmaxf(lv[2], lv[3]));
            for (int d = 1; d < 16; d <<= 1) mx = fmaxf(mx, __shfl_xor(mx, d));
            float sum = 0.f;
#pragma unroll
            for (int j = 0; j < 4; j++) { lv[j] = expf(lv[j] - mx); sum += lv[j]; }
            for (int d = 1; d < 16; d <<= 1) sum += __shfl_xor(sum, d);
            float inv = 1.f / sum;
            int row = i * 16 + lq * 4 + r;
#pragma unroll
            for (int j = 0; j < 4; j++)
                P[row * 72 + j * 16 + lm] = f2b(lv[j] * inv);
        }
    }
    __syncthreads();
    s8v af[4][2], bf[4][2];
#pragma unroll
    for (int i = 0; i < 4; i++)
#pragma unroll
        for (int c = 0; c < 2; c++) {
            af[i][c] = *(const s8v*)&P[(i * 16 + lm) * 72 + c * 32 + lq * 8];
            bf[i][c] = *(const s8v*)&Vt[(i * 16 + lm) * 72 + c * 32 + lq * 8];
        }
    f4v o2[4][4];
#pragma unroll
    for (int i = 0; i < 4; i++)
#pragma unroll
        for (int j = 0; j < 4; j++) o2[i][j] = (f4v){0.f, 0.f, 0.f, 0.f};
#pragma unroll
    for (int c = 0; c < 2; c++)
#pragma unroll
        for (int i = 0; i < 4; i++)
#pragma unroll
            for (int j = 0; j < 4; j++)
                o2[i][j] = __builtin_amdgcn_mfma_f32_16x16x32_bf16(af[i][c], bf[j][c], o2[i][j], 0, 0, 0);
#pragma unroll
    for (int i = 0; i < 4; i++)
#pragma unroll
        for (int j = 0; j < 4; j++)
#pragma unroll
            for (int r = 0; r < 4; r++) {
                int s = i * 16 + lq * 4 + r, d = j * 16 + lm;
                O[(size_t)(b * 64 + s) * 256 + h * 64 + d] = f2b(o2[i][j][r]);
            }
}

// final head: mean over S (bf16 in) then [256]x[256,3] matvec + bias (fp32)
__global__ __launch_bounds__(256) void headk(
    const short* __restrict__ h, const float* __restrict__ ow,
    const float* __restrict__ ob, float* __restrict__ out)
{
    int b = blockIdx.x, t = threadIdx.x;
    float acc = 0.f;
    for (int s = 0; s < SS; s++) acc += b2f(h[((size_t)(b * SS + s)) * WW + t]);
    __shared__ float mean[256];
    mean[t] = acc * (1.f / 64.f);
    __syncthreads();
    if (t < 3) {
        float o = ob[t];
        for (int w = 0; w < WW; w++) o += mean[w] * ow[w * 3 + t];
        out[b * 3 + t] = o;
    }
}

// ---------------------------------------------------------------------------
#define GEMM_BF(TMv,TNv,WMv,WNv, A,Bt,bias,C,M,N,K,ldc,relu) \
  gemm_mfma<TMv,TNv,WMv,WNv,true><<<dim3((N)/(TNv),(M)/(TMv)),256,0,stream>>>((A),(Bt),(bias),nullptr,nullptr,(C),nullptr,(M),(N),(K),(ldc),0,(relu))
#define GEMM_F(TMv,TNv,WMv,WNv, A,Bt,bias,res,C,M,N,K,relu) \
  gemm_mfma<TMv,TNv,WMv,WNv,false><<<dim3((N)/(TNv),(M)/(TMv)),256,0,stream>>>((A),(Bt),(bias),(res),(C),nullptr,nullptr,(M),(N),(K),(N),0,(relu))
#define GEMM_F2(TMv,TNv,WMv,WNv, A,Bt,bias,res,C,C2,ldc2,M,N,K,relu) \
  gemm_mfma<TMv,TNv,WMv,WNv,false><<<dim3((N)/(TNv),(M)/(TMv)),256,0,stream>>>((A),(Bt),(bias),(res),(C),nullptr,(C2),(M),(N),(K),(N),(ldc2),(relu))
// LN-input GEMMs (K=256, TM=64): bf16 out / fp32 out
#define GEMM_LNB(TNv,WMv,WNv, A,Bt,g,b,eps,bias,C,N,ldc,relu) \
  gemm_lnin<TNv,WMv,WNv,true><<<dim3((N)/(TNv),BS/64),256,0,stream>>>((A),(Bt),(g),(b),(eps),(bias),nullptr,(C),(ldc),(relu))
#define GEMM_LNF(TNv,WMv,WNv, A,Bt,g,b,eps,bias,C,N,ldc,relu) \
  gemm_lnin<TNv,WMv,WNv,false><<<dim3((N)/(TNv),BS/64),256,0,stream>>>((A),(Bt),(g),(b),(eps),(bias),(C),nullptr,(ldc),(relu))

extern "C" void kernel_launch(void* const* d_in, const int* in_sizes, int n_in,
                              void* d_out, int out_size, void* d_ws, size_t ws_size,
                              hipStream_t stream)
{
    const float* rgb_feat   = (const float*)d_in[0];
    const float* ray_diff   = (const float*)d_in[1];
    const int*   maskp      = (const int*)d_in[2];
    const float* pts        = (const float*)d_in[3];
    const float* ray_d      = (const float*)d_in[4];
    const float* rgbfeat_w1 = (const float*)d_in[5];
    const float* rgbfeat_b1 = (const float*)d_in[6];
    const float* rgbfeat_w2 = (const float*)d_in[7];
    const float* rgbfeat_b2 = (const float*)d_in[8];
    const float* c_ln_g = (const float*)d_in[9];
    const float* c_ln_b = (const float*)d_in[10];
    const float* c_qw   = (const float*)d_in[11];
    const float* c_kw   = (const float*)d_in[12];
    const float* c_vw   = (const float*)d_in[13];
    const float* c_pw1  = (const float*)d_in[14];
    const float* c_pb1  = (const float*)d_in[15];
    const float* c_pw2  = (const float*)d_in[16];
    const float* c_pb2  = (const float*)d_in[17];
    const float* c_aw1  = (const float*)d_in[18];
    const float* c_ab1  = (const float*)d_in[19];
    const float* c_aw2  = (const float*)d_in[20];
    const float* c_ab2  = (const float*)d_in[21];
    const float* c_ow   = (const float*)d_in[22];
    const float* c_ob   = (const float*)d_in[23];
    const float* c_fg   = (const float*)d_in[24];
    const float* c_fb   = (const float*)d_in[25];
    const float* c_fw1  = (const float*)d_in[26];
    const float* c_fb1  = (const float*)d_in[27];
    const float* c_fw2  = (const float*)d_in[28];
    const float* c_fb2  = (const float*)d_in[29];
    const float* s_ln_g = (const float*)d_in[30];
    const float* s_ln_b = (const float*)d_in[31];
    const float* s_qw   = (const float*)d_in[32];
    const float* s_kw   = (const float*)d_in[33];
    const float* s_vw   = (const float*)d_in[34];
    const float* s_ow   = (const float*)d_in[35];
    const float* s_ob   = (const float*)d_in[36];
    const float* s_fg   = (const float*)d_in[37];
    const float* s_fb   = (const float*)d_in[38];
    const float* s_fw1  = (const float*)d_in[39];
    const float* s_fb1  = (const float*)d_in[40];
    const float* s_fw2  = (const float*)d_in[41];
    const float* s_fb2  = (const float*)d_in[42];
    const float* q_w1   = (const float*)d_in[43];
    const float* q_b1   = (const float*)d_in[44];
    const float* q_w2   = (const float*)d_in[45];
    const float* q_b2   = (const float*)d_in[46];
    const float* norm_g = (const float*)d_in[47];
    const float* norm_b = (const float*)d_in[48];
    const float* out_w  = (const float*)d_in[49];
    const float* out_b  = (const float*)d_in[50];
    float* out = (float*)d_out;

    // ---- workspace carve (256B aligned) ----
    char* p = (char*)d_ws;
    auto alloc = [&](size_t bytes) { char* r = p; p += (bytes + 255) & ~(size_t)255; return r; };
    short* rgbf  = (short*)alloc((size_t)BSV * 256 * 2);
    short* hall  = (short*)alloc((size_t)DD * BSV * 32 * 2);
    short* kvall = (short*)alloc((size_t)4 * BSV * 512 * 2);
    short* a_in  = (short*)alloc((size_t)BSV * 256 * 2);
    short* obb   = (short*)alloc((size_t)BS * 256 * 2);
    short* hb    = (short*)alloc((size_t)BS * 256 * 2);
    short* ffh   = (short*)alloc((size_t)BS * 1024 * 2);
    short* catb  = (short*)alloc((size_t)BS * 384 * 2);
    short* qkv   = (short*)alloc((size_t)BS * 768 * 2);
    short* rgbp  = qkv;
    float* qf    = (float*)alloc((size_t)BS * 256 * 4);
    float* fq    = (float*)alloc((size_t)BS * 256 * 4);
    float* ipts  = (float*)alloc((size_t)BS * 63 * 4);
    float* ivw   = (float*)alloc((size_t)BB * 27 * 4);
    // weights (bf16, transposed [N,Kpad])
    short* w1T   = (short*)alloc(256 * 64 * 2);
    short* w2T   = (short*)alloc(256 * 256 * 2);
    short* qwT   = (short*)alloc((size_t)DD * 256 * 256 * 2);
    short* kvpT  = (short*)alloc((size_t)DD * 512 * 288 * 2);
    short* aw1T  = (short*)alloc((size_t)DD * 32 * 256 * 2);
    short* aw2T  = (short*)alloc((size_t)DD * 256 * 32 * 2);
    short* owT   = (short*)alloc((size_t)DD * 256 * 256 * 2);
    short* fw1T  = (short*)alloc((size_t)DD * 1024 * 256 * 2);
    short* fw2T  = (short*)alloc((size_t)DD * 256 * 1024 * 2);
    short* sqkvT = (short*)alloc((size_t)DD * 768 * 256 * 2);
    short* sowT  = (short*)alloc((size_t)DD * 256 * 256 * 2);
    short* sfw1T = (short*)alloc((size_t)DD * 1024 * 256 * 2);
    short* sfw2T = (short*)alloc((size_t)DD * 256 * 1024 * 2);
    short* qw1T  = (short*)alloc((size_t)4 * 256 * 384 * 2);
    short* qw2T  = (short*)alloc((size_t)4 * 256 * 256 * 2);

    // ---- weight conversion ----
    dim3 wb(32, 8);
    wconv<<<dim3(8, 2, 1), wb, 0, stream>>>(rgbfeat_w1, w1T, 35, 256, 64, 0, 0);
    wconv<<<dim3(8, 8, 1), wb, 0, stream>>>(rgbfeat_w2, w2T, 256, 256, 256, 0, 0);
    wconv<<<dim3(8, 8, DD), wb, 0, stream>>>(c_qw, qwT, 256, 256, 256, 65536, 65536);
    wconv<<<dim3(8, 8, DD), wb, 0, stream>>>(c_kw, kvpT, 256, 256, 288, 65536, 147456);
    wconv<<<dim3(8, 1, DD), wb, 0, stream>>>(c_pw2, kvpT + 256, 32, 256, 288, 8192, 147456);
    wconv<<<dim3(8, 8, DD), wb, 0, stream>>>(c_vw, kvpT + 256 * 288, 256, 256, 288, 65536, 147456);
    wconv<<<dim3(8, 1, DD), wb, 0, stream>>>(c_pw2, kvpT + 256 * 288 + 256, 32, 256, 288, 8192, 147456);
    wconv<<<dim3(1, 8, DD), wb, 0, stream>>>(c_aw1, aw1T, 256, 32, 256, 8192, 8192);
    wconv<<<dim3(8, 1, DD), wb, 0, stream>>>(c_aw2, aw2T, 32, 256, 32, 8192, 8192);
    wconv<<<dim3(8, 8, DD), wb, 0, stream>>>(c_ow, owT, 256, 256, 256, 65536, 65536);
    wconv<<<dim3(32, 8, DD), wb, 0, stream>>>(c_fw1, fw1T, 256, 1024, 256, 262144, 262144);
    wconv<<<dim3(8, 32, DD), wb, 0, stream>>>(c_fw2, fw2T, 1024, 256, 1024, 262144, 262144);
    wconv<<<dim3(8, 8, DD), wb, 0, stream>>>(s_qw, sqkvT, 256, 256, 256, 65536, 196608);
    wconv<<<dim3(8, 8, DD), wb, 0, stream>>>(s_kw, sqkvT + 65536, 256, 256, 256, 65536, 196608);
    wconv<<<dim3(8, 8, DD), wb, 0, stream>>>(s_vw, sqkvT + 131072, 256, 256, 256, 65536, 196608);
    wconv<<<dim3(8, 8, DD), wb, 0, stream>>>(s_ow, sowT, 256, 256, 256, 65536, 65536);
    wconv<<<dim3(32, 8, DD), wb, 0, stream>>>(s_fw1, sfw1T, 256, 1024, 256, 262144, 262144);
    wconv<<<dim3(8, 32, DD), wb, 0, stream>>>(s_fw2, sfw2T, 1024, 256, 1024, 262144, 262144);
    wconv<<<dim3(8, 12, 4), wb, 0, stream>>>(q_w1, qw1T, 346, 256, 384, 88576, 98304);
    wconv<<<dim3(8, 8, 4), wb, 0, stream>>>(q_w2, qw2T, 256, 256, 256, 65536, 65536);

    // ---- preamble ----
    penc_pts<<<(BS + 255) / 256, 256, 0, stream>>>(pts, ipts);
    penc_views<<<1, 64, 0, stream>>>(ray_d, ivw);
    catfill<<<(BS * 128) / 256, 256, 0, stream>>>(ipts, ivw, catb);
    rgbconv<<<(BSV * 64) / 256, 256, 0, stream>>>(rgb_feat, rgbp);
    hallk<<<(DD * BSV * 32) / 256, 256, 0, stream>>>(ray_diff, c_pw1, c_pb1, hall);
    GEMM_BF(128, 128, 64, 64, rgbp, w1T, rgbfeat_b1, a_in, BSV, 256, 64, 256, 1);
    GEMM_BF(128, 128, 64, 64, a_in, w2T, rgbfeat_b2, rgbf, BSV, 256, 256, 256, 0);
    vmax<<<BS, 256, 0, stream>>>(rgbf, fq);
    kvbatch<<<dim3(4, 4, 256), 256, 0, stream>>>(rgbf, hall, kvpT, kvall, 0);

    for (int i = 0; i < DD; i++) {
        int j = i >> 1;
        if (i == 4)
            kvbatch<<<dim3(4, 4, 256), 256, 0, stream>>>(rgbf, hall, kvpT, kvall, 4);
        // ---- cross transformer ----
        GEMM_LNF(64, 32, 32, fq, qwT + (size_t)i * 65536,
                 c_ln_g + i * WW, c_ln_b + i * WW, 1e-6f, nullptr, qf, 256, 256, 0);
        crossattn<<<BSV / 64, 256, 0, stream>>>(kvall + (size_t)(i & 3) * BSV * 512, qf, maskp,
            aw1T + (size_t)i * 8192, c_ab1 + i * 32,
            aw2T + (size_t)i * 8192, c_ab2 + i * 256, obb);
        GEMM_F(64, 64, 32, 32, obb, owT + (size_t)i * 65536, c_ob + i * 256, fq, fq, BS, 256, 256, 0);
        GEMM_LNB(128, 32, 64, fq, fw1T + (size_t)i * 262144,
                 c_fg + i * WW, c_fb + i * WW, 1e-6f, c_fb1 + i * 1024, ffh, 1024, 1024, 1);
        if ((i & 1) == 0) {
            GEMM_F2(64, 64, 32, 32, ffh, fw2T + (size_t)i * 262144, c_fb2 + i * 256, fq, fq,
                    catb, 384, BS, 256, 1024, 0);
            GEMM_BF(64, 64, 32, 32, catb, qw1T + (size_t)j * 98304, q_b1 + j * 256, hb, BS, 256, 384, 256, 1);
            GEMM_F(64, 64, 32, 32, hb, qw2T + (size_t)j * 65536, q_b2 + j * 256, nullptr, fq, BS, 256, 256, 0);
        } else {
            GEMM_F(64, 64, 32, 32, ffh, fw2T + (size_t)i * 262144, c_fb2 + i * 256, fq, fq, BS, 256, 1024, 0);
        }
        // ---- self transformer ----
        GEMM_LNB(128, 32, 64, fq, sqkvT + (size_t)i * 196608,
                 s_ln_g + i * WW, s_ln_b + i * WW, 1e-6f, nullptr, qkv, 768, 768, 0);
        attn_mfma<<<BB * 4, 64, 0, stream>>>(qkv, obb);
        GEMM_F(64, 64, 32, 32, obb, sowT + (size_t)i * 65536, s_ob + i * 256, fq, fq, BS, 256, 256, 0);
        GEMM_LNB(128, 32, 64, fq, sfw1T + (size_t)i * 262144,
                 s_fg + i * WW, s_fb + i * WW, 1e-6f, s_fb1 + i * 1024, ffh, 1024, 1024, 1);
        GEMM_F(64, 64, 32, 32, ffh, sfw2T + (size_t)i * 262144, s_fb2 + i * 256, fq, fq, BS, 256, 1024, 0);
    }

    // ---- final norm + head ----
    lnormB<<<BS, 256, 0, stream>>>(fq, norm_g, norm_b, hb, 1e-5f);
    headk<<<BB, 256, 0, stream>>>(hb, out_w, out_b, out);
}

// Round 9
// 1817.560 us; speedup vs baseline: 1.0192x; 1.0192x over previous
//
#include <hip/hip_runtime.h>
#include <hip/hip_bf16.h>
#include <math.h>

#define BB 64
#define SS 64
#define VV 8
#define WW 256
#define DD 8
#define BS (BB*SS)        // 4096
#define BSV (BB*SS*VV)    // 32768

typedef __attribute__((ext_vector_type(8))) short s8v;
typedef __attribute__((ext_vector_type(4))) float f4v;

__device__ __forceinline__ short f2b(float f) {
    __hip_bfloat16 h = __float2bfloat16(f);
    return *reinterpret_cast<short*>(&h);
}
__device__ __forceinline__ float b2f(short s) {
    __hip_bfloat16 h = *reinterpret_cast<__hip_bfloat16*>(&s);
    return __bfloat162float(h);
}

// ---------------------------------------------------------------------------
// bf16 MFMA GEMM (BK=32, LDS stride 40): C = act(A@B + bias) (+res)
// A bf16 [M,K]. Bt bf16 [N,K]. Dual output: Cf fp32 (ldc) and optional
// Cb2 bf16 (ldc2); or single bf16 Cb when OUTBF.
// Tile configs: 128x128/64x64 waves (big), 64x64/32x32, 32x64/16x32 (2 blk/CU).
// ---------------------------------------------------------------------------
template<int TM, int TN, int WM, int WN, bool OUTBF>
__global__ __launch_bounds__(256) void gemm_mfma(
    const short* __restrict__ A, const short* __restrict__ Bt,
    const float* __restrict__ bias, const float* __restrict__ res,
    float* __restrict__ Cf, short* __restrict__ Cb, short* __restrict__ Cb2,
    int M, int N, int K, int ldc, int ldc2, int relu)
{
    constexpr int MT  = WM / 16;
    constexpr int NT  = WN / 16;
    constexpr int RWN = TN / WN;
    __shared__ __align__(16) short As[TM * 40];
    __shared__ __align__(16) short Bs[TN * 40];
    int tid = threadIdx.x;
    int m0 = blockIdx.y * TM, n0 = blockIdx.x * TN;
    int lane = tid & 63, w = tid >> 6;
    int lm = lane & 15, lq = lane >> 4;
    int wm = (w / RWN) * WM, wn = (w % RWN) * WN;
    f4v acc[MT][NT];
#pragma unroll
    for (int i = 0; i < MT; i++)
#pragma unroll
        for (int j = 0; j < NT; j++) acc[i][j] = (f4v){0.f, 0.f, 0.f, 0.f};

    for (int k0 = 0; k0 < K; k0 += 32) {
        for (int c = tid; c < TM * 4; c += 256) {
            int r = c >> 2, kc = (c & 3) << 3;
            *(s8v*)&As[r * 40 + kc] = *(const s8v*)&A[(size_t)(m0 + r) * K + k0 + kc];
        }
        for (int c = tid; c < TN * 4; c += 256) {
            int r = c >> 2, kc = (c & 3) << 3;
            *(s8v*)&Bs[r * 40 + kc] = *(const s8v*)&Bt[(size_t)(n0 + r) * K + k0 + kc];
        }
        __syncthreads();
        s8v af[MT], bfv[NT];
#pragma unroll
        for (int i = 0; i < MT; i++)
            af[i] = *(const s8v*)&As[(wm + i * 16 + lm) * 40 + lq * 8];
#pragma unroll
        for (int j = 0; j < NT; j++)
            bfv[j] = *(const s8v*)&Bs[(wn + j * 16 + lm) * 40 + lq * 8];
#pragma unroll
        for (int i = 0; i < MT; i++)
#pragma unroll
            for (int j = 0; j < NT; j++)
                acc[i][j] = __builtin_amdgcn_mfma_f32_16x16x32_bf16(af[i], bfv[j], acc[i][j], 0, 0, 0);
        __syncthreads();
    }
#pragma unroll
    for (int i = 0; i < MT; i++) {
        int row = m0 + wm + i * 16 + lq * 4;
#pragma unroll
        for (int j = 0; j < NT; j++) {
            int col = n0 + wn + j * 16 + lm;
            float bv = bias ? bias[col] : 0.f;
#pragma unroll
            for (int r = 0; r < 4; r++) {
                float v = acc[i][j][r] + bv;
                if (relu) v = fmaxf(v, 0.f);
                size_t idx = (size_t)(row + r) * ldc + col;
                if (OUTBF) {
                    Cb[idx] = f2b(v);
                } else {
                    if (res) v += res[idx];
                    Cf[idx] = v;
                    if (Cb2) Cb2[(size_t)(row + r) * ldc2 + col] = f2b(v);
                }
            }
        }
    }
}

// ---------------------------------------------------------------------------
// Batched kv GEMM for 4 layers (grid n=4, z=4, m=256 for rgbf L2 locality)
// ---------------------------------------------------------------------------
__global__ __launch_bounds__(256) void kvbatch(
    const short* __restrict__ rgbf, const short* __restrict__ hall,
    const short* __restrict__ kvpT, short* __restrict__ kvall, int base)
{
    __shared__ __align__(16) short As[128 * 72];
    __shared__ __align__(16) short Bs[128 * 72];
    int z = blockIdx.y, layer = base + z;
    const short* H  = hall + (size_t)layer * BSV * 32;
    const short* Bt = kvpT + (size_t)layer * 512 * 288;
    short* C = kvall + (size_t)z * BSV * 512;
    int tid = threadIdx.x;
    int m0 = blockIdx.z * 128, n0 = blockIdx.x * 128;
    int lane = tid & 63, w = tid >> 6;
    int lm = lane & 15, lq = lane >> 4;
    int wm = (w >> 1) * 64, wn = (w & 1) * 64;
    f4v acc[4][4];
#pragma unroll
    for (int i = 0; i < 4; i++)
#pragma unroll
        for (int j = 0; j < 4; j++) acc[i][j] = (f4v){0.f, 0.f, 0.f, 0.f};

    for (int k0 = 0; k0 < 256; k0 += 64) {
#pragma unroll
        for (int c = 0; c < 4; c++) {
            int e = tid + c * 256;
            int r = e >> 3, kc = (e & 7) << 3;
            *(s8v*)&As[r * 72 + kc] = *(const s8v*)&rgbf[(size_t)(m0 + r) * 256 + k0 + kc];
            *(s8v*)&Bs[r * 72 + kc] = *(const s8v*)&Bt[(size_t)(n0 + r) * 288 + k0 + kc];
        }
        __syncthreads();
#pragma unroll
        for (int cc = 0; cc < 2; cc++) {
            s8v af[4], bfv[4];
#pragma unroll
            for (int i = 0; i < 4; i++)
                af[i] = *(const s8v*)&As[(wm + i * 16 + lm) * 72 + cc * 32 + lq * 8];
#pragma unroll
            for (int j = 0; j < 4; j++)
                bfv[j] = *(const s8v*)&Bs[(wn + j * 16 + lm) * 72 + cc * 32 + lq * 8];
#pragma unroll
            for (int i = 0; i < 4; i++)
#pragma unroll
                for (int j = 0; j < 4; j++)
                    acc[i][j] = __builtin_amdgcn_mfma_f32_16x16x32_bf16(af[i], bfv[j], acc[i][j], 0, 0, 0);
        }
        __syncthreads();
    }
#pragma unroll
    for (int c = 0; c < 2; c++) {
        int e = tid + c * 256;
        int r = e >> 2, kc = (e & 3) << 3;
        *(s8v*)&As[r * 72 + kc] = *(const s8v*)&H[(size_t)(m0 + r) * 32 + kc];
        *(s8v*)&Bs[r * 72 + kc] = *(const s8v*)&Bt[(size_t)(n0 + r) * 288 + 256 + kc];
    }
    __syncthreads();
    {
        s8v af[4], bfv[4];
#pragma unroll
        for (int i = 0; i < 4; i++)
            af[i] = *(const s8v*)&As[(wm + i * 16 + lm) * 72 + lq * 8];
#pragma unroll
        for (int j = 0; j < 4; j++)
            bfv[j] = *(const s8v*)&Bs[(wn + j * 16 + lm) * 72 + lq * 8];
#pragma unroll
        for (int i = 0; i < 4; i++)
#pragma unroll
            for (int j = 0; j < 4; j++)
                acc[i][j] = __builtin_amdgcn_mfma_f32_16x16x32_bf16(af[i], bfv[j], acc[i][j], 0, 0, 0);
    }
#pragma unroll
    for (int i = 0; i < 4; i++) {
        int row = m0 + wm + i * 16 + lq * 4;
#pragma unroll
        for (int j = 0; j < 4; j++) {
            int col = n0 + wn + j * 16 + lm;
#pragma unroll
            for (int r = 0; r < 4; r++)
                C[(size_t)(row + r) * 512 + col] = f2b(acc[i][j][r]);
        }
    }
}

// hall[l][row][t] = relu(ray_diff[row] @ pw1[l] + pb1[l])  (all 8 layers)
__global__ void hallk(const float* __restrict__ rdiff, const float* __restrict__ pw1,
                      const float* __restrict__ pb1, short* __restrict__ hall)
{
    int idx = blockIdx.x * 256 + threadIdx.x;
    int t = idx & 31, row = (idx >> 5) & (BSV - 1), l = idx >> 20;
    float a = pb1[l * 32 + t];
    for (int c = 0; c < 4; c++) a += rdiff[row * 4 + c] * pw1[l * 128 + c * 32 + t];
    hall[idx] = f2b(fmaxf(a, 0.f));
}

// ---------------------------------------------------------------------------
// Fused cross-attention: per block = 8 samples (64 kv rows).
// ---------------------------------------------------------------------------
__global__ __launch_bounds__(256) void crossattn(
    const short* __restrict__ kv, const float* __restrict__ qf,
    const int* __restrict__ mask,
    const short* __restrict__ aw1T, const float* __restrict__ ab1,
    const short* __restrict__ aw2T, const float* __restrict__ ab2,
    short* __restrict__ obb)
{
    __shared__ __align__(16) short a_s[64 * 264];
    __shared__ __align__(16) short w_s[256 * 40];
    __shared__ __align__(16) short ph_s[64 * 40];
    __shared__ int msk[64];
    int blk = blockIdx.x, tid = threadIdx.x;
    int row0 = blk * 64, bs0 = blk * 8;
    int lane = tid & 63, w = tid >> 6, lm = lane & 15, lq = lane >> 4;
    if (tid < 64) msk[tid] = mask[bs0 * 8 + tid];
#pragma unroll
    for (int i = 0; i < 8; i++) {
        int e = tid + i * 256;
        int r = e >> 5, col = (e & 31) << 3;
        s8v kk = *(const s8v*)&kv[(size_t)(row0 + r) * 512 + col];
        const float* qp = &qf[(size_t)(bs0 + (r >> 3)) * 256 + col];
        s8v o;
#pragma unroll
        for (int j = 0; j < 8; j++) o[j] = f2b(b2f(kk[j]) - qp[j]);
        *(s8v*)&a_s[r * 264 + col] = o;
    }
#pragma unroll
    for (int i = 0; i < 4; i++) {
        int e = tid + i * 256;
        int r = e >> 5, col = (e & 31) << 3;
        *(s8v*)&w_s[r * 264 + col] = *(const s8v*)&aw1T[r * 256 + col];
    }
    __syncthreads();
    f4v a2[2];
    a2[0] = (f4v){0.f, 0.f, 0.f, 0.f}; a2[1] = (f4v){0.f, 0.f, 0.f, 0.f};
#pragma unroll
    for (int c = 0; c < 8; c++) {
        s8v af = *(const s8v*)&a_s[(w * 16 + lm) * 264 + c * 32 + lq * 8];
#pragma unroll
        for (int j = 0; j < 2; j++) {
            s8v bf = *(const s8v*)&w_s[(j * 16 + lm) * 264 + c * 32 + lq * 8];
            a2[j] = __builtin_amdgcn_mfma_f32_16x16x32_bf16(af, bf, a2[j], 0, 0, 0);
        }
    }
#pragma unroll
    for (int j = 0; j < 2; j++) {
        int col = j * 16 + lm;
        float bv = ab1[col];
#pragma unroll
        for (int r = 0; r < 4; r++)
            ph_s[(w * 16 + lq * 4 + r) * 40 + col] = f2b(fmaxf(a2[j][r] + bv, 0.f));
    }
    __syncthreads();
#pragma unroll
    for (int i = 0; i < 4; i++) {
        int e = tid + i * 256;
        int r = e >> 2, col = (e & 3) << 3;
        *(s8v*)&w_s[r * 40 + col] = *(const s8v*)&aw2T[r * 32 + col];
    }
#pragma unroll
    for (int i = 0; i < 8; i++) {
        int e = tid + i * 256;
        int r = e >> 5, col = (e & 31) << 3;
        *(s8v*)&a_s[r * 264 + col] = *(const s8v*)&kv[(size_t)(row0 + r) * 512 + 256 + col];
    }
    __syncthreads();
    s8v pf = *(const s8v*)&ph_s[(w * 16 + lm) * 40 + lq * 8];
    f4v a3[16];
#pragma unroll
    for (int j = 0; j < 16; j++) {
        s8v bf = *(const s8v*)&w_s[(j * 16 + lm) * 40 + lq * 8];
        a3[j] = __builtin_amdgcn_mfma_f32_16x16x32_bf16(pf, bf, (f4v){0.f, 0.f, 0.f, 0.f}, 0, 0, 0);
    }
    int sample = 2 * w + (lq >> 1);
    int mk[4];
#pragma unroll
    for (int r = 0; r < 4; r++) mk[r] = msk[sample * 8 + (lq & 1) * 4 + r];
#pragma unroll
    for (int j = 0; j < 16; j++) {
        int col = j * 16 + lm;
        float bv = ab2[col];
        float vals[4];
#pragma unroll
        for (int r = 0; r < 4; r++) vals[r] = mk[r] ? (a3[j][r] + bv) : -1e9f;
        float mx = fmaxf(fmaxf(vals[0], vals[1]), fmaxf(vals[2], vals[3]));
        mx = fmaxf(mx, __shfl_xor(mx, 16));
        float ev[4], s = 0.f;
#pragma unroll
        for (int r = 0; r < 4; r++) { ev[r] = expf(vals[r] - mx); s += ev[r]; }
        s += __shfl_xor(s, 16);
        float o = 0.f;
#pragma unroll
        for (int r = 0; r < 4; r++)
            o += ev[r] * b2f(a_s[(w * 16 + lq * 4 + r) * 264 + col]);
        o += __shfl_xor(o, 16);
        o /= s;
        if (!(lq & 1)) obb[(size_t)(bs0 + sample) * 256 + col] = f2b(o);
    }
}

// LayerNorm over 256, fp32 in -> bf16 out
__global__ __launch_bounds__(256) void lnormB(
    const float* __restrict__ in, const float* __restrict__ g,
    const float* __restrict__ b, short* __restrict__ out, float eps)
{
    int row = blockIdx.x, t = threadIdx.x;
    float x = in[(size_t)row * WW + t];
    __shared__ float red[256];
    red[t] = x;
    __syncthreads();
    for (int s = 128; s > 0; s >>= 1) { if (t < s) red[t] += red[t + s]; __syncthreads(); }
    float m = red[0] * (1.f / 256.f);
    __syncthreads();
    float d = x - m;
    red[t] = d * d;
    __syncthreads();
    for (int s = 128; s > 0; s >>= 1) { if (t < s) red[t] += red[t + s]; __syncthreads(); }
    float var = red[0] * (1.f / 256.f);
    out[(size_t)row * WW + t] = f2b(d / sqrtf(var + eps) * g[t] + b[t]);
}

// Weight convert+transpose: W fp32 [K,N] -> Wt bf16 [N,Kpad]
__global__ void wconv(const float* __restrict__ W, short* __restrict__ Wt,
                      int K, int N, int Kpad, int zi, size_t zo)
{
    __shared__ float t[32][33];
    int z = blockIdx.z;
    W  += (size_t)z * zi;
    Wt += (size_t)z * zo;
    int n0 = blockIdx.x * 32, k0 = blockIdx.y * 32;
    int tx = threadIdx.x, ty = threadIdx.y;
#pragma unroll
    for (int i = 0; i < 4; i++) {
        int k = k0 + ty + i * 8;
        t[ty + i * 8][tx] = (k < K) ? W[(size_t)k * N + n0 + tx] : 0.f;
    }
    __syncthreads();
#pragma unroll
    for (int i = 0; i < 4; i++) {
        int n = n0 + ty + i * 8;
        Wt[(size_t)n * Kpad + k0 + tx] = f2b(t[tx][ty + i * 8]);
    }
}

// rgb_feat fp32 [32768,35] -> bf16 [32768,64] zero-padded
__global__ void rgbconv(const float* __restrict__ x, short* __restrict__ o)
{
    int idx = blockIdx.x * 256 + threadIdx.x;
    int row = idx >> 6, col = idx & 63;
    o[idx] = f2b(col < 35 ? x[row * 35 + col] : 0.f);
}

__global__ void penc_pts(const float* __restrict__ pts, float* __restrict__ out)
{
    int bs = blockIdx.x * blockDim.x + threadIdx.x;
    if (bs >= BS) return;
    float xs[3] = {pts[bs * 3], pts[bs * 3 + 1], pts[bs * 3 + 2]};
    float* o = out + (size_t)bs * 63;
    o[0] = xs[0]; o[1] = xs[1]; o[2] = xs[2];
    for (int d = 0; d < 3; d++) {
        float f = 1.f;
        for (int k = 0; k < 10; k++) {
            float ang = xs[d] * f;
            o[3 + d * 10 + k]  = sinf(ang);
            o[33 + d * 10 + k] = cosf(ang);
            f *= 2.f;
        }
    }
}

__global__ void penc_views(const float* __restrict__ ray_d, float* __restrict__ out)
{
    int b = threadIdx.x;
    if (b >= BB) return;
    float x = ray_d[b * 3], y = ray_d[b * 3 + 1], z = ray_d[b * 3 + 2];
    float inv = 1.f / sqrtf(x * x + y * y + z * z);
    float v[3] = {x * inv, y * inv, z * inv};
    float* o = out + (size_t)b * 27;
    o[0] = v[0]; o[1] = v[1]; o[2] = v[2];
    for (int d = 0; d < 3; d++) {
        float f = 1.f;
        for (int k = 0; k < 4; k++) {
            float ang = v[d] * f;
            o[3 + d * 4 + k]  = sinf(ang);
            o[15 + d * 4 + k] = cosf(ang);
            f *= 2.f;
        }
    }
}

// static tail of cat buffer: catb[bs][256..383] = [ipts(63) | ivw(27) | 0(38)]
__global__ void catfill(const float* __restrict__ ipts, const float* __restrict__ ivw,
                        short* __restrict__ catb)
{
    int idx = blockIdx.x * 256 + threadIdx.x;
    int bs = idx >> 7, c = idx & 127;
    float v;
    if (c < 63)      v = ipts[bs * 63 + c];
    else if (c < 90) v = ivw[(bs >> 6) * 27 + (c - 63)];
    else             v = 0.f;
    catb[(size_t)bs * 384 + 256 + c] = f2b(v);
}

// view-max + layer-0 LayerNorm fused
__global__ __launch_bounds__(256) void vmaxln(
    const short* __restrict__ rgbf, const float* __restrict__ g,
    const float* __restrict__ b, float* __restrict__ fq, short* __restrict__ xq)
{
    int bs = blockIdx.x, t = threadIdx.x;
    float m = -1e30f;
    for (int v = 0; v < VV; v++) m = fmaxf(m, b2f(rgbf[((size_t)(bs * VV + v)) * 256 + t]));
    fq[(size_t)bs * WW + t] = m;
    __shared__ float red[256];
    red[t] = m;
    __syncthreads();
    for (int s = 128; s > 0; s >>= 1) { if (t < s) red[t] += red[t + s]; __syncthreads(); }
    float mean = red[0] * (1.f / 256.f);
    __syncthreads();
    float d = m - mean;
    red[t] = d * d;
    __syncthreads();
    for (int s = 128; s > 0; s >>= 1) { if (t < s) red[t] += red[t + s]; __syncthreads(); }
    float var = red[0] * (1.f / 256.f);
    xq[(size_t)bs * WW + t] = f2b(d / sqrtf(var + 1e-6f) * g[t] + b[t]);
}

// ---------------------------------------------------------------------------
// MFMA self-attention: one wave per (b,h). QKV packed bf16 [4096,768].
// ---------------------------------------------------------------------------
__global__ __launch_bounds__(64) void attn_mfma(
    const short* __restrict__ QKV, short* __restrict__ O)
{
    __shared__ __align__(16) short P[64 * 72];
    __shared__ __align__(16) short Vt[64 * 72];
    int blk = blockIdx.x;
    int b = blk >> 2, h = blk & 3, lane = threadIdx.x;
    int lm = lane & 15, lq = lane >> 4;
    const short* base = QKV + (size_t)b * 64 * 768 + h * 64;
    {
        const short* vrow = base + 512 + (size_t)lane * 768;
#pragma unroll
        for (int c = 0; c < 8; c++) {
            s8v v = *(const s8v*)&vrow[c * 8];
#pragma unroll
            for (int j = 0; j < 8; j++)
                Vt[(c * 8 + j) * 72 + lane] = v[j];
        }
    }
    s8v qfr[4][2], kf[4][2];
#pragma unroll
    for (int i = 0; i < 4; i++)
#pragma unroll
        for (int c = 0; c < 2; c++) {
            qfr[i][c] = *(const s8v*)&base[(size_t)(i * 16 + lm) * 768 + c * 32 + lq * 8];
            kf[i][c]  = *(const s8v*)&base[(size_t)(i * 16 + lm) * 768 + 256 + c * 32 + lq * 8];
        }
    f4v acc[4][4];
#pragma unroll
    for (int i = 0; i < 4; i++)
#pragma unroll
        for (int j = 0; j < 4; j++) acc[i][j] = (f4v){0.f, 0.f, 0.f, 0.f};
#pragma unroll
    for (int c = 0; c < 2; c++)
#pragma unroll
        for (int i = 0; i < 4; i++)
#pragma unroll
            for (int j = 0; j < 4; j++)
                acc[i][j] = __builtin_amdgcn_mfma_f32_16x16x32_bf16(qfr[i][c], kf[j][c], acc[i][j], 0, 0, 0);
#pragma unroll
    for (int i = 0; i < 4; i++) {
#pragma unroll
        for (int r = 0; r < 4; r++) {
            float lv[4];
#pragma unroll
            for (int j = 0; j < 4; j++) lv[j] = acc[i][j][r] * 0.125f;
            float mx = fmaxf(fmaxf(lv[0], lv[1]), fmaxf(lv[2], lv[3]));
            for (int d = 1; d < 16; d <<= 1) mx = fmaxf(mx, __shfl_xor(mx, d));
            float sum = 0.f;
#pragma unroll
            for (int j = 0; j < 4; j++) { lv[j] = expf(lv[j] - mx); sum += lv[j]; }
            for (int d = 1; d < 16; d <<= 1) sum += __shfl_xor(sum, d);
            float inv = 1.f / sum;
            int row = i * 16 + lq * 4 + r;
#pragma unroll
            for (int j = 0; j < 4; j++)
                P[row * 72 + j * 16 + lm] = f2b(lv[j] * inv);
        }
    }
    __syncthreads();
    s8v af[4][2], bf[4][2];
#pragma unroll
    for (int i = 0; i < 4; i++)
#pragma unroll
        for (int c = 0; c < 2; c++) {
            af[i][c] = *(const s8v*)&P[(i * 16 + lm) * 72 + c * 32 + lq * 8];
            bf[i][c] = *(const s8v*)&Vt[(i * 16 + lm) * 72 + c * 32 + lq * 8];
        }
    f4v o2[4][4];
#pragma unroll
    for (int i = 0; i < 4; i++)
#pragma unroll
        for (int j = 0; j < 4; j++) o2[i][j] = (f4v){0.f, 0.f, 0.f, 0.f};
#pragma unroll
    for (int c = 0; c < 2; c++)
#pragma unroll
        for (int i = 0; i < 4; i++)
#pragma unroll
            for (int j = 0; j < 4; j++)
                o2[i][j] = __builtin_amdgcn_mfma_f32_16x16x32_bf16(af[i][c], bf[j][c], o2[i][j], 0, 0, 0);
#pragma unroll
    for (int i = 0; i < 4; i++)
#pragma unroll
        for (int j = 0; j < 4; j++)
#pragma unroll
            for (int r = 0; r < 4; r++) {
                int s = i * 16 + lq * 4 + r, d = j * 16 + lm;
                O[(size_t)(b * 64 + s) * 256 + h * 64 + d] = f2b(o2[i][j][r]);
            }
}

// final head: mean over S (bf16 in) then [256]x[256,3] matvec + bias (fp32)
__global__ __launch_bounds__(256) void headk(
    const short* __restrict__ h, const float* __restrict__ ow,
    const float* __restrict__ ob, float* __restrict__ out)
{
    int b = blockIdx.x, t = threadIdx.x;
    float acc = 0.f;
    for (int s = 0; s < SS; s++) acc += b2f(h[((size_t)(b * SS + s)) * WW + t]);
    __shared__ float mean[256];
    mean[t] = acc * (1.f / 64.f);
    __syncthreads();
    if (t < 3) {
        float o = ob[t];
        for (int w = 0; w < WW; w++) o += mean[w] * ow[w * 3 + t];
        out[b * 3 + t] = o;
    }
}

// ---------------------------------------------------------------------------
#define GEMM_BF(TMv,TNv,WMv,WNv, A,Bt,bias,C,M,N,K,ldc,relu) \
  gemm_mfma<TMv,TNv,WMv,WNv,true><<<dim3((N)/(TNv),(M)/(TMv)),256,0,stream>>>((A),(Bt),(bias),nullptr,nullptr,(C),nullptr,(M),(N),(K),(ldc),0,(relu))
#define GEMM_F(TMv,TNv,WMv,WNv, A,Bt,bias,res,C,M,N,K,relu) \
  gemm_mfma<TMv,TNv,WMv,WNv,false><<<dim3((N)/(TNv),(M)/(TMv)),256,0,stream>>>((A),(Bt),(bias),(res),(C),nullptr,nullptr,(M),(N),(K),(N),0,(relu))
#define GEMM_F2(TMv,TNv,WMv,WNv, A,Bt,bias,res,C,C2,ldc2,M,N,K,relu) \
  gemm_mfma<TMv,TNv,WMv,WNv,false><<<dim3((N)/(TNv),(M)/(TMv)),256,0,stream>>>((A),(Bt),(bias),(res),(C),nullptr,(C2),(M),(N),(K),(N),(ldc2),(relu))

extern "C" void kernel_launch(void* const* d_in, const int* in_sizes, int n_in,
                              void* d_out, int out_size, void* d_ws, size_t ws_size,
                              hipStream_t stream)
{
    const float* rgb_feat   = (const float*)d_in[0];
    const float* ray_diff   = (const float*)d_in[1];
    const int*   maskp      = (const int*)d_in[2];
    const float* pts        = (const float*)d_in[3];
    const float* ray_d      = (const float*)d_in[4];
    const float* rgbfeat_w1 = (const float*)d_in[5];
    const float* rgbfeat_b1 = (const float*)d_in[6];
    const float* rgbfeat_w2 = (const float*)d_in[7];
    const float* rgbfeat_b2 = (const float*)d_in[8];
    const float* c_ln_g = (const float*)d_in[9];
    const float* c_ln_b = (const float*)d_in[10];
    const float* c_qw   = (const float*)d_in[11];
    const float* c_kw   = (const float*)d_in[12];
    const float* c_vw   = (const float*)d_in[13];
    const float* c_pw1  = (const float*)d_in[14];
    const float* c_pb1  = (const float*)d_in[15];
    const float* c_pw2  = (const float*)d_in[16];
    const float* c_pb2  = (const float*)d_in[17];
    const float* c_aw1  = (const float*)d_in[18];
    const float* c_ab1  = (const float*)d_in[19];
    const float* c_aw2  = (const float*)d_in[20];
    const float* c_ab2  = (const float*)d_in[21];
    const float* c_ow   = (const float*)d_in[22];
    const float* c_ob   = (const float*)d_in[23];
    const float* c_fg   = (const float*)d_in[24];
    const float* c_fb   = (const float*)d_in[25];
    const float* c_fw1  = (const float*)d_in[26];
    const float* c_fb1  = (const float*)d_in[27];
    const float* c_fw2  = (const float*)d_in[28];
    const float* c_fb2  = (const float*)d_in[29];
    const float* s_ln_g = (const float*)d_in[30];
    const float* s_ln_b = (const float*)d_in[31];
    const float* s_qw   = (const float*)d_in[32];
    const float* s_kw   = (const float*)d_in[33];
    const float* s_vw   = (const float*)d_in[34];
    const float* s_ow   = (const float*)d_in[35];
    const float* s_ob   = (const float*)d_in[36];
    const float* s_fg   = (const float*)d_in[37];
    const float* s_fb   = (const float*)d_in[38];
    const float* s_fw1  = (const float*)d_in[39];
    const float* s_fb1  = (const float*)d_in[40];
    const float* s_fw2  = (const float*)d_in[41];
    const float* s_fb2  = (const float*)d_in[42];
    const float* q_w1   = (const float*)d_in[43];
    const float* q_b1   = (const float*)d_in[44];
    const float* q_w2   = (const float*)d_in[45];
    const float* q_b2   = (const float*)d_in[46];
    const float* norm_g = (const float*)d_in[47];
    const float* norm_b = (const float*)d_in[48];
    const float* out_w  = (const float*)d_in[49];
    const float* out_b  = (const float*)d_in[50];
    float* out = (float*)d_out;

    // ---- workspace carve (256B aligned) ----
    char* p = (char*)d_ws;
    auto alloc = [&](size_t bytes) { char* r = p; p += (bytes + 255) & ~(size_t)255; return r; };
    short* rgbf  = (short*)alloc((size_t)BSV * 256 * 2);
    short* hall  = (short*)alloc((size_t)DD * BSV * 32 * 2);
    short* kvall = (short*)alloc((size_t)4 * BSV * 512 * 2);
    short* a_in  = (short*)alloc((size_t)BSV * 256 * 2);
    short* obb   = (short*)alloc((size_t)BS * 256 * 2);
    short* xq    = (short*)alloc((size_t)BS * 256 * 2);
    short* hb    = (short*)alloc((size_t)BS * 256 * 2);
    short* ffh   = (short*)alloc((size_t)BS * 1024 * 2);
    short* catb  = (short*)alloc((size_t)BS * 384 * 2);
    short* qkv   = (short*)alloc((size_t)BS * 768 * 2);
    short* rgbp  = qkv;
    float* qf    = (float*)alloc((size_t)BS * 256 * 4);
    float* fq    = (float*)alloc((size_t)BS * 256 * 4);
    float* ipts  = (float*)alloc((size_t)BS * 63 * 4);
    float* ivw   = (float*)alloc((size_t)BB * 27 * 4);
    // weights (bf16, transposed [N,Kpad])
    short* w1T   = (short*)alloc(256 * 64 * 2);
    short* w2T   = (short*)alloc(256 * 256 * 2);
    short* qwT   = (short*)alloc((size_t)DD * 256 * 256 * 2);
    short* kvpT  = (short*)alloc((size_t)DD * 512 * 288 * 2);
    short* aw1T  = (short*)alloc((size_t)DD * 32 * 256 * 2);
    short* aw2T  = (short*)alloc((size_t)DD * 256 * 32 * 2);
    short* owT   = (short*)alloc((size_t)DD * 256 * 256 * 2);
    short* fw1T  = (short*)alloc((size_t)DD * 1024 * 256 * 2);
    short* fw2T  = (short*)alloc((size_t)DD * 256 * 1024 * 2);
    short* sqkvT = (short*)alloc((size_t)DD * 768 * 256 * 2);
    short* sowT  = (short*)alloc((size_t)DD * 256 * 256 * 2);
    short* sfw1T = (short*)alloc((size_t)DD * 1024 * 256 * 2);
    short* sfw2T = (short*)alloc((size_t)DD * 256 * 1024 * 2);
    short* qw1T  = (short*)alloc((size_t)4 * 256 * 384 * 2);
    short* qw2T  = (short*)alloc((size_t)4 * 256 * 256 * 2);

    // ---- weight conversion ----
    dim3 wb(32, 8);
    wconv<<<dim3(8, 2, 1), wb, 0, stream>>>(rgbfeat_w1, w1T, 35, 256, 64, 0, 0);
    wconv<<<dim3(8, 8, 1), wb, 0, stream>>>(rgbfeat_w2, w2T, 256, 256, 256, 0, 0);
    wconv<<<dim3(8, 8, DD), wb, 0, stream>>>(c_qw, qwT, 256, 256, 256, 65536, 65536);
    wconv<<<dim3(8, 8, DD), wb, 0, stream>>>(c_kw, kvpT, 256, 256, 288, 65536, 147456);
    wconv<<<dim3(8, 1, DD), wb, 0, stream>>>(c_pw2, kvpT + 256, 32, 256, 288, 8192, 147456);
    wconv<<<dim3(8, 8, DD), wb, 0, stream>>>(c_vw, kvpT + 256 * 288, 256, 256, 288, 65536, 147456);
    wconv<<<dim3(8, 1, DD), wb, 0, stream>>>(c_pw2, kvpT + 256 * 288 + 256, 32, 256, 288, 8192, 147456);
    wconv<<<dim3(1, 8, DD), wb, 0, stream>>>(c_aw1, aw1T, 256, 32, 256, 8192, 8192);
    wconv<<<dim3(8, 1, DD), wb, 0, stream>>>(c_aw2, aw2T, 32, 256, 32, 8192, 8192);
    wconv<<<dim3(8, 8, DD), wb, 0, stream>>>(c_ow, owT, 256, 256, 256, 65536, 65536);
    wconv<<<dim3(32, 8, DD), wb, 0, stream>>>(c_fw1, fw1T, 256, 1024, 256, 262144, 262144);
    wconv<<<dim3(8, 32, DD), wb, 0, stream>>>(c_fw2, fw2T, 1024, 256, 1024, 262144, 262144);
    wconv<<<dim3(8, 8, DD), wb, 0, stream>>>(s_qw, sqkvT, 256, 256, 256, 65536, 196608);
    wconv<<<dim3(8, 8, DD), wb, 0, stream>>>(s_kw, sqkvT + 65536, 256, 256, 256, 65536, 196608);
    wconv<<<dim3(8, 8, DD), wb, 0, stream>>>(s_vw, sqkvT + 131072, 256, 256, 256, 65536, 196608);
    wconv<<<dim3(8, 8, DD), wb, 0, stream>>>(s_ow, sowT, 256, 256, 256, 65536, 65536);
    wconv<<<dim3(32, 8, DD), wb, 0, stream>>>(s_fw1, sfw1T, 256, 1024, 256, 262144, 262144);
    wconv<<<dim3(8, 32, DD), wb, 0, stream>>>(s_fw2, sfw2T, 1024, 256, 1024, 262144, 262144);
    wconv<<<dim3(8, 12, 4), wb, 0, stream>>>(q_w1, qw1T, 346, 256, 384, 88576, 98304);
    wconv<<<dim3(8, 8, 4), wb, 0, stream>>>(q_w2, qw2T, 256, 256, 256, 65536, 65536);

    // ---- preamble ----
    penc_pts<<<(BS + 255) / 256, 256, 0, stream>>>(pts, ipts);
    penc_views<<<1, 64, 0, stream>>>(ray_d, ivw);
    catfill<<<(BS * 128) / 256, 256, 0, stream>>>(ipts, ivw, catb);
    rgbconv<<<(BSV * 64) / 256, 256, 0, stream>>>(rgb_feat, rgbp);
    hallk<<<(DD * BSV * 32) / 256, 256, 0, stream>>>(ray_diff, c_pw1, c_pb1, hall);
    GEMM_BF(128, 128, 64, 64, rgbp, w1T, rgbfeat_b1, a_in, BSV, 256, 64, 256, 1);
    GEMM_BF(128, 128, 64, 64, a_in, w2T, rgbfeat_b2, rgbf, BSV, 256, 256, 256, 0);
    vmaxln<<<BS, 256, 0, stream>>>(rgbf, c_ln_g, c_ln_b, fq, xq);
    kvbatch<<<dim3(4, 4, 256), 256, 0, stream>>>(rgbf, hall, kvpT, kvall, 0);

    for (int i = 0; i < DD; i++) {
        int j = i >> 1;
        if (i == 4)
            kvbatch<<<dim3(4, 4, 256), 256, 0, stream>>>(rgbf, hall, kvpT, kvall, 4);
        // ---- cross transformer ----
        if (i > 0)
            lnormB<<<BS, 256, 0, stream>>>(fq, c_ln_g + i * WW, c_ln_b + i * WW, xq, 1e-6f);
        GEMM_F(32, 64, 16, 32, xq, qwT + (size_t)i * 65536, nullptr, nullptr, qf, BS, 256, 256, 0);
        crossattn<<<BSV / 64, 256, 0, stream>>>(kvall + (size_t)(i & 3) * BSV * 512, qf, maskp,
            aw1T + (size_t)i * 8192, c_ab1 + i * 32,
            aw2T + (size_t)i * 8192, c_ab2 + i * 256, obb);
        GEMM_F(32, 64, 16, 32, obb, owT + (size_t)i * 65536, c_ob + i * 256, fq, fq, BS, 256, 256, 0);
        lnormB<<<BS, 256, 0, stream>>>(fq, c_fg + i * WW, c_fb + i * WW, hb, 1e-6f);
        GEMM_BF(64, 128, 32, 64, hb, fw1T + (size_t)i * 262144, c_fb1 + i * 1024, ffh, BS, 1024, 256, 1024, 1);
        if ((i & 1) == 0) {
            GEMM_F2(32, 64, 16, 32, ffh, fw2T + (size_t)i * 262144, c_fb2 + i * 256, fq, fq,
                    catb, 384, BS, 256, 1024, 0);
            GEMM_BF(32, 64, 16, 32, catb, qw1T + (size_t)j * 98304, q_b1 + j * 256, hb, BS, 256, 384, 256, 1);
            GEMM_F(32, 64, 16, 32, hb, qw2T + (size_t)j * 65536, q_b2 + j * 256, nullptr, fq, BS, 256, 256, 0);
        } else {
            GEMM_F(32, 64, 16, 32, ffh, fw2T + (size_t)i * 262144, c_fb2 + i * 256, fq, fq, BS, 256, 1024, 0);
        }
        // ---- self transformer ----
        lnormB<<<BS, 256, 0, stream>>>(fq, s_ln_g + i * WW, s_ln_b + i * WW, xq, 1e-6f);
        GEMM_BF(64, 128, 32, 64, xq, sqkvT + (size_t)i * 196608, nullptr, qkv, BS, 768, 256, 768, 0);
        attn_mfma<<<BB * 4, 64, 0, stream>>>(qkv, obb);
        GEMM_F(32, 64, 16, 32, obb, sowT + (size_t)i * 65536, s_ob + i * 256, fq, fq, BS, 256, 256, 0);
        lnormB<<<BS, 256, 0, stream>>>(fq, s_fg + i * WW, s_fb + i * WW, hb, 1e-6f);
        GEMM_BF(64, 128, 32, 64, hb, sfw1T + (size_t)i * 262144, s_fb1 + i * 1024, ffh, BS, 1024, 256, 1024, 1);
        GEMM_F(32, 64, 16, 32, ffh, sfw2T + (size_t)i * 262144, s_fb2 + i * 256, fq, fq, BS, 256, 1024, 0);
    }

    // ---- final norm + head ----
    lnormB<<<BS, 256, 0, stream>>>(fq, norm_g, norm_b, hb, 1e-5f);
    headk<<<BB, 256, 0, stream>>>(hb, out_w, out_b, out);
}

// Round 10
// 1568.402 us; speedup vs baseline: 1.1811x; 1.1589x over previous
//
#include <hip/hip_runtime.h>
#include <hip/hip_bf16.h>
#include <math.h>

#define BB 64
#define SS 64
#define VV 8
#define WW 256
#define DD 8
#define BS (BB*SS)        // 4096
#define BSV (BB*SS*VV)    // 32768

#define RB 392            // rowbuf stride (shorts): 196 dw % 32 = 4 -> 2-way
#define HBs 1064          // hid stride: 532 dw % 32 = 20 (stride-40 class)
#define TB 264            // tmpb stride

typedef __attribute__((ext_vector_type(8))) short s8v;
typedef __attribute__((ext_vector_type(4))) float f4v;

__device__ __forceinline__ short f2b(float f) {
    __hip_bfloat16 h = __float2bfloat16(f);
    return *reinterpret_cast<short*>(&h);
}
__device__ __forceinline__ float b2f(short s) {
    __hip_bfloat16 h = *reinterpret_cast<__hip_bfloat16*>(&s);
    return __bfloat162float(h);
}

// ---------------------------------------------------------------------------
// One 16x16 output tile over K: A from LDS (16 rows, stride lda), B fragments
// straight from global (Bt row-major [N][K], bG points at tile's first row).
// ---------------------------------------------------------------------------
__device__ __forceinline__ f4v rowgemm(const short* __restrict__ aL, int lda,
                                       const short* __restrict__ bG, int K,
                                       int ksteps, int lm, int lq)
{
    f4v acc = (f4v){0.f, 0.f, 0.f, 0.f};
#pragma unroll 8
    for (int k = 0; k < ksteps; k++) {
        s8v a = *(const s8v*)&aL[lm * lda + k * 32 + lq * 8];
        s8v b = *(const s8v*)&bG[(size_t)lm * K + k * 32 + lq * 8];
        acc = __builtin_amdgcn_mfma_f32_16x16x32_bf16(a, b, acc, 0, 0, 0);
    }
    return acc;
}

// ---------------------------------------------------------------------------
// In-block LayerNorm of 16 rows x 256 cols held in registers v[t][r]
// (col=(w*4+t)*16+lm, row=lq*4+r). Writes LN'd bf16 into rowbuf[, and
// optionally bf16 to global outG]. Uniform barriers inside.
// ---------------------------------------------------------------------------
__device__ __forceinline__ void ln_rows(
    float v[4][4], const float* __restrict__ g, const float* __restrict__ b,
    float eps, short* rowbuf, float* red, int w, int lm, int lq,
    short* __restrict__ outG, int row0)
{
    float ps[4] = {0.f, 0.f, 0.f, 0.f};
#pragma unroll
    for (int t = 0; t < 4; t++)
#pragma unroll
        for (int r = 0; r < 4; r++) ps[r] += v[t][r];
#pragma unroll
    for (int m = 1; m < 16; m <<= 1)
#pragma unroll
        for (int r = 0; r < 4; r++) ps[r] += __shfl_xor(ps[r], m);
    if (lm == 0)
#pragma unroll
        for (int r = 0; r < 4; r++) red[(lq * 4 + r) * 4 + w] = ps[r];
    __syncthreads();
    float mean[4];
#pragma unroll
    for (int r = 0; r < 4; r++) {
        int row = lq * 4 + r;
        mean[r] = (red[row * 4] + red[row * 4 + 1] + red[row * 4 + 2] + red[row * 4 + 3]) * (1.f / 256.f);
    }
    __syncthreads();
    float pq[4] = {0.f, 0.f, 0.f, 0.f};
#pragma unroll
    for (int t = 0; t < 4; t++)
#pragma unroll
        for (int r = 0; r < 4; r++) { float d = v[t][r] - mean[r]; pq[r] += d * d; }
#pragma unroll
    for (int m = 1; m < 16; m <<= 1)
#pragma unroll
        for (int r = 0; r < 4; r++) pq[r] += __shfl_xor(pq[r], m);
    if (lm == 0)
#pragma unroll
        for (int r = 0; r < 4; r++) red[(lq * 4 + r) * 4 + w] = pq[r];
    __syncthreads();
    float inv[4];
#pragma unroll
    for (int r = 0; r < 4; r++) {
        int row = lq * 4 + r;
        float var = (red[row * 4] + red[row * 4 + 1] + red[row * 4 + 2] + red[row * 4 + 3]) * (1.f / 256.f);
        inv[r] = rsqrtf(var + eps);
    }
#pragma unroll
    for (int t = 0; t < 4; t++) {
        int col = (w * 4 + t) * 16 + lm;
        float gc = g[col], bc = b[col];
#pragma unroll
        for (int r = 0; r < 4; r++) {
            float val = (v[t][r] - mean[r]) * inv[r] * gc + bc;
            rowbuf[(lq * 4 + r) * RB + col] = f2b(val);
            if (outG) outG[(size_t)(row0 + lq * 4 + r) * 256 + col] = f2b(val);
        }
    }
    __syncthreads();
}

// ---------------------------------------------------------------------------
// chainA: ow+res -> LN(c_fg) -> fw1 -> fw2+res -> [even: cat->q1->q2]
//         -> write fq -> LN(s_ln) -> sqkv.  Block = 16 rows, grid 256.
// ---------------------------------------------------------------------------
__global__ __launch_bounds__(256) void chainA(
    const short* __restrict__ obb, float* __restrict__ fq,
    const short* __restrict__ catb, short* __restrict__ qkv,
    const short* __restrict__ owT, const float* __restrict__ c_ob,
    const float* __restrict__ c_fg, const float* __restrict__ c_fb,
    const short* __restrict__ fw1T, const float* __restrict__ c_fb1,
    const short* __restrict__ fw2T, const float* __restrict__ c_fb2,
    const short* __restrict__ qw1T, const float* __restrict__ q_b1,
    const short* __restrict__ qw2T, const float* __restrict__ q_b2,
    const float* __restrict__ s_ln_g, const float* __restrict__ s_ln_b,
    const short* __restrict__ sqkvT, int even)
{
    __shared__ __align__(16) short rowbuf[16 * RB];
    __shared__ __align__(16) short hid[16 * HBs];
    __shared__ __align__(16) short tmpb[16 * TB];
    __shared__ float red[64];
    int tid = threadIdx.x, lane = tid & 63, w = tid >> 6;
    int lm = lane & 15, lq = lane >> 4;
    int row0 = blockIdx.x * 16;
    {
        int r = tid >> 4, c = (tid & 15) * 16;
        *(s8v*)&rowbuf[r * RB + c]     = *(const s8v*)&obb[(size_t)(row0 + r) * 256 + c];
        *(s8v*)&rowbuf[r * RB + c + 8] = *(const s8v*)&obb[(size_t)(row0 + r) * 256 + c + 8];
    }
    __syncthreads();
    // S1: ow + bias + residual(fq)
    float fqreg[4][4];
    {
        f4v o[4];
#pragma unroll
        for (int t = 0; t < 4; t++)
            o[t] = rowgemm(rowbuf, RB, owT + (size_t)(w * 4 + t) * 16 * 256, 256, 8, lm, lq);
#pragma unroll
        for (int t = 0; t < 4; t++) {
            int col = (w * 4 + t) * 16 + lm;
            float bb = c_ob[col];
#pragma unroll
            for (int r = 0; r < 4; r++)
                fqreg[t][r] = o[t][r] + bb + fq[(size_t)(row0 + lq * 4 + r) * 256 + col];
        }
    }
    ln_rows(fqreg, c_fg, c_fb, 1e-6f, rowbuf, red, w, lm, lq, nullptr, row0);
    // S2: fw1 -> hid (relu)
#pragma unroll
    for (int t = 0; t < 16; t++) {
        f4v o = rowgemm(rowbuf, RB, fw1T + (size_t)(w * 16 + t) * 16 * 256, 256, 8, lm, lq);
        int col = (w * 16 + t) * 16 + lm;
        float bb = c_fb1[col];
#pragma unroll
        for (int r = 0; r < 4; r++)
            hid[(lq * 4 + r) * HBs + col] = f2b(fmaxf(o[r] + bb, 0.f));
    }
    __syncthreads();
    // S3: fw2 + bias + residual(fqreg)
    {
        f4v o[4];
#pragma unroll
        for (int t = 0; t < 4; t++)
            o[t] = rowgemm(hid, HBs, fw2T + (size_t)(w * 4 + t) * 16 * 1024, 1024, 32, lm, lq);
#pragma unroll
        for (int t = 0; t < 4; t++) {
            int col = (w * 4 + t) * 16 + lm;
            float bb = c_fb2[col];
#pragma unroll
            for (int r = 0; r < 4; r++)
                fqreg[t][r] = o[t][r] + bb + fqreg[t][r];
        }
    }
    if (even) {
        // cat = [bf16(fq_mid) | static tail] in rowbuf (rowbuf free: last read
        // was S2, whose trailing barrier has passed)
#pragma unroll
        for (int t = 0; t < 4; t++) {
            int col = (w * 4 + t) * 16 + lm;
#pragma unroll
            for (int r = 0; r < 4; r++)
                rowbuf[(lq * 4 + r) * RB + col] = f2b(fqreg[t][r]);
        }
        {
            int r = tid >> 4, c = (tid & 15) * 8;
            *(s8v*)&rowbuf[r * RB + 256 + c] = *(const s8v*)&catb[(size_t)(row0 + r) * 384 + 256 + c];
        }
        __syncthreads();
        // q1 (K=384, relu) -> tmpb
#pragma unroll
        for (int t = 0; t < 4; t++) {
            f4v o = rowgemm(rowbuf, RB, qw1T + (size_t)(w * 4 + t) * 16 * 384, 384, 12, lm, lq);
            int col = (w * 4 + t) * 16 + lm;
            float bb = q_b1[col];
#pragma unroll
            for (int r = 0; r < 4; r++)
                tmpb[(lq * 4 + r) * TB + col] = f2b(fmaxf(o[r] + bb, 0.f));
        }
        __syncthreads();
        // q2 (no residual) -> fqreg
        f4v o[4];
#pragma unroll
        for (int t = 0; t < 4; t++)
            o[t] = rowgemm(tmpb, TB, qw2T + (size_t)(w * 4 + t) * 16 * 256, 256, 8, lm, lq);
#pragma unroll
        for (int t = 0; t < 4; t++) {
            int col = (w * 4 + t) * 16 + lm;
            float bb = q_b2[col];
#pragma unroll
            for (int r = 0; r < 4; r++)
                fqreg[t][r] = o[t][r] + bb;
        }
    }
    // write final fq, LN(s_ln) -> rowbuf
#pragma unroll
    for (int t = 0; t < 4; t++) {
        int col = (w * 4 + t) * 16 + lm;
#pragma unroll
        for (int r = 0; r < 4; r++)
            fq[(size_t)(row0 + lq * 4 + r) * 256 + col] = fqreg[t][r];
    }
    ln_rows(fqreg, s_ln_g, s_ln_b, 1e-6f, rowbuf, red, w, lm, lq, nullptr, row0);
    // sqkv (N=768)
#pragma unroll
    for (int t = 0; t < 12; t++) {
        f4v o = rowgemm(rowbuf, RB, sqkvT + (size_t)(w * 12 + t) * 16 * 256, 256, 8, lm, lq);
        int col = (w * 12 + t) * 16 + lm;
#pragma unroll
        for (int r = 0; r < 4; r++)
            qkv[(size_t)(row0 + lq * 4 + r) * 768 + col] = f2b(o[r]);
    }
}

// ---------------------------------------------------------------------------
// chainB: sow+res -> LN(s_fg) -> sfw1 -> sfw2+res -> write fq ->
//         LN(next c_ln | final norm[->hb]) -> qw_next -> qf.
// ---------------------------------------------------------------------------
__global__ __launch_bounds__(256) void chainB(
    const short* __restrict__ obb, float* __restrict__ fq,
    const short* __restrict__ sowT, const float* __restrict__ s_ob,
    const float* __restrict__ s_fg, const float* __restrict__ s_fb,
    const short* __restrict__ sfw1T, const float* __restrict__ s_fb1,
    const short* __restrict__ sfw2T, const float* __restrict__ s_fb2,
    const float* __restrict__ ln2_g, const float* __restrict__ ln2_b, float eps2,
    const short* __restrict__ qwTn, float* __restrict__ qf,
    short* __restrict__ hbG)
{
    __shared__ __align__(16) short rowbuf[16 * RB];
    __shared__ __align__(16) short hid[16 * HBs];
    __shared__ float red[64];
    int tid = threadIdx.x, lane = tid & 63, w = tid >> 6;
    int lm = lane & 15, lq = lane >> 4;
    int row0 = blockIdx.x * 16;
    {
        int r = tid >> 4, c = (tid & 15) * 16;
        *(s8v*)&rowbuf[r * RB + c]     = *(const s8v*)&obb[(size_t)(row0 + r) * 256 + c];
        *(s8v*)&rowbuf[r * RB + c + 8] = *(const s8v*)&obb[(size_t)(row0 + r) * 256 + c + 8];
    }
    __syncthreads();
    float fqreg[4][4];
    {
        f4v o[4];
#pragma unroll
        for (int t = 0; t < 4; t++)
            o[t] = rowgemm(rowbuf, RB, sowT + (size_t)(w * 4 + t) * 16 * 256, 256, 8, lm, lq);
#pragma unroll
        for (int t = 0; t < 4; t++) {
            int col = (w * 4 + t) * 16 + lm;
            float bb = s_ob[col];
#pragma unroll
            for (int r = 0; r < 4; r++)
                fqreg[t][r] = o[t][r] + bb + fq[(size_t)(row0 + lq * 4 + r) * 256 + col];
        }
    }
    ln_rows(fqreg, s_fg, s_fb, 1e-6f, rowbuf, red, w, lm, lq, nullptr, row0);
#pragma unroll
    for (int t = 0; t < 16; t++) {
        f4v o = rowgemm(rowbuf, RB, sfw1T + (size_t)(w * 16 + t) * 16 * 256, 256, 8, lm, lq);
        int col = (w * 16 + t) * 16 + lm;
        float bb = s_fb1[col];
#pragma unroll
        for (int r = 0; r < 4; r++)
            hid[(lq * 4 + r) * HBs + col] = f2b(fmaxf(o[r] + bb, 0.f));
    }
    __syncthreads();
    {
        f4v o[4];
#pragma unroll
        for (int t = 0; t < 4; t++)
            o[t] = rowgemm(hid, HBs, sfw2T + (size_t)(w * 4 + t) * 16 * 1024, 1024, 32, lm, lq);
#pragma unroll
        for (int t = 0; t < 4; t++) {
            int col = (w * 4 + t) * 16 + lm;
            float bb = s_fb2[col];
#pragma unroll
            for (int r = 0; r < 4; r++)
                fqreg[t][r] = o[t][r] + bb + fqreg[t][r];
        }
    }
#pragma unroll
    for (int t = 0; t < 4; t++) {
        int col = (w * 4 + t) * 16 + lm;
#pragma unroll
        for (int r = 0; r < 4; r++)
            fq[(size_t)(row0 + lq * 4 + r) * 256 + col] = fqreg[t][r];
    }
    ln_rows(fqreg, ln2_g, ln2_b, eps2, rowbuf, red, w, lm, lq, hbG, row0);
    if (qwTn) {
#pragma unroll
        for (int t = 0; t < 4; t++) {
            f4v o = rowgemm(rowbuf, RB, qwTn + (size_t)(w * 4 + t) * 16 * 256, 256, 8, lm, lq);
            int col = (w * 4 + t) * 16 + lm;
#pragma unroll
            for (int r = 0; r < 4; r++)
                qf[(size_t)(row0 + lq * 4 + r) * 256 + col] = o[r];
        }
    }
}

// ---------------------------------------------------------------------------
// bf16 MFMA GEMM (BK=32, LDS stride 40) — preamble + layer-0 qw only.
// ---------------------------------------------------------------------------
template<int TM, int TN, int WM, int WN, bool OUTBF>
__global__ __launch_bounds__(256) void gemm_mfma(
    const short* __restrict__ A, const short* __restrict__ Bt,
    const float* __restrict__ bias, const float* __restrict__ res,
    float* __restrict__ Cf, short* __restrict__ Cb,
    int M, int N, int K, int ldc, int relu)
{
    constexpr int MT  = WM / 16;
    constexpr int NT  = WN / 16;
    constexpr int RWN = TN / WN;
    __shared__ __align__(16) short As[TM * 40];
    __shared__ __align__(16) short Bs[TN * 40];
    int tid = threadIdx.x;
    int m0 = blockIdx.y * TM, n0 = blockIdx.x * TN;
    int lane = tid & 63, w = tid >> 6;
    int lm = lane & 15, lq = lane >> 4;
    int wm = (w / RWN) * WM, wn = (w % RWN) * WN;
    f4v acc[MT][NT];
#pragma unroll
    for (int i = 0; i < MT; i++)
#pragma unroll
        for (int j = 0; j < NT; j++) acc[i][j] = (f4v){0.f, 0.f, 0.f, 0.f};

    for (int k0 = 0; k0 < K; k0 += 32) {
        for (int c = tid; c < TM * 4; c += 256) {
            int r = c >> 2, kc = (c & 3) << 3;
            *(s8v*)&As[r * 40 + kc] = *(const s8v*)&A[(size_t)(m0 + r) * K + k0 + kc];
        }
        for (int c = tid; c < TN * 4; c += 256) {
            int r = c >> 2, kc = (c & 3) << 3;
            *(s8v*)&Bs[r * 40 + kc] = *(const s8v*)&Bt[(size_t)(n0 + r) * K + k0 + kc];
        }
        __syncthreads();
        s8v af[MT], bfv[NT];
#pragma unroll
        for (int i = 0; i < MT; i++)
            af[i] = *(const s8v*)&As[(wm + i * 16 + lm) * 40 + lq * 8];
#pragma unroll
        for (int j = 0; j < NT; j++)
            bfv[j] = *(const s8v*)&Bs[(wn + j * 16 + lm) * 40 + lq * 8];
#pragma unroll
        for (int i = 0; i < MT; i++)
#pragma unroll
            for (int j = 0; j < NT; j++)
                acc[i][j] = __builtin_amdgcn_mfma_f32_16x16x32_bf16(af[i], bfv[j], acc[i][j], 0, 0, 0);
        __syncthreads();
    }
#pragma unroll
    for (int i = 0; i < MT; i++) {
        int row = m0 + wm + i * 16 + lq * 4;
#pragma unroll
        for (int j = 0; j < NT; j++) {
            int col = n0 + wn + j * 16 + lm;
            float bv = bias ? bias[col] : 0.f;
#pragma unroll
            for (int r = 0; r < 4; r++) {
                float v = acc[i][j][r] + bv;
                if (relu) v = fmaxf(v, 0.f);
                size_t idx = (size_t)(row + r) * ldc + col;
                if (OUTBF) {
                    Cb[idx] = f2b(v);
                } else {
                    if (res) v += res[idx];
                    Cf[idx] = v;
                }
            }
        }
    }
}

// ---------------------------------------------------------------------------
// Batched kv GEMM for 4 layers (grid n=4, z=4, m=256)
// ---------------------------------------------------------------------------
__global__ __launch_bounds__(256) void kvbatch(
    const short* __restrict__ rgbf, const short* __restrict__ hall,
    const short* __restrict__ kvpT, short* __restrict__ kvall, int base)
{
    __shared__ __align__(16) short As[128 * 72];
    __shared__ __align__(16) short Bs[128 * 72];
    int z = blockIdx.y, layer = base + z;
    const short* H  = hall + (size_t)layer * BSV * 32;
    const short* Bt = kvpT + (size_t)layer * 512 * 288;
    short* C = kvall + (size_t)z * BSV * 512;
    int tid = threadIdx.x;
    int m0 = blockIdx.z * 128, n0 = blockIdx.x * 128;
    int lane = tid & 63, w = tid >> 6;
    int lm = lane & 15, lq = lane >> 4;
    int wm = (w >> 1) * 64, wn = (w & 1) * 64;
    f4v acc[4][4];
#pragma unroll
    for (int i = 0; i < 4; i++)
#pragma unroll
        for (int j = 0; j < 4; j++) acc[i][j] = (f4v){0.f, 0.f, 0.f, 0.f};

    for (int k0 = 0; k0 < 256; k0 += 64) {
#pragma unroll
        for (int c = 0; c < 4; c++) {
            int e = tid + c * 256;
            int r = e >> 3, kc = (e & 7) << 3;
            *(s8v*)&As[r * 72 + kc] = *(const s8v*)&rgbf[(size_t)(m0 + r) * 256 + k0 + kc];
            *(s8v*)&Bs[r * 72 + kc] = *(const s8v*)&Bt[(size_t)(n0 + r) * 288 + k0 + kc];
        }
        __syncthreads();
#pragma unroll
        for (int cc = 0; cc < 2; cc++) {
            s8v af[4], bfv[4];
#pragma unroll
            for (int i = 0; i < 4; i++)
                af[i] = *(const s8v*)&As[(wm + i * 16 + lm) * 72 + cc * 32 + lq * 8];
#pragma unroll
            for (int j = 0; j < 4; j++)
                bfv[j] = *(const s8v*)&Bs[(wn + j * 16 + lm) * 72 + cc * 32 + lq * 8];
#pragma unroll
            for (int i = 0; i < 4; i++)
#pragma unroll
                for (int j = 0; j < 4; j++)
                    acc[i][j] = __builtin_amdgcn_mfma_f32_16x16x32_bf16(af[i], bfv[j], acc[i][j], 0, 0, 0);
        }
        __syncthreads();
    }
#pragma unroll
    for (int c = 0; c < 2; c++) {
        int e = tid + c * 256;
        int r = e >> 2, kc = (e & 3) << 3;
        *(s8v*)&As[r * 72 + kc] = *(const s8v*)&H[(size_t)(m0 + r) * 32 + kc];
        *(s8v*)&Bs[r * 72 + kc] = *(const s8v*)&Bt[(size_t)(n0 + r) * 288 + 256 + kc];
    }
    __syncthreads();
    {
        s8v af[4], bfv[4];
#pragma unroll
        for (int i = 0; i < 4; i++)
            af[i] = *(const s8v*)&As[(wm + i * 16 + lm) * 72 + lq * 8];
#pragma unroll
        for (int j = 0; j < 4; j++)
            bfv[j] = *(const s8v*)&Bs[(wn + j * 16 + lm) * 72 + lq * 8];
#pragma unroll
        for (int i = 0; i < 4; i++)
#pragma unroll
            for (int j = 0; j < 4; j++)
                acc[i][j] = __builtin_amdgcn_mfma_f32_16x16x32_bf16(af[i], bfv[j], acc[i][j], 0, 0, 0);
    }
#pragma unroll
    for (int i = 0; i < 4; i++) {
        int row = m0 + wm + i * 16 + lq * 4;
#pragma unroll
        for (int j = 0; j < 4; j++) {
            int col = n0 + wn + j * 16 + lm;
#pragma unroll
            for (int r = 0; r < 4; r++)
                C[(size_t)(row + r) * 512 + col] = f2b(acc[i][j][r]);
        }
    }
}

__global__ void hallk(const float* __restrict__ rdiff, const float* __restrict__ pw1,
                      const float* __restrict__ pb1, short* __restrict__ hall)
{
    int idx = blockIdx.x * 256 + threadIdx.x;
    int t = idx & 31, row = (idx >> 5) & (BSV - 1), l = idx >> 20;
    float a = pb1[l * 32 + t];
    for (int c = 0; c < 4; c++) a += rdiff[row * 4 + c] * pw1[l * 128 + c * 32 + t];
    hall[idx] = f2b(fmaxf(a, 0.f));
}

// ---------------------------------------------------------------------------
// Fused cross-attention: per block = 8 samples (64 kv rows).
// ---------------------------------------------------------------------------
__global__ __launch_bounds__(256) void crossattn(
    const short* __restrict__ kv, const float* __restrict__ qf,
    const int* __restrict__ mask,
    const short* __restrict__ aw1T, const float* __restrict__ ab1,
    const short* __restrict__ aw2T, const float* __restrict__ ab2,
    short* __restrict__ obb)
{
    __shared__ __align__(16) short a_s[64 * 264];
    __shared__ __align__(16) short w_s[256 * 40];
    __shared__ __align__(16) short ph_s[64 * 40];
    __shared__ int msk[64];
    int blk = blockIdx.x, tid = threadIdx.x;
    int row0 = blk * 64, bs0 = blk * 8;
    int lane = tid & 63, w = tid >> 6, lm = lane & 15, lq = lane >> 4;
    if (tid < 64) msk[tid] = mask[bs0 * 8 + tid];
#pragma unroll
    for (int i = 0; i < 8; i++) {
        int e = tid + i * 256;
        int r = e >> 5, col = (e & 31) << 3;
        s8v kk = *(const s8v*)&kv[(size_t)(row0 + r) * 512 + col];
        const float* qp = &qf[(size_t)(bs0 + (r >> 3)) * 256 + col];
        s8v o;
#pragma unroll
        for (int j = 0; j < 8; j++) o[j] = f2b(b2f(kk[j]) - qp[j]);
        *(s8v*)&a_s[r * 264 + col] = o;
    }
#pragma unroll
    for (int i = 0; i < 4; i++) {
        int e = tid + i * 256;
        int r = e >> 5, col = (e & 31) << 3;
        *(s8v*)&w_s[r * 264 + col] = *(const s8v*)&aw1T[r * 256 + col];
    }
    __syncthreads();
    f4v a2[2];
    a2[0] = (f4v){0.f, 0.f, 0.f, 0.f}; a2[1] = (f4v){0.f, 0.f, 0.f, 0.f};
#pragma unroll
    for (int c = 0; c < 8; c++) {
        s8v af = *(const s8v*)&a_s[(w * 16 + lm) * 264 + c * 32 + lq * 8];
#pragma unroll
        for (int j = 0; j < 2; j++) {
            s8v bf = *(const s8v*)&w_s[(j * 16 + lm) * 264 + c * 32 + lq * 8];
            a2[j] = __builtin_amdgcn_mfma_f32_16x16x32_bf16(af, bf, a2[j], 0, 0, 0);
        }
    }
#pragma unroll
    for (int j = 0; j < 2; j++) {
        int col = j * 16 + lm;
        float bv = ab1[col];
#pragma unroll
        for (int r = 0; r < 4; r++)
            ph_s[(w * 16 + lq * 4 + r) * 40 + col] = f2b(fmaxf(a2[j][r] + bv, 0.f));
    }
    __syncthreads();
#pragma unroll
    for (int i = 0; i < 4; i++) {
        int e = tid + i * 256;
        int r = e >> 2, col = (e & 3) << 3;
        *(s8v*)&w_s[r * 40 + col] = *(const s8v*)&aw2T[r * 32 + col];
    }
#pragma unroll
    for (int i = 0; i < 8; i++) {
        int e = tid + i * 256;
        int r = e >> 5, col = (e & 31) << 3;
        *(s8v*)&a_s[r * 264 + col] = *(const s8v*)&kv[(size_t)(row0 + r) * 512 + 256 + col];
    }
    __syncthreads();
    s8v pf = *(const s8v*)&ph_s[(w * 16 + lm) * 40 + lq * 8];
    f4v a3[16];
#pragma unroll
    for (int j = 0; j < 16; j++) {
        s8v bf = *(const s8v*)&w_s[(j * 16 + lm) * 40 + lq * 8];
        a3[j] = __builtin_amdgcn_mfma_f32_16x16x32_bf16(pf, bf, (f4v){0.f, 0.f, 0.f, 0.f}, 0, 0, 0);
    }
    int sample = 2 * w + (lq >> 1);
    int mk[4];
#pragma unroll
    for (int r = 0; r < 4; r++) mk[r] = msk[sample * 8 + (lq & 1) * 4 + r];
#pragma unroll
    for (int j = 0; j < 16; j++) {
        int col = j * 16 + lm;
        float bv = ab2[col];
        float vals[4];
#pragma unroll
        for (int r = 0; r < 4; r++) vals[r] = mk[r] ? (a3[j][r] + bv) : -1e9f;
        float mx = fmaxf(fmaxf(vals[0], vals[1]), fmaxf(vals[2], vals[3]));
        mx = fmaxf(mx, __shfl_xor(mx, 16));
        float ev[4], s = 0.f;
#pragma unroll
        for (int r = 0; r < 4; r++) { ev[r] = expf(vals[r] - mx); s += ev[r]; }
        s += __shfl_xor(s, 16);
        float o = 0.f;
#pragma unroll
        for (int r = 0; r < 4; r++)
            o += ev[r] * b2f(a_s[(w * 16 + lq * 4 + r) * 264 + col]);
        o += __shfl_xor(o, 16);
        o /= s;
        if (!(lq & 1)) obb[(size_t)(bs0 + sample) * 256 + col] = f2b(o);
    }
}

// Weight convert+transpose: W fp32 [K,N] -> Wt bf16 [N,Kpad]
__global__ void wconv(const float* __restrict__ W, short* __restrict__ Wt,
                      int K, int N, int Kpad, int zi, size_t zo)
{
    __shared__ float t[32][33];
    int z = blockIdx.z;
    W  += (size_t)z * zi;
    Wt += (size_t)z * zo;
    int n0 = blockIdx.x * 32, k0 = blockIdx.y * 32;
    int tx = threadIdx.x, ty = threadIdx.y;
#pragma unroll
    for (int i = 0; i < 4; i++) {
        int k = k0 + ty + i * 8;
        t[ty + i * 8][tx] = (k < K) ? W[(size_t)k * N + n0 + tx] : 0.f;
    }
    __syncthreads();
#pragma unroll
    for (int i = 0; i < 4; i++) {
        int n = n0 + ty + i * 8;
        Wt[(size_t)n * Kpad + k0 + tx] = f2b(t[tx][ty + i * 8]);
    }
}

__global__ void rgbconv(const float* __restrict__ x, short* __restrict__ o)
{
    int idx = blockIdx.x * 256 + threadIdx.x;
    int row = idx >> 6, col = idx & 63;
    o[idx] = f2b(col < 35 ? x[row * 35 + col] : 0.f);
}

__global__ void penc_pts(const float* __restrict__ pts, float* __restrict__ out)
{
    int bs = blockIdx.x * blockDim.x + threadIdx.x;
    if (bs >= BS) return;
    float xs[3] = {pts[bs * 3], pts[bs * 3 + 1], pts[bs * 3 + 2]};
    float* o = out + (size_t)bs * 63;
    o[0] = xs[0]; o[1] = xs[1]; o[2] = xs[2];
    for (int d = 0; d < 3; d++) {
        float f = 1.f;
        for (int k = 0; k < 10; k++) {
            float ang = xs[d] * f;
            o[3 + d * 10 + k]  = sinf(ang);
            o[33 + d * 10 + k] = cosf(ang);
            f *= 2.f;
        }
    }
}

__global__ void penc_views(const float* __restrict__ ray_d, float* __restrict__ out)
{
    int b = threadIdx.x;
    if (b >= BB) return;
    float x = ray_d[b * 3], y = ray_d[b * 3 + 1], z = ray_d[b * 3 + 2];
    float inv = 1.f / sqrtf(x * x + y * y + z * z);
    float v[3] = {x * inv, y * inv, z * inv};
    float* o = out + (size_t)b * 27;
    o[0] = v[0]; o[1] = v[1]; o[2] = v[2];
    for (int d = 0; d < 3; d++) {
        float f = 1.f;
        for (int k = 0; k < 4; k++) {
            float ang = v[d] * f;
            o[3 + d * 4 + k]  = sinf(ang);
            o[15 + d * 4 + k] = cosf(ang);
            f *= 2.f;
        }
    }
}

__global__ void catfill(const float* __restrict__ ipts, const float* __restrict__ ivw,
                        short* __restrict__ catb)
{
    int idx = blockIdx.x * 256 + threadIdx.x;
    int bs = idx >> 7, c = idx & 127;
    float v;
    if (c < 63)      v = ipts[bs * 63 + c];
    else if (c < 90) v = ivw[(bs >> 6) * 27 + (c - 63)];
    else             v = 0.f;
    catb[(size_t)bs * 384 + 256 + c] = f2b(v);
}

__global__ __launch_bounds__(256) void vmaxln(
    const short* __restrict__ rgbf, const float* __restrict__ g,
    const float* __restrict__ b, float* __restrict__ fq, short* __restrict__ xq)
{
    int bs = blockIdx.x, t = threadIdx.x;
    float m = -1e30f;
    for (int v = 0; v < VV; v++) m = fmaxf(m, b2f(rgbf[((size_t)(bs * VV + v)) * 256 + t]));
    fq[(size_t)bs * WW + t] = m;
    __shared__ float red[256];
    red[t] = m;
    __syncthreads();
    for (int s = 128; s > 0; s >>= 1) { if (t < s) red[t] += red[t + s]; __syncthreads(); }
    float mean = red[0] * (1.f / 256.f);
    __syncthreads();
    float d = m - mean;
    red[t] = d * d;
    __syncthreads();
    for (int s = 128; s > 0; s >>= 1) { if (t < s) red[t] += red[t + s]; __syncthreads(); }
    float var = red[0] * (1.f / 256.f);
    xq[(size_t)bs * WW + t] = f2b(d / sqrtf(var + 1e-6f) * g[t] + b[t]);
}

// ---------------------------------------------------------------------------
// MFMA self-attention: one wave per (b,h). QKV packed bf16 [4096,768].
// ---------------------------------------------------------------------------
__global__ __launch_bounds__(64) void attn_mfma(
    const short* __restrict__ QKV, short* __restrict__ O)
{
    __shared__ __align__(16) short P[64 * 72];
    __shared__ __align__(16) short Vt[64 * 72];
    int blk = blockIdx.x;
    int b = blk >> 2, h = blk & 3, lane = threadIdx.x;
    int lm = lane & 15, lq = lane >> 4;
    const short* base = QKV + (size_t)b * 64 * 768 + h * 64;
    {
        const short* vrow = base + 512 + (size_t)lane * 768;
#pragma unroll
        for (int c = 0; c < 8; c++) {
            s8v v = *(const s8v*)&vrow[c * 8];
#pragma unroll
            for (int j = 0; j < 8; j++)
                Vt[(c * 8 + j) * 72 + lane] = v[j];
        }
    }
    s8v qfr[4][2], kf[4][2];
#pragma unroll
    for (int i = 0; i < 4; i++)
#pragma unroll
        for (int c = 0; c < 2; c++) {
            qfr[i][c] = *(const s8v*)&base[(size_t)(i * 16 + lm) * 768 + c * 32 + lq * 8];
            kf[i][c]  = *(const s8v*)&base[(size_t)(i * 16 + lm) * 768 + 256 + c * 32 + lq * 8];
        }
    f4v acc[4][4];
#pragma unroll
    for (int i = 0; i < 4; i++)
#pragma unroll
        for (int j = 0; j < 4; j++) acc[i][j] = (f4v){0.f, 0.f, 0.f, 0.f};
#pragma unroll
    for (int c = 0; c < 2; c++)
#pragma unroll
        for (int i = 0; i < 4; i++)
#pragma unroll
            for (int j = 0; j < 4; j++)
                acc[i][j] = __builtin_amdgcn_mfma_f32_16x16x32_bf16(qfr[i][c], kf[j][c], acc[i][j], 0, 0, 0);
#pragma unroll
    for (int i = 0; i < 4; i++) {
#pragma unroll
        for (int r = 0; r < 4; r++) {
            float lv[4];
#pragma unroll
            for (int j = 0; j < 4; j++) lv[j] = acc[i][j][r] * 0.125f;
            float mx = fmaxf(fmaxf(lv[0], lv[1]), fmaxf(lv[2], lv[3]));
            for (int d = 1; d < 16; d <<= 1) mx = fmaxf(mx, __shfl_xor(mx, d));
            float sum = 0.f;
#pragma unroll
            for (int j = 0; j < 4; j++) { lv[j] = expf(lv[j] - mx); sum += lv[j]; }
            for (int d = 1; d < 16; d <<= 1) sum += __shfl_xor(sum, d);
            float inv = 1.f / sum;
            int row = i * 16 + lq * 4 + r;
#pragma unroll
            for (int j = 0; j < 4; j++)
                P[row * 72 + j * 16 + lm] = f2b(lv[j] * inv);
        }
    }
    __syncthreads();
    s8v af[4][2], bf[4][2];
#pragma unroll
    for (int i = 0; i < 4; i++)
#pragma unroll
        for (int c = 0; c < 2; c++) {
            af[i][c] = *(const s8v*)&P[(i * 16 + lm) * 72 + c * 32 + lq * 8];
            bf[i][c] = *(const s8v*)&Vt[(i * 16 + lm) * 72 + c * 32 + lq * 8];
        }
    f4v o2[4][4];
#pragma unroll
    for (int i = 0; i < 4; i++)
#pragma unroll
        for (int j = 0; j < 4; j++) o2[i][j] = (f4v){0.f, 0.f, 0.f, 0.f};
#pragma unroll
    for (int c = 0; c < 2; c++)
#pragma unroll
        for (int i = 0; i < 4; i++)
#pragma unroll
            for (int j = 0; j < 4; j++)
                o2[i][j] = __builtin_amdgcn_mfma_f32_16x16x32_bf16(af[i][c], bf[j][c], o2[i][j], 0, 0, 0);
#pragma unroll
    for (int i = 0; i < 4; i++)
#pragma unroll
        for (int j = 0; j < 4; j++)
#pragma unroll
            for (int r = 0; r < 4; r++) {
                int s = i * 16 + lq * 4 + r, d = j * 16 + lm;
                O[(size_t)(b * 64 + s) * 256 + h * 64 + d] = f2b(o2[i][j][r]);
            }
}

__global__ __launch_bounds__(256) void headk(
    const short* __restrict__ h, const float* __restrict__ ow,
    const float* __restrict__ ob, float* __restrict__ out)
{
    int b = blockIdx.x, t = threadIdx.x;
    float acc = 0.f;
    for (int s = 0; s < SS; s++) acc += b2f(h[((size_t)(b * SS + s)) * WW + t]);
    __shared__ float mean[256];
    mean[t] = acc * (1.f / 64.f);
    __syncthreads();
    if (t < 3) {
        float o = ob[t];
        for (int w = 0; w < WW; w++) o += mean[w] * ow[w * 3 + t];
        out[b * 3 + t] = o;
    }
}

// ---------------------------------------------------------------------------
#define GEMM_BF(TMv,TNv,WMv,WNv, A,Bt,bias,C,M,N,K,ldc,relu) \
  gemm_mfma<TMv,TNv,WMv,WNv,true><<<dim3((N)/(TNv),(M)/(TMv)),256,0,stream>>>((A),(Bt),(bias),nullptr,nullptr,(C),(M),(N),(K),(ldc),(relu))
#define GEMM_F(TMv,TNv,WMv,WNv, A,Bt,bias,res,C,M,N,K,relu) \
  gemm_mfma<TMv,TNv,WMv,WNv,false><<<dim3((N)/(TNv),(M)/(TMv)),256,0,stream>>>((A),(Bt),(bias),(res),(C),nullptr,(M),(N),(K),(N),(relu))

extern "C" void kernel_launch(void* const* d_in, const int* in_sizes, int n_in,
                              void* d_out, int out_size, void* d_ws, size_t ws_size,
                              hipStream_t stream)
{
    const float* rgb_feat   = (const float*)d_in[0];
    const float* ray_diff   = (const float*)d_in[1];
    const int*   maskp      = (const int*)d_in[2];
    const float* pts        = (const float*)d_in[3];
    const float* ray_d      = (const float*)d_in[4];
    const float* rgbfeat_w1 = (const float*)d_in[5];
    const float* rgbfeat_b1 = (const float*)d_in[6];
    const float* rgbfeat_w2 = (const float*)d_in[7];
    const float* rgbfeat_b2 = (const float*)d_in[8];
    const float* c_ln_g = (const float*)d_in[9];
    const float* c_ln_b = (const float*)d_in[10];
    const float* c_qw   = (const float*)d_in[11];
    const float* c_kw   = (const float*)d_in[12];
    const float* c_vw   = (const float*)d_in[13];
    const float* c_pw1  = (const float*)d_in[14];
    const float* c_pb1  = (const float*)d_in[15];
    const float* c_pw2  = (const float*)d_in[16];
    const float* c_pb2  = (const float*)d_in[17];
    const float* c_aw1  = (const float*)d_in[18];
    const float* c_ab1  = (const float*)d_in[19];
    const float* c_aw2  = (const float*)d_in[20];
    const float* c_ab2  = (const float*)d_in[21];
    const float* c_ow   = (const float*)d_in[22];
    const float* c_ob   = (const float*)d_in[23];
    const float* c_fg   = (const float*)d_in[24];
    const float* c_fb   = (const float*)d_in[25];
    const float* c_fw1  = (const float*)d_in[26];
    const float* c_fb1  = (const float*)d_in[27];
    const float* c_fw2  = (const float*)d_in[28];
    const float* c_fb2  = (const float*)d_in[29];
    const float* s_ln_g = (const float*)d_in[30];
    const float* s_ln_b = (const float*)d_in[31];
    const float* s_qw   = (const float*)d_in[32];
    const float* s_kw   = (const float*)d_in[33];
    const float* s_vw   = (const float*)d_in[34];
    const float* s_ow   = (const float*)d_in[35];
    const float* s_ob   = (const float*)d_in[36];
    const float* s_fg   = (const float*)d_in[37];
    const float* s_fb   = (const float*)d_in[38];
    const float* s_fw1  = (const float*)d_in[39];
    const float* s_fb1  = (const float*)d_in[40];
    const float* s_fw2  = (const float*)d_in[41];
    const float* s_fb2  = (const float*)d_in[42];
    const float* q_w1   = (const float*)d_in[43];
    const float* q_b1   = (const float*)d_in[44];
    const float* q_w2   = (const float*)d_in[45];
    const float* q_b2   = (const float*)d_in[46];
    const float* norm_g = (const float*)d_in[47];
    const float* norm_b = (const float*)d_in[48];
    const float* out_w  = (const float*)d_in[49];
    const float* out_b  = (const float*)d_in[50];
    float* out = (float*)d_out;

    // ---- workspace carve (256B aligned) ----
    char* p = (char*)d_ws;
    auto alloc = [&](size_t bytes) { char* r = p; p += (bytes + 255) & ~(size_t)255; return r; };
    short* rgbf  = (short*)alloc((size_t)BSV * 256 * 2);
    short* hall  = (short*)alloc((size_t)DD * BSV * 32 * 2);
    short* kvall = (short*)alloc((size_t)4 * BSV * 512 * 2);
    short* a_in  = (short*)alloc((size_t)BSV * 256 * 2);
    short* obb   = (short*)alloc((size_t)BS * 256 * 2);
    short* xq    = (short*)alloc((size_t)BS * 256 * 2);
    short* hb    = (short*)alloc((size_t)BS * 256 * 2);
    short* catb  = (short*)alloc((size_t)BS * 384 * 2);
    short* qkv   = (short*)alloc((size_t)BS * 768 * 2);
    short* rgbp  = qkv;
    float* qf    = (float*)alloc((size_t)BS * 256 * 4);
    float* fq    = (float*)alloc((size_t)BS * 256 * 4);
    float* ipts  = (float*)alloc((size_t)BS * 63 * 4);
    float* ivw   = (float*)alloc((size_t)BB * 27 * 4);
    // weights (bf16, transposed [N,Kpad])
    short* w1T   = (short*)alloc(256 * 64 * 2);
    short* w2T   = (short*)alloc(256 * 256 * 2);
    short* qwT   = (short*)alloc((size_t)DD * 256 * 256 * 2);
    short* kvpT  = (short*)alloc((size_t)DD * 512 * 288 * 2);
    short* aw1T  = (short*)alloc((size_t)DD * 32 * 256 * 2);
    short* aw2T  = (short*)alloc((size_t)DD * 256 * 32 * 2);
    short* owT   = (short*)alloc((size_t)DD * 256 * 256 * 2);
    short* fw1T  = (short*)alloc((size_t)DD * 1024 * 256 * 2);
    short* fw2T  = (short*)alloc((size_t)DD * 256 * 1024 * 2);
    short* sqkvT = (short*)alloc((size_t)DD * 768 * 256 * 2);
    short* sowT  = (short*)alloc((size_t)DD * 256 * 256 * 2);
    short* sfw1T = (short*)alloc((size_t)DD * 1024 * 256 * 2);
    short* sfw2T = (short*)alloc((size_t)DD * 256 * 1024 * 2);
    short* qw1T  = (short*)alloc((size_t)4 * 256 * 384 * 2);
    short* qw2T  = (short*)alloc((size_t)4 * 256 * 256 * 2);

    // ---- weight conversion ----
    dim3 wb(32, 8);
    wconv<<<dim3(8, 2, 1), wb, 0, stream>>>(rgbfeat_w1, w1T, 35, 256, 64, 0, 0);
    wconv<<<dim3(8, 8, 1), wb, 0, stream>>>(rgbfeat_w2, w2T, 256, 256, 256, 0, 0);
    wconv<<<dim3(8, 8, DD), wb, 0, stream>>>(c_qw, qwT, 256, 256, 256, 65536, 65536);
    wconv<<<dim3(8, 8, DD), wb, 0, stream>>>(c_kw, kvpT, 256, 256, 288, 65536, 147456);
    wconv<<<dim3(8, 1, DD), wb, 0, stream>>>(c_pw2, kvpT + 256, 32, 256, 288, 8192, 147456);
    wconv<<<dim3(8, 8, DD), wb, 0, stream>>>(c_vw, kvpT + 256 * 288, 256, 256, 288, 65536, 147456);
    wconv<<<dim3(8, 1, DD), wb, 0, stream>>>(c_pw2, kvpT + 256 * 288 + 256, 32, 256, 288, 8192, 147456);
    wconv<<<dim3(1, 8, DD), wb, 0, stream>>>(c_aw1, aw1T, 256, 32, 256, 8192, 8192);
    wconv<<<dim3(8, 1, DD), wb, 0, stream>>>(c_aw2, aw2T, 32, 256, 32, 8192, 8192);
    wconv<<<dim3(8, 8, DD), wb, 0, stream>>>(c_ow, owT, 256, 256, 256, 65536, 65536);
    wconv<<<dim3(32, 8, DD), wb, 0, stream>>>(c_fw1, fw1T, 256, 1024, 256, 262144, 262144);
    wconv<<<dim3(8, 32, DD), wb, 0, stream>>>(c_fw2, fw2T, 1024, 256, 1024, 262144, 262144);
    wconv<<<dim3(8, 8, DD), wb, 0, stream>>>(s_qw, sqkvT, 256, 256, 256, 65536, 196608);
    wconv<<<dim3(8, 8, DD), wb, 0, stream>>>(s_kw, sqkvT + 65536, 256, 256, 256, 65536, 196608);
    wconv<<<dim3(8, 8, DD), wb, 0, stream>>>(s_vw, sqkvT + 131072, 256, 256, 256, 65536, 196608);
    wconv<<<dim3(8, 8, DD), wb, 0, stream>>>(s_ow, sowT, 256, 256, 256, 65536, 65536);
    wconv<<<dim3(32, 8, DD), wb, 0, stream>>>(s_fw1, sfw1T, 256, 1024, 256, 262144, 262144);
    wconv<<<dim3(8, 32, DD), wb, 0, stream>>>(s_fw2, sfw2T, 1024, 256, 1024, 262144, 262144);
    wconv<<<dim3(8, 12, 4), wb, 0, stream>>>(q_w1, qw1T, 346, 256, 384, 88576, 98304);
    wconv<<<dim3(8, 8, 4), wb, 0, stream>>>(q_w2, qw2T, 256, 256, 256, 65536, 65536);

    // ---- preamble ----
    penc_pts<<<(BS + 255) / 256, 256, 0, stream>>>(pts, ipts);
    penc_views<<<1, 64, 0, stream>>>(ray_d, ivw);
    catfill<<<(BS * 128) / 256, 256, 0, stream>>>(ipts, ivw, catb);
    rgbconv<<<(BSV * 64) / 256, 256, 0, stream>>>(rgb_feat, rgbp);
    hallk<<<(DD * BSV * 32) / 256, 256, 0, stream>>>(ray_diff, c_pw1, c_pb1, hall);
    GEMM_BF(128, 128, 64, 64, rgbp, w1T, rgbfeat_b1, a_in, BSV, 256, 64, 256, 1);
    GEMM_BF(128, 128, 64, 64, a_in, w2T, rgbfeat_b2, rgbf, BSV, 256, 256, 256, 0);
    vmaxln<<<BS, 256, 0, stream>>>(rgbf, c_ln_g, c_ln_b, fq, xq);
    GEMM_F(64, 64, 32, 32, xq, qwT, nullptr, nullptr, qf, BS, 256, 256, 0);
    kvbatch<<<dim3(4, 4, 256), 256, 0, stream>>>(rgbf, hall, kvpT, kvall, 0);

    for (int i = 0; i < DD; i++) {
        int j = i >> 1;
        if (i == 4)
            kvbatch<<<dim3(4, 4, 256), 256, 0, stream>>>(rgbf, hall, kvpT, kvall, 4);
        crossattn<<<BSV / 64, 256, 0, stream>>>(kvall + (size_t)(i & 3) * BSV * 512, qf, maskp,
            aw1T + (size_t)i * 8192, c_ab1 + i * 32,
            aw2T + (size_t)i * 8192, c_ab2 + i * 256, obb);
        chainA<<<256, 256, 0, stream>>>(obb, fq, catb, qkv,
            owT + (size_t)i * 65536, c_ob + i * 256, c_fg + i * 256, c_fb + i * 256,
            fw1T + (size_t)i * 262144, c_fb1 + i * 1024,
            fw2T + (size_t)i * 262144, c_fb2 + i * 256,
            qw1T + (size_t)j * 98304, q_b1 + j * 256,
            qw2T + (size_t)j * 65536, q_b2 + j * 256,
            s_ln_g + i * 256, s_ln_b + i * 256,
            sqkvT + (size_t)i * 196608, !(i & 1));
        attn_mfma<<<BB * 4, 64, 0, stream>>>(qkv, obb);
        int last = (i == DD - 1);
        chainB<<<256, 256, 0, stream>>>(obb, fq,
            sowT + (size_t)i * 65536, s_ob + i * 256, s_fg + i * 256, s_fb + i * 256,
            sfw1T + (size_t)i * 262144, s_fb1 + i * 1024,
            sfw2T + (size_t)i * 262144, s_fb2 + i * 256,
            last ? norm_g : c_ln_g + (i + 1) * 256,
            last ? norm_b : c_ln_b + (i + 1) * 256,
            last ? 1e-5f : 1e-6f,
            last ? nullptr : qwT + (size_t)(i + 1) * 65536,
            qf, last ? hb : nullptr);
    }

    headk<<<BB, 256, 0, stream>>>(hb, out_w, out_b, out);
}

// Round 11
// 1467.376 us; speedup vs baseline: 1.2625x; 1.0688x over previous
//
#include <hip/hip_runtime.h>
#include <hip/hip_bf16.h>
#include <math.h>

#define BB 64
#define SS 64
#define VV 8
#define WW 256
#define DD 8
#define BS (BB*SS)        // 4096
#define BSV (BB*SS*VV)    // 32768

#define RB 392            // rowbuf stride (shorts)
#define HBs 1064          // hid stride
#define TB 264            // tmpb stride
#define AS 296            // crosskv A stride (148 dw % 32 = 20)

typedef __attribute__((ext_vector_type(8))) short s8v;
typedef __attribute__((ext_vector_type(4))) float f4v;

__device__ __forceinline__ short f2b(float f) {
    __hip_bfloat16 h = __float2bfloat16(f);
    return *reinterpret_cast<short*>(&h);
}
__device__ __forceinline__ float b2f(short s) {
    __hip_bfloat16 h = *reinterpret_cast<__hip_bfloat16*>(&s);
    return __bfloat162float(h);
}

// ---------------------------------------------------------------------------
// One 16x16 output tile over K: A from LDS, B fragments straight from global.
// ---------------------------------------------------------------------------
__device__ __forceinline__ f4v rowgemm(const short* __restrict__ aL, int lda,
                                       const short* __restrict__ bG, int K,
                                       int ksteps, int lm, int lq)
{
    f4v acc = (f4v){0.f, 0.f, 0.f, 0.f};
#pragma unroll 8
    for (int k = 0; k < ksteps; k++) {
        s8v a = *(const s8v*)&aL[lm * lda + k * 32 + lq * 8];
        s8v b = *(const s8v*)&bG[(size_t)lm * K + k * 32 + lq * 8];
        acc = __builtin_amdgcn_mfma_f32_16x16x32_bf16(a, b, acc, 0, 0, 0);
    }
    return acc;
}

// ---------------------------------------------------------------------------
// In-block LayerNorm of 16 rows x 256 cols held in registers v[t][r].
// ---------------------------------------------------------------------------
__device__ __forceinline__ void ln_rows(
    float v[4][4], const float* __restrict__ g, const float* __restrict__ b,
    float eps, short* rowbuf, float* red, int w, int lm, int lq,
    short* __restrict__ outG, int row0)
{
    float ps[4] = {0.f, 0.f, 0.f, 0.f};
#pragma unroll
    for (int t = 0; t < 4; t++)
#pragma unroll
        for (int r = 0; r < 4; r++) ps[r] += v[t][r];
#pragma unroll
    for (int m = 1; m < 16; m <<= 1)
#pragma unroll
        for (int r = 0; r < 4; r++) ps[r] += __shfl_xor(ps[r], m);
    if (lm == 0)
#pragma unroll
        for (int r = 0; r < 4; r++) red[(lq * 4 + r) * 4 + w] = ps[r];
    __syncthreads();
    float mean[4];
#pragma unroll
    for (int r = 0; r < 4; r++) {
        int row = lq * 4 + r;
        mean[r] = (red[row * 4] + red[row * 4 + 1] + red[row * 4 + 2] + red[row * 4 + 3]) * (1.f / 256.f);
    }
    __syncthreads();
    float pq[4] = {0.f, 0.f, 0.f, 0.f};
#pragma unroll
    for (int t = 0; t < 4; t++)
#pragma unroll
        for (int r = 0; r < 4; r++) { float d = v[t][r] - mean[r]; pq[r] += d * d; }
#pragma unroll
    for (int m = 1; m < 16; m <<= 1)
#pragma unroll
        for (int r = 0; r < 4; r++) pq[r] += __shfl_xor(pq[r], m);
    if (lm == 0)
#pragma unroll
        for (int r = 0; r < 4; r++) red[(lq * 4 + r) * 4 + w] = pq[r];
    __syncthreads();
    float inv[4];
#pragma unroll
    for (int r = 0; r < 4; r++) {
        int row = lq * 4 + r;
        float var = (red[row * 4] + red[row * 4 + 1] + red[row * 4 + 2] + red[row * 4 + 3]) * (1.f / 256.f);
        inv[r] = rsqrtf(var + eps);
    }
#pragma unroll
    for (int t = 0; t < 4; t++) {
        int col = (w * 4 + t) * 16 + lm;
        float gc = g[col], bc = b[col];
#pragma unroll
        for (int r = 0; r < 4; r++) {
            float val = (v[t][r] - mean[r]) * inv[r] * gc + bc;
            rowbuf[(lq * 4 + r) * RB + col] = f2b(val);
            if (outG) outG[(size_t)(row0 + lq * 4 + r) * 256 + col] = f2b(val);
        }
    }
    __syncthreads();
}

// ---------------------------------------------------------------------------
// chainA: ow+res -> LN(c_fg) -> fw1 -> fw2+res -> [even: cat->q1->q2]
//         -> write fq -> LN(s_ln) -> sqkv.  Block = 16 rows, grid 256.
// ---------------------------------------------------------------------------
__global__ __launch_bounds__(256) void chainA(
    const short* __restrict__ obb, float* __restrict__ fq,
    const short* __restrict__ catb, short* __restrict__ qkv,
    const short* __restrict__ owT, const float* __restrict__ c_ob,
    const float* __restrict__ c_fg, const float* __restrict__ c_fb,
    const short* __restrict__ fw1T, const float* __restrict__ c_fb1,
    const short* __restrict__ fw2T, const float* __restrict__ c_fb2,
    const short* __restrict__ qw1T, const float* __restrict__ q_b1,
    const short* __restrict__ qw2T, const float* __restrict__ q_b2,
    const float* __restrict__ s_ln_g, const float* __restrict__ s_ln_b,
    const short* __restrict__ sqkvT, int even)
{
    __shared__ __align__(16) short rowbuf[16 * RB];
    __shared__ __align__(16) short hid[16 * HBs];
    __shared__ __align__(16) short tmpb[16 * TB];
    __shared__ float red[64];
    int tid = threadIdx.x, lane = tid & 63, w = tid >> 6;
    int lm = lane & 15, lq = lane >> 4;
    int row0 = blockIdx.x * 16;
    {
        int r = tid >> 4, c = (tid & 15) * 16;
        *(s8v*)&rowbuf[r * RB + c]     = *(const s8v*)&obb[(size_t)(row0 + r) * 256 + c];
        *(s8v*)&rowbuf[r * RB + c + 8] = *(const s8v*)&obb[(size_t)(row0 + r) * 256 + c + 8];
    }
    __syncthreads();
    float fqreg[4][4];
    {
        f4v o[4];
#pragma unroll
        for (int t = 0; t < 4; t++)
            o[t] = rowgemm(rowbuf, RB, owT + (size_t)(w * 4 + t) * 16 * 256, 256, 8, lm, lq);
#pragma unroll
        for (int t = 0; t < 4; t++) {
            int col = (w * 4 + t) * 16 + lm;
            float bb = c_ob[col];
#pragma unroll
            for (int r = 0; r < 4; r++)
                fqreg[t][r] = o[t][r] + bb + fq[(size_t)(row0 + lq * 4 + r) * 256 + col];
        }
    }
    ln_rows(fqreg, c_fg, c_fb, 1e-6f, rowbuf, red, w, lm, lq, nullptr, row0);
#pragma unroll
    for (int t = 0; t < 16; t++) {
        f4v o = rowgemm(rowbuf, RB, fw1T + (size_t)(w * 16 + t) * 16 * 256, 256, 8, lm, lq);
        int col = (w * 16 + t) * 16 + lm;
        float bb = c_fb1[col];
#pragma unroll
        for (int r = 0; r < 4; r++)
            hid[(lq * 4 + r) * HBs + col] = f2b(fmaxf(o[r] + bb, 0.f));
    }
    __syncthreads();
    {
        f4v o[4];
#pragma unroll
        for (int t = 0; t < 4; t++)
            o[t] = rowgemm(hid, HBs, fw2T + (size_t)(w * 4 + t) * 16 * 1024, 1024, 32, lm, lq);
#pragma unroll
        for (int t = 0; t < 4; t++) {
            int col = (w * 4 + t) * 16 + lm;
            float bb = c_fb2[col];
#pragma unroll
            for (int r = 0; r < 4; r++)
                fqreg[t][r] = o[t][r] + bb + fqreg[t][r];
        }
    }
    if (even) {
#pragma unroll
        for (int t = 0; t < 4; t++) {
            int col = (w * 4 + t) * 16 + lm;
#pragma unroll
            for (int r = 0; r < 4; r++)
                rowbuf[(lq * 4 + r) * RB + col] = f2b(fqreg[t][r]);
        }
        {
            int r = tid >> 4, c = (tid & 15) * 8;
            *(s8v*)&rowbuf[r * RB + 256 + c] = *(const s8v*)&catb[(size_t)(row0 + r) * 384 + 256 + c];
        }
        __syncthreads();
#pragma unroll
        for (int t = 0; t < 4; t++) {
            f4v o = rowgemm(rowbuf, RB, qw1T + (size_t)(w * 4 + t) * 16 * 384, 384, 12, lm, lq);
            int col = (w * 4 + t) * 16 + lm;
            float bb = q_b1[col];
#pragma unroll
            for (int r = 0; r < 4; r++)
                tmpb[(lq * 4 + r) * TB + col] = f2b(fmaxf(o[r] + bb, 0.f));
        }
        __syncthreads();
        f4v o[4];
#pragma unroll
        for (int t = 0; t < 4; t++)
            o[t] = rowgemm(tmpb, TB, qw2T + (size_t)(w * 4 + t) * 16 * 256, 256, 8, lm, lq);
#pragma unroll
        for (int t = 0; t < 4; t++) {
            int col = (w * 4 + t) * 16 + lm;
            float bb = q_b2[col];
#pragma unroll
            for (int r = 0; r < 4; r++)
                fqreg[t][r] = o[t][r] + bb;
        }
    }
#pragma unroll
    for (int t = 0; t < 4; t++) {
        int col = (w * 4 + t) * 16 + lm;
#pragma unroll
        for (int r = 0; r < 4; r++)
            fq[(size_t)(row0 + lq * 4 + r) * 256 + col] = fqreg[t][r];
    }
    ln_rows(fqreg, s_ln_g, s_ln_b, 1e-6f, rowbuf, red, w, lm, lq, nullptr, row0);
#pragma unroll
    for (int t = 0; t < 12; t++) {
        f4v o = rowgemm(rowbuf, RB, sqkvT + (size_t)(w * 12 + t) * 16 * 256, 256, 8, lm, lq);
        int col = (w * 12 + t) * 16 + lm;
#pragma unroll
        for (int r = 0; r < 4; r++)
            qkv[(size_t)(row0 + lq * 4 + r) * 768 + col] = f2b(o[r]);
    }
}

// ---------------------------------------------------------------------------
// chainB: sow+res -> LN(s_fg) -> sfw1 -> sfw2+res -> write fq ->
//         LN(next c_ln | final norm[->hb]) -> qw_next -> qf.
// ---------------------------------------------------------------------------
__global__ __launch_bounds__(256) void chainB(
    const short* __restrict__ obb, float* __restrict__ fq,
    const short* __restrict__ sowT, const float* __restrict__ s_ob,
    const float* __restrict__ s_fg, const float* __restrict__ s_fb,
    const short* __restrict__ sfw1T, const float* __restrict__ s_fb1,
    const short* __restrict__ sfw2T, const float* __restrict__ s_fb2,
    const float* __restrict__ ln2_g, const float* __restrict__ ln2_b, float eps2,
    const short* __restrict__ qwTn, float* __restrict__ qf,
    short* __restrict__ hbG)
{
    __shared__ __align__(16) short rowbuf[16 * RB];
    __shared__ __align__(16) short hid[16 * HBs];
    __shared__ float red[64];
    int tid = threadIdx.x, lane = tid & 63, w = tid >> 6;
    int lm = lane & 15, lq = lane >> 4;
    int row0 = blockIdx.x * 16;
    {
        int r = tid >> 4, c = (tid & 15) * 16;
        *(s8v*)&rowbuf[r * RB + c]     = *(const s8v*)&obb[(size_t)(row0 + r) * 256 + c];
        *(s8v*)&rowbuf[r * RB + c + 8] = *(const s8v*)&obb[(size_t)(row0 + r) * 256 + c + 8];
    }
    __syncthreads();
    float fqreg[4][4];
    {
        f4v o[4];
#pragma unroll
        for (int t = 0; t < 4; t++)
            o[t] = rowgemm(rowbuf, RB, sowT + (size_t)(w * 4 + t) * 16 * 256, 256, 8, lm, lq);
#pragma unroll
        for (int t = 0; t < 4; t++) {
            int col = (w * 4 + t) * 16 + lm;
            float bb = s_ob[col];
#pragma unroll
            for (int r = 0; r < 4; r++)
                fqreg[t][r] = o[t][r] + bb + fq[(size_t)(row0 + lq * 4 + r) * 256 + col];
        }
    }
    ln_rows(fqreg, s_fg, s_fb, 1e-6f, rowbuf, red, w, lm, lq, nullptr, row0);
#pragma unroll
    for (int t = 0; t < 16; t++) {
        f4v o = rowgemm(rowbuf, RB, sfw1T + (size_t)(w * 16 + t) * 16 * 256, 256, 8, lm, lq);
        int col = (w * 16 + t) * 16 + lm;
        float bb = s_fb1[col];
#pragma unroll
        for (int r = 0; r < 4; r++)
            hid[(lq * 4 + r) * HBs + col] = f2b(fmaxf(o[r] + bb, 0.f));
    }
    __syncthreads();
    {
        f4v o[4];
#pragma unroll
        for (int t = 0; t < 4; t++)
            o[t] = rowgemm(hid, HBs, sfw2T + (size_t)(w * 4 + t) * 16 * 1024, 1024, 32, lm, lq);
#pragma unroll
        for (int t = 0; t < 4; t++) {
            int col = (w * 4 + t) * 16 + lm;
            float bb = s_fb2[col];
#pragma unroll
            for (int r = 0; r < 4; r++)
                fqreg[t][r] = o[t][r] + bb + fqreg[t][r];
        }
    }
#pragma unroll
    for (int t = 0; t < 4; t++) {
        int col = (w * 4 + t) * 16 + lm;
#pragma unroll
        for (int r = 0; r < 4; r++)
            fq[(size_t)(row0 + lq * 4 + r) * 256 + col] = fqreg[t][r];
    }
    ln_rows(fqreg, ln2_g, ln2_b, eps2, rowbuf, red, w, lm, lq, hbG, row0);
    if (qwTn) {
#pragma unroll
        for (int t = 0; t < 4; t++) {
            f4v o = rowgemm(rowbuf, RB, qwTn + (size_t)(w * 4 + t) * 16 * 256, 256, 8, lm, lq);
            int col = (w * 4 + t) * 16 + lm;
#pragma unroll
            for (int r = 0; r < 4; r++)
                qf[(size_t)(row0 + lq * 4 + r) * 256 + col] = o[r];
        }
    }
}

// ---------------------------------------------------------------------------
// crosskv: fused kv-projection + cross-attention. Block = 32 kv rows
// (4 samples), grid 1024. kvpT [512][288] = [kw|pw2 ; vw|pw2]^T streamed
// from L2 as B-fragments. k+pos computed fp32, a_in = k+pos - q, MLP
// attention scores, masked softmax over views, weighted (v+pos) sum.
// ---------------------------------------------------------------------------
__global__ __launch_bounds__(256) void crosskv(
    const short* __restrict__ rgbf, const short* __restrict__ hall_l,
    const short* __restrict__ kvpT_l, const float* __restrict__ qf,
    const int* __restrict__ mask,
    const short* __restrict__ aw1T_l, const float* __restrict__ ab1,
    const short* __restrict__ aw2T_l, const float* __restrict__ ab2,
    short* __restrict__ obb)
{
    __shared__ __align__(16) short A_s[32 * AS];    // [rgbf(256)|h(32)]
    __shared__ __align__(16) short a_s[32 * 264];   // a_in, later v+pos
    __shared__ __align__(16) short ph_s[32 * 40];
    __shared__ int msk[32];
    int blk = blockIdx.x, tid = threadIdx.x;
    int row0 = blk * 32, bs0 = blk * 4;
    int lane = tid & 63, w = tid >> 6, lm = lane & 15, lq = lane >> 4;
    if (tid < 32) msk[tid] = mask[bs0 * 8 + tid];
    // stage A: rgbf 32x256 + h 32x32
#pragma unroll
    for (int i = 0; i < 4; i++) {
        int e = tid + i * 256;
        int r = e >> 5, c = (e & 31) << 3;
        *(s8v*)&A_s[r * AS + c] = *(const s8v*)&rgbf[(size_t)(row0 + r) * 256 + c];
    }
    if (tid < 128) {
        int r = tid >> 2, c = (tid & 3) << 3;
        *(s8v*)&A_s[r * AS + 256 + c] = *(const s8v*)&hall_l[(size_t)(row0 + r) * 32 + c];
    }
    __syncthreads();
    // stage 1: k-half (cols 0..255): wave w -> n-tiles w*4..w*4+3, m-tiles 0..1
#pragma unroll
    for (int j4 = 0; j4 < 4; j4++) {
        int n0 = (w * 4 + j4) * 16;
#pragma unroll
        for (int i = 0; i < 2; i++) {
            f4v acc = (f4v){0.f, 0.f, 0.f, 0.f};
#pragma unroll
            for (int k = 0; k < 9; k++) {
                s8v a = *(const s8v*)&A_s[(i * 16 + lm) * AS + k * 32 + lq * 8];
                s8v b = *(const s8v*)&kvpT_l[(size_t)(n0 + lm) * 288 + k * 32 + lq * 8];
                acc = __builtin_amdgcn_mfma_f32_16x16x32_bf16(a, b, acc, 0, 0, 0);
            }
#pragma unroll
            for (int r = 0; r < 4; r++) {
                int row = i * 16 + lq * 4 + r, col = n0 + lm;
                float q = qf[(size_t)(bs0 + (row >> 3)) * 256 + col];
                a_s[row * 264 + col] = f2b(acc[r] - q);
            }
        }
    }
    __syncthreads();
    // stage 2: ph = relu(a_in @ aw1 + ab1): wave w -> tile (i=w>>1, j=w&1)
    {
        int i = w >> 1, j = w & 1;
        f4v acc = (f4v){0.f, 0.f, 0.f, 0.f};
#pragma unroll
        for (int k = 0; k < 8; k++) {
            s8v a = *(const s8v*)&a_s[(i * 16 + lm) * 264 + k * 32 + lq * 8];
            s8v b = *(const s8v*)&aw1T_l[(size_t)(j * 16 + lm) * 256 + k * 32 + lq * 8];
            acc = __builtin_amdgcn_mfma_f32_16x16x32_bf16(a, b, acc, 0, 0, 0);
        }
        int col = j * 16 + lm;
        float bb = ab1[col];
#pragma unroll
        for (int r = 0; r < 4; r++)
            ph_s[(i * 16 + lq * 4 + r) * 40 + col] = f2b(fmaxf(acc[r] + bb, 0.f));
    }
    __syncthreads();
    // stage 3: a3 = ph @ aw2 (K=32) into regs
    f4v a3[2][4];
#pragma unroll
    for (int i = 0; i < 2; i++) {
        s8v pa = *(const s8v*)&ph_s[(i * 16 + lm) * 40 + lq * 8];
#pragma unroll
        for (int j4 = 0; j4 < 4; j4++) {
            int n0 = (w * 4 + j4) * 16;
            s8v b = *(const s8v*)&aw2T_l[(size_t)(n0 + lm) * 32 + lq * 8];
            a3[i][j4] = __builtin_amdgcn_mfma_f32_16x16x32_bf16(pa, b, (f4v){0.f, 0.f, 0.f, 0.f}, 0, 0, 0);
        }
    }
    // stage 4: v-half (cols 256..511) -> a_s (v+pos)
#pragma unroll
    for (int j4 = 0; j4 < 4; j4++) {
        int n0 = (w * 4 + j4) * 16;
#pragma unroll
        for (int i = 0; i < 2; i++) {
            f4v acc = (f4v){0.f, 0.f, 0.f, 0.f};
#pragma unroll
            for (int k = 0; k < 9; k++) {
                s8v a = *(const s8v*)&A_s[(i * 16 + lm) * AS + k * 32 + lq * 8];
                s8v b = *(const s8v*)&kvpT_l[(size_t)(256 + n0 + lm) * 288 + k * 32 + lq * 8];
                acc = __builtin_amdgcn_mfma_f32_16x16x32_bf16(a, b, acc, 0, 0, 0);
            }
#pragma unroll
            for (int r = 0; r < 4; r++)
                a_s[(i * 16 + lq * 4 + r) * 264 + n0 + lm] = f2b(acc[r]);
        }
    }
    __syncthreads();
    // stage 5: masked softmax over views + weighted sum
#pragma unroll
    for (int i = 0; i < 2; i++) {
        int sample = i * 2 + (lq >> 1);
        int mk[4];
#pragma unroll
        for (int r = 0; r < 4; r++) mk[r] = msk[sample * 8 + (lq & 1) * 4 + r];
#pragma unroll
        for (int j4 = 0; j4 < 4; j4++) {
            int col = (w * 4 + j4) * 16 + lm;
            float bv = ab2[col];
            float vals[4];
#pragma unroll
            for (int r = 0; r < 4; r++) vals[r] = mk[r] ? (a3[i][j4][r] + bv) : -1e9f;
            float mx = fmaxf(fmaxf(vals[0], vals[1]), fmaxf(vals[2], vals[3]));
            mx = fmaxf(mx, __shfl_xor(mx, 16));
            float ev[4], s = 0.f;
#pragma unroll
            for (int r = 0; r < 4; r++) { ev[r] = expf(vals[r] - mx); s += ev[r]; }
            s += __shfl_xor(s, 16);
            float o = 0.f;
#pragma unroll
            for (int r = 0; r < 4; r++)
                o += ev[r] * b2f(a_s[(i * 16 + lq * 4 + r) * 264 + col]);
            o += __shfl_xor(o, 16);
            o /= s;
            if (!(lq & 1)) obb[(size_t)(bs0 + sample) * 256 + col] = f2b(o);
        }
    }
}

// ---------------------------------------------------------------------------
// bf16 MFMA GEMM (BK=32, LDS stride 40) — preamble + layer-0 qw.
// ---------------------------------------------------------------------------
template<int TM, int TN, int WM, int WN, bool OUTBF>
__global__ __launch_bounds__(256) void gemm_mfma(
    const short* __restrict__ A, const short* __restrict__ Bt,
    const float* __restrict__ bias, const float* __restrict__ res,
    float* __restrict__ Cf, short* __restrict__ Cb,
    int M, int N, int K, int ldc, int relu)
{
    constexpr int MT  = WM / 16;
    constexpr int NT  = WN / 16;
    constexpr int RWN = TN / WN;
    __shared__ __align__(16) short As[TM * 40];
    __shared__ __align__(16) short Bs[TN * 40];
    int tid = threadIdx.x;
    int m0 = blockIdx.y * TM, n0 = blockIdx.x * TN;
    int lane = tid & 63, w = tid >> 6;
    int lm = lane & 15, lq = lane >> 4;
    int wm = (w / RWN) * WM, wn = (w % RWN) * WN;
    f4v acc[MT][NT];
#pragma unroll
    for (int i = 0; i < MT; i++)
#pragma unroll
        for (int j = 0; j < NT; j++) acc[i][j] = (f4v){0.f, 0.f, 0.f, 0.f};

    for (int k0 = 0; k0 < K; k0 += 32) {
        for (int c = tid; c < TM * 4; c += 256) {
            int r = c >> 2, kc = (c & 3) << 3;
            *(s8v*)&As[r * 40 + kc] = *(const s8v*)&A[(size_t)(m0 + r) * K + k0 + kc];
        }
        for (int c = tid; c < TN * 4; c += 256) {
            int r = c >> 2, kc = (c & 3) << 3;
            *(s8v*)&Bs[r * 40 + kc] = *(const s8v*)&Bt[(size_t)(n0 + r) * K + k0 + kc];
        }
        __syncthreads();
        s8v af[MT], bfv[NT];
#pragma unroll
        for (int i = 0; i < MT; i++)
            af[i] = *(const s8v*)&As[(wm + i * 16 + lm) * 40 + lq * 8];
#pragma unroll
        for (int j = 0; j < NT; j++)
            bfv[j] = *(const s8v*)&Bs[(wn + j * 16 + lm) * 40 + lq * 8];
#pragma unroll
        for (int i = 0; i < MT; i++)
#pragma unroll
            for (int j = 0; j < NT; j++)
                acc[i][j] = __builtin_amdgcn_mfma_f32_16x16x32_bf16(af[i], bfv[j], acc[i][j], 0, 0, 0);
        __syncthreads();
    }
#pragma unroll
    for (int i = 0; i < MT; i++) {
        int row = m0 + wm + i * 16 + lq * 4;
#pragma unroll
        for (int j = 0; j < NT; j++) {
            int col = n0 + wn + j * 16 + lm;
            float bv = bias ? bias[col] : 0.f;
#pragma unroll
            for (int r = 0; r < 4; r++) {
                float v = acc[i][j][r] + bv;
                if (relu) v = fmaxf(v, 0.f);
                size_t idx = (size_t)(row + r) * ldc + col;
                if (OUTBF) {
                    Cb[idx] = f2b(v);
                } else {
                    if (res) v += res[idx];
                    Cf[idx] = v;
                }
            }
        }
    }
}

// ---------------------------------------------------------------------------
// Batched weight convert+transpose: all jobs in one launch.
// ---------------------------------------------------------------------------
struct WJob {
    const float* src; short* dst;
    int K, N, Kpad, zi, gy, nblk;
    size_t zo;
};
struct WJobs { WJob j[20]; };

__global__ void wconv_all(WJobs jobs)
{
    __shared__ float t[32][33];
    int b = blockIdx.x, ji = 0;
    while (b >= jobs.j[ji].nblk) { b -= jobs.j[ji].nblk; ji++; }
    WJob J = jobs.j[ji];
    int gx = J.N >> 5;
    int z = b / (gx * J.gy);
    int rem = b - z * (gx * J.gy);
    int by = rem / gx, bx = rem - by * gx;
    const float* W = J.src + (size_t)z * J.zi;
    short* Wt = J.dst + (size_t)z * J.zo;
    int n0 = bx * 32, k0 = by * 32;
    int tx = threadIdx.x, ty = threadIdx.y;
#pragma unroll
    for (int i = 0; i < 4; i++) {
        int k = k0 + ty + i * 8;
        t[ty + i * 8][tx] = (k < J.K) ? W[(size_t)k * J.N + n0 + tx] : 0.f;
    }
    __syncthreads();
#pragma unroll
    for (int i = 0; i < 4; i++) {
        int n = n0 + ty + i * 8;
        Wt[(size_t)n * J.Kpad + k0 + tx] = f2b(t[tx][ty + i * 8]);
    }
}

// catb tail computed directly from pts/ray_d (penc inline)
__global__ void catpenc(const float* __restrict__ pts, const float* __restrict__ ray_d,
                        short* __restrict__ catb)
{
    int idx = blockIdx.x * 256 + threadIdx.x;   // BS*128
    int bs = idx >> 7, c = idx & 127;
    float v = 0.f;
    if (c < 63) {
        if (c < 3) v = pts[bs * 3 + c];
        else {
            int e = c - 3; int d, k; bool sn;
            if (e < 30) { d = e / 10; k = e - d * 10; sn = true; }
            else { e -= 30; d = e / 10; k = e - d * 10; sn = false; }
            float ang = pts[bs * 3 + d] * (float)(1 << k);
            v = sn ? sinf(ang) : cosf(ang);
        }
    } else if (c < 90) {
        int e = c - 63, b = bs >> 6;
        float x = ray_d[b * 3], y = ray_d[b * 3 + 1], z = ray_d[b * 3 + 2];
        float inv = rsqrtf(x * x + y * y + z * z);
        float vv[3] = {x * inv, y * inv, z * inv};
        if (e < 3) v = vv[e];
        else if (e < 15) { int d = (e - 3) >> 2, k = (e - 3) & 3; v = sinf(vv[d] * (float)(1 << k)); }
        else { int d = (e - 15) >> 2, k = (e - 15) & 3; v = cosf(vv[d] * (float)(1 << k)); }
    }
    catb[(size_t)bs * 384 + 256 + c] = f2b(v);
}

// rgb_feat pad-convert + hall (all 8 layers) in one launch
__global__ void rgbhall(const float* __restrict__ rgb_feat, const float* __restrict__ rdiff,
                        const float* __restrict__ pw1, const float* __restrict__ pb1,
                        short* __restrict__ rgbp, short* __restrict__ hall)
{
    int idx = blockIdx.x * 256 + threadIdx.x;
    if (idx < BSV * 64) {
        int row = idx >> 6, col = idx & 63;
        rgbp[idx] = f2b(col < 35 ? rgb_feat[row * 35 + col] : 0.f);
    } else {
        int k = idx - BSV * 64;
        int t = k & 31, row = (k >> 5) & (BSV - 1), l = k >> 20;
        float a = pb1[l * 32 + t];
        for (int c = 0; c < 4; c++) a += rdiff[row * 4 + c] * pw1[l * 128 + c * 32 + t];
        hall[k] = f2b(fmaxf(a, 0.f));
    }
}

// view-max + layer-0 LayerNorm fused
__global__ __launch_bounds__(256) void vmaxln(
    const short* __restrict__ rgbf, const float* __restrict__ g,
    const float* __restrict__ b, float* __restrict__ fq, short* __restrict__ xq)
{
    int bs = blockIdx.x, t = threadIdx.x;
    float m = -1e30f;
    for (int v = 0; v < VV; v++) m = fmaxf(m, b2f(rgbf[((size_t)(bs * VV + v)) * 256 + t]));
    fq[(size_t)bs * WW + t] = m;
    __shared__ float red[256];
    red[t] = m;
    __syncthreads();
    for (int s = 128; s > 0; s >>= 1) { if (t < s) red[t] += red[t + s]; __syncthreads(); }
    float mean = red[0] * (1.f / 256.f);
    __syncthreads();
    float d = m - mean;
    red[t] = d * d;
    __syncthreads();
    for (int s = 128; s > 0; s >>= 1) { if (t < s) red[t] += red[t + s]; __syncthreads(); }
    float var = red[0] * (1.f / 256.f);
    xq[(size_t)bs * WW + t] = f2b(d / sqrtf(var + 1e-6f) * g[t] + b[t]);
}

// ---------------------------------------------------------------------------
// MFMA self-attention: one wave per (b,h). QKV packed bf16 [4096,768].
// ---------------------------------------------------------------------------
__global__ __launch_bounds__(64) void attn_mfma(
    const short* __restrict__ QKV, short* __restrict__ O)
{
    __shared__ __align__(16) short P[64 * 72];
    __shared__ __align__(16) short Vt[64 * 72];
    int blk = blockIdx.x;
    int b = blk >> 2, h = blk & 3, lane = threadIdx.x;
    int lm = lane & 15, lq = lane >> 4;
    const short* base = QKV + (size_t)b * 64 * 768 + h * 64;
    {
        const short* vrow = base + 512 + (size_t)lane * 768;
#pragma unroll
        for (int c = 0; c < 8; c++) {
            s8v v = *(const s8v*)&vrow[c * 8];
#pragma unroll
            for (int j = 0; j < 8; j++)
                Vt[(c * 8 + j) * 72 + lane] = v[j];
        }
    }
    s8v qfr[4][2], kf[4][2];
#pragma unroll
    for (int i = 0; i < 4; i++)
#pragma unroll
        for (int c = 0; c < 2; c++) {
            qfr[i][c] = *(const s8v*)&base[(size_t)(i * 16 + lm) * 768 + c * 32 + lq * 8];
            kf[i][c]  = *(const s8v*)&base[(size_t)(i * 16 + lm) * 768 + 256 + c * 32 + lq * 8];
        }
    f4v acc[4][4];
#pragma unroll
    for (int i = 0; i < 4; i++)
#pragma unroll
        for (int j = 0; j < 4; j++) acc[i][j] = (f4v){0.f, 0.f, 0.f, 0.f};
#pragma unroll
    for (int c = 0; c < 2; c++)
#pragma unroll
        for (int i = 0; i < 4; i++)
#pragma unroll
            for (int j = 0; j < 4; j++)
                acc[i][j] = __builtin_amdgcn_mfma_f32_16x16x32_bf16(qfr[i][c], kf[j][c], acc[i][j], 0, 0, 0);
#pragma unroll
    for (int i = 0; i < 4; i++) {
#pragma unroll
        for (int r = 0; r < 4; r++) {
            float lv[4];
#pragma unroll
            for (int j = 0; j < 4; j++) lv[j] = acc[i][j][r] * 0.125f;
            float mx = fmaxf(fmaxf(lv[0], lv[1]), fmaxf(lv[2], lv[3]));
            for (int d = 1; d < 16; d <<= 1) mx = fmaxf(mx, __shfl_xor(mx, d));
            float sum = 0.f;
#pragma unroll
            for (int j = 0; j < 4; j++) { lv[j] = expf(lv[j] - mx); sum += lv[j]; }
            for (int d = 1; d < 16; d <<= 1) sum += __shfl_xor(sum, d);
            float inv = 1.f / sum;
            int row = i * 16 + lq * 4 + r;
#pragma unroll
            for (int j = 0; j < 4; j++)
                P[row * 72 + j * 16 + lm] = f2b(lv[j] * inv);
        }
    }
    __syncthreads();
    s8v af[4][2], bf[4][2];
#pragma unroll
    for (int i = 0; i < 4; i++)
#pragma unroll
        for (int c = 0; c < 2; c++) {
            af[i][c] = *(const s8v*)&P[(i * 16 + lm) * 72 + c * 32 + lq * 8];
            bf[i][c] = *(const s8v*)&Vt[(i * 16 + lm) * 72 + c * 32 + lq * 8];
        }
    f4v o2[4][4];
#pragma unroll
    for (int i = 0; i < 4; i++)
#pragma unroll
        for (int j = 0; j < 4; j++) o2[i][j] = (f4v){0.f, 0.f, 0.f, 0.f};
#pragma unroll
    for (int c = 0; c < 2; c++)
#pragma unroll
        for (int i = 0; i < 4; i++)
#pragma unroll
            for (int j = 0; j < 4; j++)
                o2[i][j] = __builtin_amdgcn_mfma_f32_16x16x32_bf16(af[i][c], bf[j][c], o2[i][j], 0, 0, 0);
#pragma unroll
    for (int i = 0; i < 4; i++)
#pragma unroll
        for (int j = 0; j < 4; j++)
#pragma unroll
            for (int r = 0; r < 4; r++) {
                int s = i * 16 + lq * 4 + r, d = j * 16 + lm;
                O[(size_t)(b * 64 + s) * 256 + h * 64 + d] = f2b(o2[i][j][r]);
            }
}

__global__ __launch_bounds__(256) void headk(
    const short* __restrict__ h, const float* __restrict__ ow,
    const float* __restrict__ ob, float* __restrict__ out)
{
    int b = blockIdx.x, t = threadIdx.x;
    float acc = 0.f;
    for (int s = 0; s < SS; s++) acc += b2f(h[((size_t)(b * SS + s)) * WW + t]);
    __shared__ float mean[256];
    mean[t] = acc * (1.f / 64.f);
    __syncthreads();
    if (t < 3) {
        float o = ob[t];
        for (int w = 0; w < WW; w++) o += mean[w] * ow[w * 3 + t];
        out[b * 3 + t] = o;
    }
}

// ---------------------------------------------------------------------------
#define GEMM_BF(TMv,TNv,WMv,WNv, A,Bt,bias,C,M,N,K,ldc,relu) \
  gemm_mfma<TMv,TNv,WMv,WNv,true><<<dim3((N)/(TNv),(M)/(TMv)),256,0,stream>>>((A),(Bt),(bias),nullptr,nullptr,(C),(M),(N),(K),(ldc),(relu))
#define GEMM_F(TMv,TNv,WMv,WNv, A,Bt,bias,res,C,M,N,K,relu) \
  gemm_mfma<TMv,TNv,WMv,WNv,false><<<dim3((N)/(TNv),(M)/(TMv)),256,0,stream>>>((A),(Bt),(bias),(res),(C),nullptr,(M),(N),(K),(N),(relu))

extern "C" void kernel_launch(void* const* d_in, const int* in_sizes, int n_in,
                              void* d_out, int out_size, void* d_ws, size_t ws_size,
                              hipStream_t stream)
{
    const float* rgb_feat   = (const float*)d_in[0];
    const float* ray_diff   = (const float*)d_in[1];
    const int*   maskp      = (const int*)d_in[2];
    const float* pts        = (const float*)d_in[3];
    const float* ray_d      = (const float*)d_in[4];
    const float* rgbfeat_w1 = (const float*)d_in[5];
    const float* rgbfeat_b1 = (const float*)d_in[6];
    const float* rgbfeat_w2 = (const float*)d_in[7];
    const float* rgbfeat_b2 = (const float*)d_in[8];
    const float* c_ln_g = (const float*)d_in[9];
    const float* c_ln_b = (const float*)d_in[10];
    const float* c_qw   = (const float*)d_in[11];
    const float* c_kw   = (const float*)d_in[12];
    const float* c_vw   = (const float*)d_in[13];
    const float* c_pw1  = (const float*)d_in[14];
    const float* c_pb1  = (const float*)d_in[15];
    const float* c_pw2  = (const float*)d_in[16];
    const float* c_pb2  = (const float*)d_in[17];
    const float* c_aw1  = (const float*)d_in[18];
    const float* c_ab1  = (const float*)d_in[19];
    const float* c_aw2  = (const float*)d_in[20];
    const float* c_ab2  = (const float*)d_in[21];
    const float* c_ow   = (const float*)d_in[22];
    const float* c_ob   = (const float*)d_in[23];
    const float* c_fg   = (const float*)d_in[24];
    const float* c_fb   = (const float*)d_in[25];
    const float* c_fw1  = (const float*)d_in[26];
    const float* c_fb1  = (const float*)d_in[27];
    const float* c_fw2  = (const float*)d_in[28];
    const float* c_fb2  = (const float*)d_in[29];
    const float* s_ln_g = (const float*)d_in[30];
    const float* s_ln_b = (const float*)d_in[31];
    const float* s_qw   = (const float*)d_in[32];
    const float* s_kw   = (const float*)d_in[33];
    const float* s_vw   = (const float*)d_in[34];
    const float* s_ow   = (const float*)d_in[35];
    const float* s_ob   = (const float*)d_in[36];
    const float* s_fg   = (const float*)d_in[37];
    const float* s_fb   = (const float*)d_in[38];
    const float* s_fw1  = (const float*)d_in[39];
    const float* s_fb1  = (const float*)d_in[40];
    const float* s_fw2  = (const float*)d_in[41];
    const float* s_fb2  = (const float*)d_in[42];
    const float* q_w1   = (const float*)d_in[43];
    const float* q_b1   = (const float*)d_in[44];
    const float* q_w2   = (const float*)d_in[45];
    const float* q_b2   = (const float*)d_in[46];
    const float* norm_g = (const float*)d_in[47];
    const float* norm_b = (const float*)d_in[48];
    const float* out_w  = (const float*)d_in[49];
    const float* out_b  = (const float*)d_in[50];
    float* out = (float*)d_out;

    // ---- workspace carve (256B aligned) ----
    char* p = (char*)d_ws;
    auto alloc = [&](size_t bytes) { char* r = p; p += (bytes + 255) & ~(size_t)255; return r; };
    short* rgbf  = (short*)alloc((size_t)BSV * 256 * 2);
    short* hall  = (short*)alloc((size_t)DD * BSV * 32 * 2);
    short* a_in  = (short*)alloc((size_t)BSV * 256 * 2);
    short* obb   = (short*)alloc((size_t)BS * 256 * 2);
    short* xq    = (short*)alloc((size_t)BS * 256 * 2);
    short* hb    = (short*)alloc((size_t)BS * 256 * 2);
    short* catb  = (short*)alloc((size_t)BS * 384 * 2);
    short* qkv   = (short*)alloc((size_t)BS * 768 * 2);
    short* rgbp  = qkv;
    float* qf    = (float*)alloc((size_t)BS * 256 * 4);
    float* fq    = (float*)alloc((size_t)BS * 256 * 4);
    // weights (bf16, transposed [N,Kpad])
    short* w1T   = (short*)alloc(256 * 64 * 2);
    short* w2T   = (short*)alloc(256 * 256 * 2);
    short* qwT   = (short*)alloc((size_t)DD * 256 * 256 * 2);
    short* kvpT  = (short*)alloc((size_t)DD * 512 * 288 * 2);
    short* aw1T  = (short*)alloc((size_t)DD * 32 * 256 * 2);
    short* aw2T  = (short*)alloc((size_t)DD * 256 * 32 * 2);
    short* owT   = (short*)alloc((size_t)DD * 256 * 256 * 2);
    short* fw1T  = (short*)alloc((size_t)DD * 1024 * 256 * 2);
    short* fw2T  = (short*)alloc((size_t)DD * 256 * 1024 * 2);
    short* sqkvT = (short*)alloc((size_t)DD * 768 * 256 * 2);
    short* sowT  = (short*)alloc((size_t)DD * 256 * 256 * 2);
    short* sfw1T = (short*)alloc((size_t)DD * 1024 * 256 * 2);
    short* sfw2T = (short*)alloc((size_t)DD * 256 * 1024 * 2);
    short* qw1T  = (short*)alloc((size_t)4 * 256 * 384 * 2);
    short* qw2T  = (short*)alloc((size_t)4 * 256 * 256 * 2);

    // ---- batched weight conversion (one dispatch) ----
    WJobs wj; int nj = 0, totblk = 0;
    auto addj = [&](const float* s, short* d, int K, int N, int Kpad,
                    int zi, size_t zo, int gy, int nz) {
        WJob& J = wj.j[nj++];
        J.src = s; J.dst = d; J.K = K; J.N = N; J.Kpad = Kpad;
        J.zi = zi; J.zo = zo; J.gy = gy; J.nblk = (N >> 5) * gy * nz;
        totblk += J.nblk;
    };
    addj(rgbfeat_w1, w1T, 35, 256, 64, 0, 0, 2, 1);
    addj(rgbfeat_w2, w2T, 256, 256, 256, 0, 0, 8, 1);
    addj(c_qw, qwT, 256, 256, 256, 65536, 65536, 8, DD);
    addj(c_kw, kvpT, 256, 256, 288, 65536, 147456, 8, DD);
    addj(c_pw2, kvpT + 256, 32, 256, 288, 8192, 147456, 1, DD);
    addj(c_vw, kvpT + 256 * 288, 256, 256, 288, 65536, 147456, 8, DD);
    addj(c_pw2, kvpT + 256 * 288 + 256, 32, 256, 288, 8192, 147456, 1, DD);
    addj(c_aw1, aw1T, 256, 32, 256, 8192, 8192, 8, DD);
    addj(c_aw2, aw2T, 32, 256, 32, 8192, 8192, 1, DD);
    addj(c_ow, owT, 256, 256, 256, 65536, 65536, 8, DD);
    addj(c_fw1, fw1T, 256, 1024, 256, 262144, 262144, 8, DD);
    addj(c_fw2, fw2T, 1024, 256, 1024, 262144, 262144, 32, DD);
    addj(s_qw, sqkvT, 256, 256, 256, 65536, 196608, 8, DD);
    addj(s_kw, sqkvT + 65536, 256, 256, 256, 65536, 196608, 8, DD);
    addj(s_vw, sqkvT + 131072, 256, 256, 256, 65536, 196608, 8, DD);
    addj(s_ow, sowT, 256, 256, 256, 65536, 65536, 8, DD);
    addj(s_fw1, sfw1T, 256, 1024, 256, 262144, 262144, 8, DD);
    addj(s_fw2, sfw2T, 1024, 256, 1024, 262144, 262144, 32, DD);
    addj(q_w1, qw1T, 346, 256, 384, 88576, 98304, 12, 4);
    addj(q_w2, qw2T, 256, 256, 256, 65536, 65536, 8, 4);
    wconv_all<<<totblk, dim3(32, 8), 0, stream>>>(wj);

    // ---- preamble ----
    catpenc<<<(BS * 128) / 256, 256, 0, stream>>>(pts, ray_d, catb);
    rgbhall<<<(BSV * 64 + DD * BSV * 32) / 256, 256, 0, stream>>>(
        rgb_feat, ray_diff, c_pw1, c_pb1, rgbp, hall);
    GEMM_BF(128, 128, 64, 64, rgbp, w1T, rgbfeat_b1, a_in, BSV, 256, 64, 256, 1);
    GEMM_BF(128, 128, 64, 64, a_in, w2T, rgbfeat_b2, rgbf, BSV, 256, 256, 256, 0);
    vmaxln<<<BS, 256, 0, stream>>>(rgbf, c_ln_g, c_ln_b, fq, xq);
    GEMM_F(64, 64, 32, 32, xq, qwT, nullptr, nullptr, qf, BS, 256, 256, 0);

    for (int i = 0; i < DD; i++) {
        int j = i >> 1;
        crosskv<<<BSV / 32, 256, 0, stream>>>(
            rgbf, hall + (size_t)i * BSV * 32, kvpT + (size_t)i * 147456,
            qf, maskp,
            aw1T + (size_t)i * 8192, c_ab1 + i * 32,
            aw2T + (size_t)i * 8192, c_ab2 + i * 256, obb);
        chainA<<<256, 256, 0, stream>>>(obb, fq, catb, qkv,
            owT + (size_t)i * 65536, c_ob + i * 256, c_fg + i * 256, c_fb + i * 256,
            fw1T + (size_t)i * 262144, c_fb1 + i * 1024,
            fw2T + (size_t)i * 262144, c_fb2 + i * 256,
            qw1T + (size_t)j * 98304, q_b1 + j * 256,
            qw2T + (size_t)j * 65536, q_b2 + j * 256,
            s_ln_g + i * 256, s_ln_b + i * 256,
            sqkvT + (size_t)i * 196608, !(i & 1));
        attn_mfma<<<BB * 4, 64, 0, stream>>>(qkv, obb);
        int last = (i == DD - 1);
        chainB<<<256, 256, 0, stream>>>(obb, fq,
            sowT + (size_t)i * 65536, s_ob + i * 256, s_fg + i * 256, s_fb + i * 256,
            sfw1T + (size_t)i * 262144, s_fb1 + i * 1024,
            sfw2T + (size_t)i * 262144, s_fb2 + i * 256,
            last ? norm_g : c_ln_g + (i + 1) * 256,
            last ? norm_b : c_ln_b + (i + 1) * 256,
            last ? 1e-5f : 1e-6f,
            last ? nullptr : qwT + (size_t)(i + 1) * 65536,
            qf, last ? hb : nullptr);
    }

    headk<<<BB, 256, 0, stream>>>(hb, out_w, out_b, out);
}

// Round 12
// 1196.625 us; speedup vs baseline: 1.5481x; 1.2263x over previous
//
#include <hip/hip_runtime.h>
#include <hip/hip_bf16.h>
#include <math.h>

#define BB 64
#define SS 64
#define VV 8
#define WW 256
#define DD 8
#define BS (BB*SS)        // 4096
#define BSV (BB*SS*VV)    // 32768

#define RB 392            // rowbuf stride (shorts)
#define HBs 1064          // hid stride
#define TB 264            // tmpb stride
#define AS 296            // crosskv A stride

typedef __attribute__((ext_vector_type(8))) short s8v;
typedef __attribute__((ext_vector_type(4))) float f4v;

__device__ __forceinline__ short f2b(float f) {
    __hip_bfloat16 h = __float2bfloat16(f);
    return *reinterpret_cast<short*>(&h);
}
__device__ __forceinline__ float b2f(short s) {
    __hip_bfloat16 h = *reinterpret_cast<__hip_bfloat16*>(&s);
    return __bfloat162float(h);
}

// ---------------------------------------------------------------------------
// One 16x16 output tile over K. A from LDS (16 rows, stride lda).
// B in FRAGMENT-PACKED layout: bF[(k*64+lane)*8] -> one contiguous 1KB
// burst per wave per MFMA (fixes the 16-line scatter of row-major B^T).
// ---------------------------------------------------------------------------
__device__ __forceinline__ f4v rowgemm(const short* __restrict__ aL, int lda,
                                       const short* __restrict__ bF,
                                       int ksteps, int lane)
{
    int lm = lane & 15, lq = lane >> 4;
    f4v acc = (f4v){0.f, 0.f, 0.f, 0.f};
#pragma unroll 8
    for (int k = 0; k < ksteps; k++) {
        s8v a = *(const s8v*)&aL[lm * lda + k * 32 + lq * 8];
        s8v b = *(const s8v*)&bF[(size_t)(k * 64 + lane) * 8];
        acc = __builtin_amdgcn_mfma_f32_16x16x32_bf16(a, b, acc, 0, 0, 0);
    }
    return acc;
}

// ---------------------------------------------------------------------------
// In-block LayerNorm of 16 rows x 256 cols held in registers v[t][r].
// ---------------------------------------------------------------------------
__device__ __forceinline__ void ln_rows(
    float v[4][4], const float* __restrict__ g, const float* __restrict__ b,
    float eps, short* rowbuf, float* red, int w, int lm, int lq,
    short* __restrict__ outG, int row0)
{
    float ps[4] = {0.f, 0.f, 0.f, 0.f};
#pragma unroll
    for (int t = 0; t < 4; t++)
#pragma unroll
        for (int r = 0; r < 4; r++) ps[r] += v[t][r];
#pragma unroll
    for (int m = 1; m < 16; m <<= 1)
#pragma unroll
        for (int r = 0; r < 4; r++) ps[r] += __shfl_xor(ps[r], m);
    if (lm == 0)
#pragma unroll
        for (int r = 0; r < 4; r++) red[(lq * 4 + r) * 4 + w] = ps[r];
    __syncthreads();
    float mean[4];
#pragma unroll
    for (int r = 0; r < 4; r++) {
        int row = lq * 4 + r;
        mean[r] = (red[row * 4] + red[row * 4 + 1] + red[row * 4 + 2] + red[row * 4 + 3]) * (1.f / 256.f);
    }
    __syncthreads();
    float pq[4] = {0.f, 0.f, 0.f, 0.f};
#pragma unroll
    for (int t = 0; t < 4; t++)
#pragma unroll
        for (int r = 0; r < 4; r++) { float d = v[t][r] - mean[r]; pq[r] += d * d; }
#pragma unroll
    for (int m = 1; m < 16; m <<= 1)
#pragma unroll
        for (int r = 0; r < 4; r++) pq[r] += __shfl_xor(pq[r], m);
    if (lm == 0)
#pragma unroll
        for (int r = 0; r < 4; r++) red[(lq * 4 + r) * 4 + w] = pq[r];
    __syncthreads();
    float inv[4];
#pragma unroll
    for (int r = 0; r < 4; r++) {
        int row = lq * 4 + r;
        float var = (red[row * 4] + red[row * 4 + 1] + red[row * 4 + 2] + red[row * 4 + 3]) * (1.f / 256.f);
        inv[r] = rsqrtf(var + eps);
    }
#pragma unroll
    for (int t = 0; t < 4; t++) {
        int col = (w * 4 + t) * 16 + lm;
        float gc = g[col], bc = b[col];
#pragma unroll
        for (int r = 0; r < 4; r++) {
            float val = (v[t][r] - mean[r]) * inv[r] * gc + bc;
            rowbuf[(lq * 4 + r) * RB + col] = f2b(val);
            if (outG) outG[(size_t)(row0 + lq * 4 + r) * 256 + col] = f2b(val);
        }
    }
    __syncthreads();
}

// ---------------------------------------------------------------------------
// chainA: ow+res -> LN(c_fg) -> fw1 -> fw2+res -> [even: cat->q1->q2]
//         -> write fq -> LN(s_ln) -> sqkv.  Block = 16 rows, grid 256.
// All weights fragment-packed.
// ---------------------------------------------------------------------------
__global__ __launch_bounds__(256) void chainA(
    const short* __restrict__ obb, float* __restrict__ fq,
    const short* __restrict__ catb, short* __restrict__ qkv,
    const short* __restrict__ owT, const float* __restrict__ c_ob,
    const float* __restrict__ c_fg, const float* __restrict__ c_fb,
    const short* __restrict__ fw1T, const float* __restrict__ c_fb1,
    const short* __restrict__ fw2T, const float* __restrict__ c_fb2,
    const short* __restrict__ qw1T, const float* __restrict__ q_b1,
    const short* __restrict__ qw2T, const float* __restrict__ q_b2,
    const float* __restrict__ s_ln_g, const float* __restrict__ s_ln_b,
    const short* __restrict__ sqkvT, int even)
{
    __shared__ __align__(16) short rowbuf[16 * RB];
    __shared__ __align__(16) short hid[16 * HBs];
    __shared__ __align__(16) short tmpb[16 * TB];
    __shared__ float red[64];
    int tid = threadIdx.x, lane = tid & 63, w = tid >> 6;
    int lm = lane & 15, lq = lane >> 4;
    int row0 = blockIdx.x * 16;
    {
        int r = tid >> 4, c = (tid & 15) * 16;
        *(s8v*)&rowbuf[r * RB + c]     = *(const s8v*)&obb[(size_t)(row0 + r) * 256 + c];
        *(s8v*)&rowbuf[r * RB + c + 8] = *(const s8v*)&obb[(size_t)(row0 + r) * 256 + c + 8];
    }
    __syncthreads();
    float fqreg[4][4];
    {
        f4v o[4];
#pragma unroll
        for (int t = 0; t < 4; t++)
            o[t] = rowgemm(rowbuf, RB, owT + (size_t)(w * 4 + t) * 4096, 8, lane);
#pragma unroll
        for (int t = 0; t < 4; t++) {
            int col = (w * 4 + t) * 16 + lm;
            float bb = c_ob[col];
#pragma unroll
            for (int r = 0; r < 4; r++)
                fqreg[t][r] = o[t][r] + bb + fq[(size_t)(row0 + lq * 4 + r) * 256 + col];
        }
    }
    ln_rows(fqreg, c_fg, c_fb, 1e-6f, rowbuf, red, w, lm, lq, nullptr, row0);
#pragma unroll
    for (int t = 0; t < 16; t++) {
        f4v o = rowgemm(rowbuf, RB, fw1T + (size_t)(w * 16 + t) * 4096, 8, lane);
        int col = (w * 16 + t) * 16 + lm;
        float bb = c_fb1[col];
#pragma unroll
        for (int r = 0; r < 4; r++)
            hid[(lq * 4 + r) * HBs + col] = f2b(fmaxf(o[r] + bb, 0.f));
    }
    __syncthreads();
    {
        f4v o[4];
#pragma unroll
        for (int t = 0; t < 4; t++)
            o[t] = rowgemm(hid, HBs, fw2T + (size_t)(w * 4 + t) * 16384, 32, lane);
#pragma unroll
        for (int t = 0; t < 4; t++) {
            int col = (w * 4 + t) * 16 + lm;
            float bb = c_fb2[col];
#pragma unroll
            for (int r = 0; r < 4; r++)
                fqreg[t][r] = o[t][r] + bb + fqreg[t][r];
        }
    }
    if (even) {
#pragma unroll
        for (int t = 0; t < 4; t++) {
            int col = (w * 4 + t) * 16 + lm;
#pragma unroll
            for (int r = 0; r < 4; r++)
                rowbuf[(lq * 4 + r) * RB + col] = f2b(fqreg[t][r]);
        }
        {
            int r = tid >> 4, c = (tid & 15) * 8;
            *(s8v*)&rowbuf[r * RB + 256 + c] = *(const s8v*)&catb[(size_t)(row0 + r) * 384 + 256 + c];
        }
        __syncthreads();
#pragma unroll
        for (int t = 0; t < 4; t++) {
            f4v o = rowgemm(rowbuf, RB, qw1T + (size_t)(w * 4 + t) * 6144, 12, lane);
            int col = (w * 4 + t) * 16 + lm;
            float bb = q_b1[col];
#pragma unroll
            for (int r = 0; r < 4; r++)
                tmpb[(lq * 4 + r) * TB + col] = f2b(fmaxf(o[r] + bb, 0.f));
        }
        __syncthreads();
        f4v o[4];
#pragma unroll
        for (int t = 0; t < 4; t++)
            o[t] = rowgemm(tmpb, TB, qw2T + (size_t)(w * 4 + t) * 4096, 8, lane);
#pragma unroll
        for (int t = 0; t < 4; t++) {
            int col = (w * 4 + t) * 16 + lm;
            float bb = q_b2[col];
#pragma unroll
            for (int r = 0; r < 4; r++)
                fqreg[t][r] = o[t][r] + bb;
        }
    }
#pragma unroll
    for (int t = 0; t < 4; t++) {
        int col = (w * 4 + t) * 16 + lm;
#pragma unroll
        for (int r = 0; r < 4; r++)
            fq[(size_t)(row0 + lq * 4 + r) * 256 + col] = fqreg[t][r];
    }
    ln_rows(fqreg, s_ln_g, s_ln_b, 1e-6f, rowbuf, red, w, lm, lq, nullptr, row0);
#pragma unroll
    for (int t = 0; t < 12; t++) {
        f4v o = rowgemm(rowbuf, RB, sqkvT + (size_t)(w * 12 + t) * 4096, 8, lane);
        int col = (w * 12 + t) * 16 + lm;
#pragma unroll
        for (int r = 0; r < 4; r++)
            qkv[(size_t)(row0 + lq * 4 + r) * 768 + col] = f2b(o[r]);
    }
}

// ---------------------------------------------------------------------------
// chainB: sow+res -> LN(s_fg) -> sfw1 -> sfw2+res -> write fq ->
//         LN(next c_ln | final norm[->hb]) -> qw_next -> qf.
// ---------------------------------------------------------------------------
__global__ __launch_bounds__(256) void chainB(
    const short* __restrict__ obb, float* __restrict__ fq,
    const short* __restrict__ sowT, const float* __restrict__ s_ob,
    const float* __restrict__ s_fg, const float* __restrict__ s_fb,
    const short* __restrict__ sfw1T, const float* __restrict__ s_fb1,
    const short* __restrict__ sfw2T, const float* __restrict__ s_fb2,
    const float* __restrict__ ln2_g, const float* __restrict__ ln2_b, float eps2,
    const short* __restrict__ qwTn, float* __restrict__ qf,
    short* __restrict__ hbG)
{
    __shared__ __align__(16) short rowbuf[16 * RB];
    __shared__ __align__(16) short hid[16 * HBs];
    __shared__ float red[64];
    int tid = threadIdx.x, lane = tid & 63, w = tid >> 6;
    int lm = lane & 15, lq = lane >> 4;
    int row0 = blockIdx.x * 16;
    {
        int r = tid >> 4, c = (tid & 15) * 16;
        *(s8v*)&rowbuf[r * RB + c]     = *(const s8v*)&obb[(size_t)(row0 + r) * 256 + c];
        *(s8v*)&rowbuf[r * RB + c + 8] = *(const s8v*)&obb[(size_t)(row0 + r) * 256 + c + 8];
    }
    __syncthreads();
    float fqreg[4][4];
    {
        f4v o[4];
#pragma unroll
        for (int t = 0; t < 4; t++)
            o[t] = rowgemm(rowbuf, RB, sowT + (size_t)(w * 4 + t) * 4096, 8, lane);
#pragma unroll
        for (int t = 0; t < 4; t++) {
            int col = (w * 4 + t) * 16 + lm;
            float bb = s_ob[col];
#pragma unroll
            for (int r = 0; r < 4; r++)
                fqreg[t][r] = o[t][r] + bb + fq[(size_t)(row0 + lq * 4 + r) * 256 + col];
        }
    }
    ln_rows(fqreg, s_fg, s_fb, 1e-6f, rowbuf, red, w, lm, lq, nullptr, row0);
#pragma unroll
    for (int t = 0; t < 16; t++) {
        f4v o = rowgemm(rowbuf, RB, sfw1T + (size_t)(w * 16 + t) * 4096, 8, lane);
        int col = (w * 16 + t) * 16 + lm;
        float bb = s_fb1[col];
#pragma unroll
        for (int r = 0; r < 4; r++)
            hid[(lq * 4 + r) * HBs + col] = f2b(fmaxf(o[r] + bb, 0.f));
    }
    __syncthreads();
    {
        f4v o[4];
#pragma unroll
        for (int t = 0; t < 4; t++)
            o[t] = rowgemm(hid, HBs, sfw2T + (size_t)(w * 4 + t) * 16384, 32, lane);
#pragma unroll
        for (int t = 0; t < 4; t++) {
            int col = (w * 4 + t) * 16 + lm;
            float bb = s_fb2[col];
#pragma unroll
            for (int r = 0; r < 4; r++)
                fqreg[t][r] = o[t][r] + bb + fqreg[t][r];
        }
    }
#pragma unroll
    for (int t = 0; t < 4; t++) {
        int col = (w * 4 + t) * 16 + lm;
#pragma unroll
        for (int r = 0; r < 4; r++)
            fq[(size_t)(row0 + lq * 4 + r) * 256 + col] = fqreg[t][r];
    }
    ln_rows(fqreg, ln2_g, ln2_b, eps2, rowbuf, red, w, lm, lq, hbG, row0);
    if (qwTn) {
#pragma unroll
        for (int t = 0; t < 4; t++) {
            f4v o = rowgemm(rowbuf, RB, qwTn + (size_t)(w * 4 + t) * 4096, 8, lane);
            int col = (w * 4 + t) * 16 + lm;
#pragma unroll
            for (int r = 0; r < 4; r++)
                qf[(size_t)(row0 + lq * 4 + r) * 256 + col] = o[r];
        }
    }
}

// layer-0 q projection: qf = xq @ qw0 (frag-packed), block = 16 rows
__global__ __launch_bounds__(256) void qgemm0(
    const short* __restrict__ xq, const short* __restrict__ qwT0,
    float* __restrict__ qf)
{
    __shared__ __align__(16) short rowbuf[16 * TB];
    int tid = threadIdx.x, lane = tid & 63, w = tid >> 6;
    int lm = lane & 15, lq = lane >> 4;
    int row0 = blockIdx.x * 16;
    {
        int r = tid >> 4, c = (tid & 15) * 16;
        *(s8v*)&rowbuf[r * TB + c]     = *(const s8v*)&xq[(size_t)(row0 + r) * 256 + c];
        *(s8v*)&rowbuf[r * TB + c + 8] = *(const s8v*)&xq[(size_t)(row0 + r) * 256 + c + 8];
    }
    __syncthreads();
#pragma unroll
    for (int t = 0; t < 4; t++) {
        f4v o = rowgemm(rowbuf, TB, qwT0 + (size_t)(w * 4 + t) * 4096, 8, lane);
        int col = (w * 4 + t) * 16 + lm;
#pragma unroll
        for (int r = 0; r < 4; r++)
            qf[(size_t)(row0 + lq * 4 + r) * 256 + col] = o[r];
    }
}

// ---------------------------------------------------------------------------
// crosskv: fused kv-projection + cross-attention. Block = 32 kv rows
// (4 samples), grid 1024. All weights fragment-packed (kvp KS=9).
// ---------------------------------------------------------------------------
__global__ __launch_bounds__(256) void crosskv(
    const short* __restrict__ rgbf, const short* __restrict__ hall_l,
    const short* __restrict__ kvpT_l, const float* __restrict__ qf,
    const int* __restrict__ mask,
    const short* __restrict__ aw1T_l, const float* __restrict__ ab1,
    const short* __restrict__ aw2T_l, const float* __restrict__ ab2,
    short* __restrict__ obb)
{
    __shared__ __align__(16) short A_s[32 * AS];
    __shared__ __align__(16) short a_s[32 * 264];
    __shared__ __align__(16) short ph_s[32 * 40];
    __shared__ int msk[32];
    int blk = blockIdx.x, tid = threadIdx.x;
    int row0 = blk * 32, bs0 = blk * 4;
    int lane = tid & 63, w = tid >> 6, lm = lane & 15, lq = lane >> 4;
    if (tid < 32) msk[tid] = mask[bs0 * 8 + tid];
#pragma unroll
    for (int i = 0; i < 4; i++) {
        int e = tid + i * 256;
        int r = e >> 5, c = (e & 31) << 3;
        *(s8v*)&A_s[r * AS + c] = *(const s8v*)&rgbf[(size_t)(row0 + r) * 256 + c];
    }
    if (tid < 128) {
        int r = tid >> 2, c = (tid & 3) << 3;
        *(s8v*)&A_s[r * AS + 256 + c] = *(const s8v*)&hall_l[(size_t)(row0 + r) * 32 + c];
    }
    __syncthreads();
    // k-half: ntile = w*4+j4
#pragma unroll
    for (int j4 = 0; j4 < 4; j4++) {
        int nt = w * 4 + j4;
#pragma unroll
        for (int i = 0; i < 2; i++) {
            f4v acc = rowgemm(&A_s[i * 16 * AS], AS, kvpT_l + (size_t)nt * 9 * 512, 9, lane);
#pragma unroll
            for (int r = 0; r < 4; r++) {
                int row = i * 16 + lq * 4 + r, col = nt * 16 + lm;
                float q = qf[(size_t)(bs0 + (row >> 3)) * 256 + col];
                a_s[row * 264 + col] = f2b(acc[r] - q);
            }
        }
    }
    __syncthreads();
    // ph = relu(a_in @ aw1 + ab1)
    {
        int i = w >> 1, j = w & 1;
        f4v acc = rowgemm(&a_s[i * 16 * 264], 264, aw1T_l + (size_t)j * 4096, 8, lane);
        int col = j * 16 + lm;
        float bb = ab1[col];
#pragma unroll
        for (int r = 0; r < 4; r++)
            ph_s[(i * 16 + lq * 4 + r) * 40 + col] = f2b(fmaxf(acc[r] + bb, 0.f));
    }
    __syncthreads();
    // a3 = ph @ aw2 (KS=1)
    f4v a3[2][4];
#pragma unroll
    for (int i = 0; i < 2; i++) {
#pragma unroll
        for (int j4 = 0; j4 < 4; j4++) {
            int nt = w * 4 + j4;
            a3[i][j4] = rowgemm(&ph_s[i * 16 * 40], 40, aw2T_l + (size_t)nt * 512, 1, lane);
        }
    }
    // v-half: ntile = 16 + w*4+j4
#pragma unroll
    for (int j4 = 0; j4 < 4; j4++) {
        int nt = w * 4 + j4;
#pragma unroll
        for (int i = 0; i < 2; i++) {
            f4v acc = rowgemm(&A_s[i * 16 * AS], AS, kvpT_l + (size_t)(16 + nt) * 9 * 512, 9, lane);
#pragma unroll
            for (int r = 0; r < 4; r++)
                a_s[(i * 16 + lq * 4 + r) * 264 + nt * 16 + lm] = f2b(acc[r]);
        }
    }
    __syncthreads();
    // masked softmax over views + weighted sum
#pragma unroll
    for (int i = 0; i < 2; i++) {
        int sample = i * 2 + (lq >> 1);
        int mk[4];
#pragma unroll
        for (int r = 0; r < 4; r++) mk[r] = msk[sample * 8 + (lq & 1) * 4 + r];
#pragma unroll
        for (int j4 = 0; j4 < 4; j4++) {
            int col = (w * 4 + j4) * 16 + lm;
            float bv = ab2[col];
            float vals[4];
#pragma unroll
            for (int r = 0; r < 4; r++) vals[r] = mk[r] ? (a3[i][j4][r] + bv) : -1e9f;
            float mx = fmaxf(fmaxf(vals[0], vals[1]), fmaxf(vals[2], vals[3]));
            mx = fmaxf(mx, __shfl_xor(mx, 16));
            float ev[4], s = 0.f;
#pragma unroll
            for (int r = 0; r < 4; r++) { ev[r] = expf(vals[r] - mx); s += ev[r]; }
            s += __shfl_xor(s, 16);
            float o = 0.f;
#pragma unroll
            for (int r = 0; r < 4; r++)
                o += ev[r] * b2f(a_s[(i * 16 + lq * 4 + r) * 264 + col]);
            o += __shfl_xor(o, 16);
            o /= s;
            if (!(lq & 1)) obb[(size_t)(bs0 + sample) * 256 + col] = f2b(o);
        }
    }
}

// ---------------------------------------------------------------------------
// bf16 MFMA GEMM (BK=32, LDS stride 40) — preamble only (row-major B^T).
// ---------------------------------------------------------------------------
template<int TM, int TN, int WM, int WN, bool OUTBF>
__global__ __launch_bounds__(256) void gemm_mfma(
    const short* __restrict__ A, const short* __restrict__ Bt,
    const float* __restrict__ bias, const float* __restrict__ res,
    float* __restrict__ Cf, short* __restrict__ Cb,
    int M, int N, int K, int ldc, int relu)
{
    constexpr int MT  = WM / 16;
    constexpr int NT  = WN / 16;
    constexpr int RWN = TN / WN;
    __shared__ __align__(16) short As[TM * 40];
    __shared__ __align__(16) short Bs[TN * 40];
    int tid = threadIdx.x;
    int m0 = blockIdx.y * TM, n0 = blockIdx.x * TN;
    int lane = tid & 63, w = tid >> 6;
    int lm = lane & 15, lq = lane >> 4;
    int wm = (w / RWN) * WM, wn = (w % RWN) * WN;
    f4v acc[MT][NT];
#pragma unroll
    for (int i = 0; i < MT; i++)
#pragma unroll
        for (int j = 0; j < NT; j++) acc[i][j] = (f4v){0.f, 0.f, 0.f, 0.f};

    for (int k0 = 0; k0 < K; k0 += 32) {
        for (int c = tid; c < TM * 4; c += 256) {
            int r = c >> 2, kc = (c & 3) << 3;
            *(s8v*)&As[r * 40 + kc] = *(const s8v*)&A[(size_t)(m0 + r) * K + k0 + kc];
        }
        for (int c = tid; c < TN * 4; c += 256) {
            int r = c >> 2, kc = (c & 3) << 3;
            *(s8v*)&Bs[r * 40 + kc] = *(const s8v*)&Bt[(size_t)(n0 + r) * K + k0 + kc];
        }
        __syncthreads();
        s8v af[MT], bfv[NT];
#pragma unroll
        for (int i = 0; i < MT; i++)
            af[i] = *(const s8v*)&As[(wm + i * 16 + lm) * 40 + lq * 8];
#pragma unroll
        for (int j = 0; j < NT; j++)
            bfv[j] = *(const s8v*)&Bs[(wn + j * 16 + lm) * 40 + lq * 8];
#pragma unroll
        for (int i = 0; i < MT; i++)
#pragma unroll
            for (int j = 0; j < NT; j++)
                acc[i][j] = __builtin_amdgcn_mfma_f32_16x16x32_bf16(af[i], bfv[j], acc[i][j], 0, 0, 0);
        __syncthreads();
    }
#pragma unroll
    for (int i = 0; i < MT; i++) {
        int row = m0 + wm + i * 16 + lq * 4;
#pragma unroll
        for (int j = 0; j < NT; j++) {
            int col = n0 + wn + j * 16 + lm;
            float bv = bias ? bias[col] : 0.f;
#pragma unroll
            for (int r = 0; r < 4; r++) {
                float v = acc[i][j][r] + bv;
                if (relu) v = fmaxf(v, 0.f);
                size_t idx = (size_t)(row + r) * ldc + col;
                if (OUTBF) {
                    Cb[idx] = f2b(v);
                } else {
                    if (res) v += res[idx];
                    Cf[idx] = v;
                }
            }
        }
    }
}

// ---------------------------------------------------------------------------
// Batched weight convert: fp32 [K,N] -> bf16, either row-major [N,Kpad]
// (frag=0) or MFMA-fragment-packed [ntile][kstep][lane][8] (frag=1).
// ---------------------------------------------------------------------------
struct WJob {
    const float* src; short* dst;
    int K, N, KS, ntoff, ksoff, Kpad, zi, gy, nblk, frag;
    size_t zo;
};
struct WJobs { WJob j[20]; };

__global__ void wconv_all(WJobs jobs)
{
    __shared__ float t[32][33];
    int b = blockIdx.x, ji = 0;
    while (b >= jobs.j[ji].nblk) { b -= jobs.j[ji].nblk; ji++; }
    WJob J = jobs.j[ji];
    int gx = J.N >> 5;
    int z = b / (gx * J.gy);
    int rem = b - z * (gx * J.gy);
    int by = rem / gx, bx = rem - by * gx;
    const float* W = J.src + (size_t)z * J.zi;
    short* Wt = J.dst + (size_t)z * J.zo;
    int n0 = bx * 32, k0 = by * 32;
    int tx = threadIdx.x, ty = threadIdx.y;
#pragma unroll
    for (int i = 0; i < 4; i++) {
        int k = k0 + ty + i * 8;
        t[ty + i * 8][tx] = (k < J.K) ? W[(size_t)k * J.N + n0 + tx] : 0.f;
    }
    __syncthreads();
    if (J.frag) {
        if (ty < 4) {
            int n = n0 + tx;
            int nt = J.ntoff + (n >> 4), lmm = n & 15;
            int ks = J.ksoff + (k0 >> 5);
            s8v o;
#pragma unroll
            for (int jj = 0; jj < 8; jj++) o[jj] = f2b(t[ty * 8 + jj][tx]);
            *(s8v*)&Wt[(((size_t)nt * J.KS + ks) * 64 + ty * 16 + lmm) * 8] = o;
        }
    } else {
#pragma unroll
        for (int i = 0; i < 4; i++) {
            int n = n0 + ty + i * 8;
            Wt[(size_t)n * J.Kpad + k0 + tx] = f2b(t[tx][ty + i * 8]);
        }
    }
}

// catb tail computed directly from pts/ray_d (penc inline)
__global__ void catpenc(const float* __restrict__ pts, const float* __restrict__ ray_d,
                        short* __restrict__ catb)
{
    int idx = blockIdx.x * 256 + threadIdx.x;
    int bs = idx >> 7, c = idx & 127;
    float v = 0.f;
    if (c < 63) {
        if (c < 3) v = pts[bs * 3 + c];
        else {
            int e = c - 3; int d, k; bool sn;
            if (e < 30) { d = e / 10; k = e - d * 10; sn = true; }
            else { e -= 30; d = e / 10; k = e - d * 10; sn = false; }
            float ang = pts[bs * 3 + d] * (float)(1 << k);
            v = sn ? sinf(ang) : cosf(ang);
        }
    } else if (c < 90) {
        int e = c - 63, b = bs >> 6;
        float x = ray_d[b * 3], y = ray_d[b * 3 + 1], z = ray_d[b * 3 + 2];
        float inv = rsqrtf(x * x + y * y + z * z);
        float vv[3] = {x * inv, y * inv, z * inv};
        if (e < 3) v = vv[e];
        else if (e < 15) { int d = (e - 3) >> 2, k = (e - 3) & 3; v = sinf(vv[d] * (float)(1 << k)); }
        else { int d = (e - 15) >> 2, k = (e - 15) & 3; v = cosf(vv[d] * (float)(1 << k)); }
    }
    catb[(size_t)bs * 384 + 256 + c] = f2b(v);
}

// rgb_feat pad-convert + hall (all 8 layers) in one launch
__global__ void rgbhall(const float* __restrict__ rgb_feat, const float* __restrict__ rdiff,
                        const float* __restrict__ pw1, const float* __restrict__ pb1,
                        short* __restrict__ rgbp, short* __restrict__ hall)
{
    int idx = blockIdx.x * 256 + threadIdx.x;
    if (idx < BSV * 64) {
        int row = idx >> 6, col = idx & 63;
        rgbp[idx] = f2b(col < 35 ? rgb_feat[row * 35 + col] : 0.f);
    } else {
        int k = idx - BSV * 64;
        int t = k & 31, row = (k >> 5) & (BSV - 1), l = k >> 20;
        float a = pb1[l * 32 + t];
        for (int c = 0; c < 4; c++) a += rdiff[row * 4 + c] * pw1[l * 128 + c * 32 + t];
        hall[k] = f2b(fmaxf(a, 0.f));
    }
}

// view-max + layer-0 LayerNorm fused
__global__ __launch_bounds__(256) void vmaxln(
    const short* __restrict__ rgbf, const float* __restrict__ g,
    const float* __restrict__ b, float* __restrict__ fq, short* __restrict__ xq)
{
    int bs = blockIdx.x, t = threadIdx.x;
    float m = -1e30f;
    for (int v = 0; v < VV; v++) m = fmaxf(m, b2f(rgbf[((size_t)(bs * VV + v)) * 256 + t]));
    fq[(size_t)bs * WW + t] = m;
    __shared__ float red[256];
    red[t] = m;
    __syncthreads();
    for (int s = 128; s > 0; s >>= 1) { if (t < s) red[t] += red[t + s]; __syncthreads(); }
    float mean = red[0] * (1.f / 256.f);
    __syncthreads();
    float d = m - mean;
    red[t] = d * d;
    __syncthreads();
    for (int s = 128; s > 0; s >>= 1) { if (t < s) red[t] += red[t + s]; __syncthreads(); }
    float var = red[0] * (1.f / 256.f);
    xq[(size_t)bs * WW + t] = f2b(d / sqrtf(var + 1e-6f) * g[t] + b[t]);
}

// ---------------------------------------------------------------------------
// MFMA self-attention: one wave per (b,h). QKV packed bf16 [4096,768].
// ---------------------------------------------------------------------------
__global__ __launch_bounds__(64) void attn_mfma(
    const short* __restrict__ QKV, short* __restrict__ O)
{
    __shared__ __align__(16) short P[64 * 72];
    __shared__ __align__(16) short Vt[64 * 72];
    int blk = blockIdx.x;
    int b = blk >> 2, h = blk & 3, lane = threadIdx.x;
    int lm = lane & 15, lq = lane >> 4;
    const short* base = QKV + (size_t)b * 64 * 768 + h * 64;
    {
        const short* vrow = base + 512 + (size_t)lane * 768;
#pragma unroll
        for (int c = 0; c < 8; c++) {
            s8v v = *(const s8v*)&vrow[c * 8];
#pragma unroll
            for (int j = 0; j < 8; j++)
                Vt[(c * 8 + j) * 72 + lane] = v[j];
        }
    }
    s8v qfr[4][2], kf[4][2];
#pragma unroll
    for (int i = 0; i < 4; i++)
#pragma unroll
        for (int c = 0; c < 2; c++) {
            qfr[i][c] = *(const s8v*)&base[(size_t)(i * 16 + lm) * 768 + c * 32 + lq * 8];
            kf[i][c]  = *(const s8v*)&base[(size_t)(i * 16 + lm) * 768 + 256 + c * 32 + lq * 8];
        }
    f4v acc[4][4];
#pragma unroll
    for (int i = 0; i < 4; i++)
#pragma unroll
        for (int j = 0; j < 4; j++) acc[i][j] = (f4v){0.f, 0.f, 0.f, 0.f};
#pragma unroll
    for (int c = 0; c < 2; c++)
#pragma unroll
        for (int i = 0; i < 4; i++)
#pragma unroll
            for (int j = 0; j < 4; j++)
                acc[i][j] = __builtin_amdgcn_mfma_f32_16x16x32_bf16(qfr[i][c], kf[j][c], acc[i][j], 0, 0, 0);
#pragma unroll
    for (int i = 0; i < 4; i++) {
#pragma unroll
        for (int r = 0; r < 4; r++) {
            float lv[4];
#pragma unroll
            for (int j = 0; j < 4; j++) lv[j] = acc[i][j][r] * 0.125f;
            float mx = fmaxf(fmaxf(lv[0], lv[1]), fmaxf(lv[2], lv[3]));
            for (int d = 1; d < 16; d <<= 1) mx = fmaxf(mx, __shfl_xor(mx, d));
            float sum = 0.f;
#pragma unroll
            for (int j = 0; j < 4; j++) { lv[j] = expf(lv[j] - mx); sum += lv[j]; }
            for (int d = 1; d < 16; d <<= 1) sum += __shfl_xor(sum, d);
            float inv = 1.f / sum;
            int row = i * 16 + lq * 4 + r;
#pragma unroll
            for (int j = 0; j < 4; j++)
                P[row * 72 + j * 16 + lm] = f2b(lv[j] * inv);
        }
    }
    __syncthreads();
    s8v af[4][2], bf[4][2];
#pragma unroll
    for (int i = 0; i < 4; i++)
#pragma unroll
        for (int c = 0; c < 2; c++) {
            af[i][c] = *(const s8v*)&P[(i * 16 + lm) * 72 + c * 32 + lq * 8];
            bf[i][c] = *(const s8v*)&Vt[(i * 16 + lm) * 72 + c * 32 + lq * 8];
        }
    f4v o2[4][4];
#pragma unroll
    for (int i = 0; i < 4; i++)
#pragma unroll
        for (int j = 0; j < 4; j++) o2[i][j] = (f4v){0.f, 0.f, 0.f, 0.f};
#pragma unroll
    for (int c = 0; c < 2; c++)
#pragma unroll
        for (int i = 0; i < 4; i++)
#pragma unroll
            for (int j = 0; j < 4; j++)
                o2[i][j] = __builtin_amdgcn_mfma_f32_16x16x32_bf16(af[i][c], bf[j][c], o2[i][j], 0, 0, 0);
#pragma unroll
    for (int i = 0; i < 4; i++)
#pragma unroll
        for (int j = 0; j < 4; j++)
#pragma unroll
            for (int r = 0; r < 4; r++) {
                int s = i * 16 + lq * 4 + r, d = j * 16 + lm;
                O[(size_t)(b * 64 + s) * 256 + h * 64 + d] = f2b(o2[i][j][r]);
            }
}

__global__ __launch_bounds__(256) void headk(
    const short* __restrict__ h, const float* __restrict__ ow,
    const float* __restrict__ ob, float* __restrict__ out)
{
    int b = blockIdx.x, t = threadIdx.x;
    float acc = 0.f;
    for (int s = 0; s < SS; s++) acc += b2f(h[((size_t)(b * SS + s)) * WW + t]);
    __shared__ float mean[256];
    mean[t] = acc * (1.f / 64.f);
    __syncthreads();
    if (t < 3) {
        float o = ob[t];
        for (int w = 0; w < WW; w++) o += mean[w] * ow[w * 3 + t];
        out[b * 3 + t] = o;
    }
}

// ---------------------------------------------------------------------------
#define GEMM_BF(TMv,TNv,WMv,WNv, A,Bt,bias,C,M,N,K,ldc,relu) \
  gemm_mfma<TMv,TNv,WMv,WNv,true><<<dim3((N)/(TNv),(M)/(TMv)),256,0,stream>>>((A),(Bt),(bias),nullptr,nullptr,(C),(M),(N),(K),(ldc),(relu))

extern "C" void kernel_launch(void* const* d_in, const int* in_sizes, int n_in,
                              void* d_out, int out_size, void* d_ws, size_t ws_size,
                              hipStream_t stream)
{
    const float* rgb_feat   = (const float*)d_in[0];
    const float* ray_diff   = (const float*)d_in[1];
    const int*   maskp      = (const int*)d_in[2];
    const float* pts        = (const float*)d_in[3];
    const float* ray_d      = (const float*)d_in[4];
    const float* rgbfeat_w1 = (const float*)d_in[5];
    const float* rgbfeat_b1 = (const float*)d_in[6];
    const float* rgbfeat_w2 = (const float*)d_in[7];
    const float* rgbfeat_b2 = (const float*)d_in[8];
    const float* c_ln_g = (const float*)d_in[9];
    const float* c_ln_b = (const float*)d_in[10];
    const float* c_qw   = (const float*)d_in[11];
    const float* c_kw   = (const float*)d_in[12];
    const float* c_vw   = (const float*)d_in[13];
    const float* c_pw1  = (const float*)d_in[14];
    const float* c_pb1  = (const float*)d_in[15];
    const float* c_pw2  = (const float*)d_in[16];
    const float* c_pb2  = (const float*)d_in[17];
    const float* c_aw1  = (const float*)d_in[18];
    const float* c_ab1  = (const float*)d_in[19];
    const float* c_aw2  = (const float*)d_in[20];
    const float* c_ab2  = (const float*)d_in[21];
    const float* c_ow   = (const float*)d_in[22];
    const float* c_ob   = (const float*)d_in[23];
    const float* c_fg   = (const float*)d_in[24];
    const float* c_fb   = (const float*)d_in[25];
    const float* c_fw1  = (const float*)d_in[26];
    const float* c_fb1  = (const float*)d_in[27];
    const float* c_fw2  = (const float*)d_in[28];
    const float* c_fb2  = (const float*)d_in[29];
    const float* s_ln_g = (const float*)d_in[30];
    const float* s_ln_b = (const float*)d_in[31];
    const float* s_qw   = (const float*)d_in[32];
    const float* s_kw   = (const float*)d_in[33];
    const float* s_vw   = (const float*)d_in[34];
    const float* s_ow   = (const float*)d_in[35];
    const float* s_ob   = (const float*)d_in[36];
    const float* s_fg   = (const float*)d_in[37];
    const float* s_fb   = (const float*)d_in[38];
    const float* s_fw1  = (const float*)d_in[39];
    const float* s_fb1  = (const float*)d_in[40];
    const float* s_fw2  = (const float*)d_in[41];
    const float* s_fb2  = (const float*)d_in[42];
    const float* q_w1   = (const float*)d_in[43];
    const float* q_b1   = (const float*)d_in[44];
    const float* q_w2   = (const float*)d_in[45];
    const float* q_b2   = (const float*)d_in[46];
    const float* norm_g = (const float*)d_in[47];
    const float* norm_b = (const float*)d_in[48];
    const float* out_w  = (const float*)d_in[49];
    const float* out_b  = (const float*)d_in[50];
    float* out = (float*)d_out;

    // ---- workspace carve (256B aligned) ----
    char* p = (char*)d_ws;
    auto alloc = [&](size_t bytes) { char* r = p; p += (bytes + 255) & ~(size_t)255; return r; };
    short* rgbf  = (short*)alloc((size_t)BSV * 256 * 2);
    short* hall  = (short*)alloc((size_t)DD * BSV * 32 * 2);
    short* a_in  = (short*)alloc((size_t)BSV * 256 * 2);
    short* obb   = (short*)alloc((size_t)BS * 256 * 2);
    short* xq    = (short*)alloc((size_t)BS * 256 * 2);
    short* hb    = (short*)alloc((size_t)BS * 256 * 2);
    short* catb  = (short*)alloc((size_t)BS * 384 * 2);
    short* qkv   = (short*)alloc((size_t)BS * 768 * 2);
    short* rgbp  = qkv;
    float* qf    = (float*)alloc((size_t)BS * 256 * 4);
    float* fq    = (float*)alloc((size_t)BS * 256 * 4);
    // weights
    short* w1T   = (short*)alloc(256 * 64 * 2);
    short* w2T   = (short*)alloc(256 * 256 * 2);
    short* qwT   = (short*)alloc((size_t)DD * 256 * 256 * 2);
    short* kvpT  = (short*)alloc((size_t)DD * 512 * 288 * 2);
    short* aw1T  = (short*)alloc((size_t)DD * 32 * 256 * 2);
    short* aw2T  = (short*)alloc((size_t)DD * 256 * 32 * 2);
    short* owT   = (short*)alloc((size_t)DD * 256 * 256 * 2);
    short* fw1T  = (short*)alloc((size_t)DD * 1024 * 256 * 2);
    short* fw2T  = (short*)alloc((size_t)DD * 256 * 1024 * 2);
    short* sqkvT = (short*)alloc((size_t)DD * 768 * 256 * 2);
    short* sowT  = (short*)alloc((size_t)DD * 256 * 256 * 2);
    short* sfw1T = (short*)alloc((size_t)DD * 1024 * 256 * 2);
    short* sfw2T = (short*)alloc((size_t)DD * 256 * 1024 * 2);
    short* qw1T  = (short*)alloc((size_t)4 * 256 * 384 * 2);
    short* qw2T  = (short*)alloc((size_t)4 * 256 * 256 * 2);

    // ---- batched weight conversion (one dispatch) ----
    WJobs wj; int nj = 0, totblk = 0;
    // frag=0 (row-major [N,Kpad]), frag=1 (fragment-packed; KS/ntoff/ksoff)
    auto addj = [&](const float* s, short* d, int K, int N, int frag,
                    int KS, int ntoff, int ksoff, int Kpad,
                    int zi, size_t zo, int nz) {
        WJob& J = wj.j[nj++];
        J.src = s; J.dst = d; J.K = K; J.N = N; J.frag = frag;
        J.KS = KS; J.ntoff = ntoff; J.ksoff = ksoff; J.Kpad = Kpad;
        J.zi = zi; J.zo = zo; J.gy = (K + 31) >> 5;
        J.nblk = (N >> 5) * J.gy * nz;
        totblk += J.nblk;
    };
    addj(rgbfeat_w1, w1T, 35, 256, 0, 0, 0, 0, 64, 0, 0, 1);
    addj(rgbfeat_w2, w2T, 256, 256, 0, 0, 0, 0, 256, 0, 0, 1);
    addj(c_qw,  qwT,  256, 256, 1, 8, 0, 0, 0, 65536, 65536, DD);
    addj(c_kw,  kvpT, 256, 256, 1, 9, 0, 0, 0, 65536, 147456, DD);
    addj(c_pw2, kvpT, 32, 256, 1, 9, 0, 8, 0, 8192, 147456, DD);
    addj(c_vw,  kvpT, 256, 256, 1, 9, 16, 0, 0, 65536, 147456, DD);
    addj(c_pw2, kvpT, 32, 256, 1, 9, 16, 8, 0, 8192, 147456, DD);
    addj(c_aw1, aw1T, 256, 32, 1, 8, 0, 0, 0, 8192, 8192, DD);
    addj(c_aw2, aw2T, 32, 256, 1, 1, 0, 0, 0, 8192, 8192, DD);
    addj(c_ow,  owT,  256, 256, 1, 8, 0, 0, 0, 65536, 65536, DD);
    addj(c_fw1, fw1T, 256, 1024, 1, 8, 0, 0, 0, 262144, 262144, DD);
    addj(c_fw2, fw2T, 1024, 256, 1, 32, 0, 0, 0, 262144, 262144, DD);
    addj(s_qw,  sqkvT, 256, 256, 1, 8, 0, 0, 0, 65536, 196608, DD);
    addj(s_kw,  sqkvT, 256, 256, 1, 8, 16, 0, 0, 65536, 196608, DD);
    addj(s_vw,  sqkvT, 256, 256, 1, 8, 32, 0, 0, 65536, 196608, DD);
    addj(s_ow,  sowT,  256, 256, 1, 8, 0, 0, 0, 65536, 65536, DD);
    addj(s_fw1, sfw1T, 256, 1024, 1, 8, 0, 0, 0, 262144, 262144, DD);
    addj(s_fw2, sfw2T, 1024, 256, 1, 32, 0, 0, 0, 262144, 262144, DD);
    addj(q_w1,  qw1T, 346, 256, 1, 12, 0, 0, 0, 88576, 98304, 4);
    addj(q_w2,  qw2T, 256, 256, 1, 8, 0, 0, 0, 65536, 65536, 4);
    wconv_all<<<totblk, dim3(32, 8), 0, stream>>>(wj);

    // ---- preamble ----
    catpenc<<<(BS * 128) / 256, 256, 0, stream>>>(pts, ray_d, catb);
    rgbhall<<<(BSV * 64 + DD * BSV * 32) / 256, 256, 0, stream>>>(
        rgb_feat, ray_diff, c_pw1, c_pb1, rgbp, hall);
    GEMM_BF(128, 128, 64, 64, rgbp, w1T, rgbfeat_b1, a_in, BSV, 256, 64, 256, 1);
    GEMM_BF(128, 128, 64, 64, a_in, w2T, rgbfeat_b2, rgbf, BSV, 256, 256, 256, 0);
    vmaxln<<<BS, 256, 0, stream>>>(rgbf, c_ln_g, c_ln_b, fq, xq);
    qgemm0<<<256, 256, 0, stream>>>(xq, qwT, qf);

    for (int i = 0; i < DD; i++) {
        int j = i >> 1;
        crosskv<<<BSV / 32, 256, 0, stream>>>(
            rgbf, hall + (size_t)i * BSV * 32, kvpT + (size_t)i * 147456,
            qf, maskp,
            aw1T + (size_t)i * 8192, c_ab1 + i * 32,
            aw2T + (size_t)i * 8192, c_ab2 + i * 256, obb);
        chainA<<<256, 256, 0, stream>>>(obb, fq, catb, qkv,
            owT + (size_t)i * 65536, c_ob + i * 256, c_fg + i * 256, c_fb + i * 256,
            fw1T + (size_t)i * 262144, c_fb1 + i * 1024,
            fw2T + (size_t)i * 262144, c_fb2 + i * 256,
            qw1T + (size_t)j * 98304, q_b1 + j * 256,
            qw2T + (size_t)j * 65536, q_b2 + j * 256,
            s_ln_g + i * 256, s_ln_b + i * 256,
            sqkvT + (size_t)i * 196608, !(i & 1));
        attn_mfma<<<BB * 4, 64, 0, stream>>>(qkv, obb);
        int last = (i == DD - 1);
        chainB<<<256, 256, 0, stream>>>(obb, fq,
            sowT + (size_t)i * 65536, s_ob + i * 256, s_fg + i * 256, s_fb + i * 256,
            sfw1T + (size_t)i * 262144, s_fb1 + i * 1024,
            sfw2T + (size_t)i * 262144, s_fb2 + i * 256,
            last ? norm_g : c_ln_g + (i + 1) * 256,
            last ? norm_b : c_ln_b + (i + 1) * 256,
            last ? 1e-5f : 1e-6f,
            last ? nullptr : qwT + (size_t)(i + 1) * 65536,
            qf, last ? hb : nullptr);
    }

    headk<<<BB, 256, 0, stream>>>(hb, out_w, out_b, out);
}